// Round 6
// baseline (701.115 us; speedup 1.0000x reference)
//
#include <hip/hip_runtime.h>
#include <math.h>

#define B_ 16
#define L_ 8192
#define C_ 256
#define KTOP 2457            // max(1, int(8192*0.3))
#define JT 20                // recurrence taps; ||A||^20 ~ 1e-16 -> exact at fp32
#define M1 (B_*L_)           // 131072
#define M2 (B_*KTOP)         // 39312

// workspace layout in floats
#define XP_OFF  ((size_t)0)
#define Y_OFF   (XP_OFF + (size_t)M1*C_)        // 33554432
#define E_OFF   (Y_OFF  + (size_t)M2*C_)        // 43618304
#define CN_OFF  (E_OFF  + (size_t)M1)           // 43749376
#define CF_OFF  (CN_OFF + (size_t)B_*C_)        // 43753472
#define IDX_OFF (CF_OFF + (size_t)JT*C_)        // 43758592 (ints)
#define WIT_OFF (IDX_OFF + (size_t)M2)          // 43797904
#define WOT_OFF (WIT_OFF + (size_t)C_*C_)       // 43863440
// u64 key buffers alias the (not-yet-written) yb region: keys die before y_kernel writes yb

// ---------------- transpose Wi/Wo (256x256 each) into [K][N] layout ----------------
__global__ void transpose_kernel(const float* __restrict__ Wi, const float* __restrict__ Wo,
                                 float* __restrict__ WiT, float* __restrict__ WoT)
{
    __shared__ float t[32][33];
    const float* src = blockIdx.z ? Wo : Wi;
    float* dst = blockIdx.z ? WoT : WiT;
    int r0 = blockIdx.y * 32, c0 = blockIdx.x * 32;
    int tx = threadIdx.x, ty = threadIdx.y;      // 32 x 8
    #pragma unroll
    for (int r = 0; r < 4; r++)
        t[ty + r*8][tx] = src[(size_t)(r0 + ty + r*8)*C_ + c0 + tx];
    __syncthreads();
    #pragma unroll
    for (int r = 0; r < 4; r++)
        dst[(size_t)(c0 + ty + r*8)*C_ + r0 + tx] = t[tx][ty + r*8];
}

// ---------------- coef: cf[j][c] = sigmoid(Cp[c,:]) . (A^j sigmoid(Bp)) ----------------
__global__ void coef_kernel(const float* __restrict__ A, const float* __restrict__ Bp,
                            const float* __restrict__ Cp, float* __restrict__ cf)
{
    int c = threadIdx.x;                       // 256 threads
    __shared__ float As[256];
    __shared__ float v0[16];
    As[c] = A[c];
    if (c < 16) v0[c] = 1.0f / (1.0f + expf(-Bp[c]));
    float sC[16];
    #pragma unroll
    for (int i = 0; i < 16; i++) sC[i] = 1.0f / (1.0f + expf(-Cp[c*16 + i]));
    __syncthreads();
    float v[16];
    #pragma unroll
    for (int i = 0; i < 16; i++) v[i] = v0[i];
    for (int j = 0; j < JT; j++) {
        float d = 0.f;
        #pragma unroll
        for (int i = 0; i < 16; i++) d += sC[i] * v[i];
        cf[j*C_ + c] = d;
        float nv[16];
        #pragma unroll
        for (int i = 0; i < 16; i++) {
            float s = 0.f;
            #pragma unroll
            for (int m = 0; m < 16; m++) s += As[i*16 + m] * v[m];
            nv[i] = s;
        }
        #pragma unroll
        for (int i = 0; i < 16; i++) v[i] = nv[i];
    }
}

// ---------------- center2: cn[b,:] = normalize(dyt(x[b,L/2,:]) @ WiT + bi) ----------------
__global__ void center2_kernel(const float* __restrict__ x, const float* __restrict__ WiT,
                               const float* __restrict__ bi, const float* __restrict__ alpha,
                               const float* __restrict__ dw, const float* __restrict__ db,
                               float* __restrict__ cn)
{
    __shared__ float xn[256];
    __shared__ float red[4];
    int b = blockIdx.x, c = threadIdx.x;       // 256 threads
    float al = alpha[0];
    size_t base = ((size_t)b*L_ + L_/2)*C_;
    xn[c] = tanhf(al*x[base + c])*dw[c] + db[c];
    __syncthreads();
    float s = bi[c];
    #pragma unroll 8
    for (int k = 0; k < 256; k++) s = fmaf(xn[k], WiT[(size_t)k*C_ + c], s);
    float ss = s*s;
    #pragma unroll
    for (int off = 32; off; off >>= 1) ss += __shfl_xor(ss, off);
    if ((c & 63) == 0) red[c >> 6] = ss;
    __syncthreads();
    float tot = red[0] + red[1] + red[2] + red[3];
    float inv = 1.0f / fmaxf(sqrtf(tot), 1e-12f);
    cn[b*C_ + c] = s * inv;
}

// ---------------- GEMM1 + fused e: xp = dyt(x)@WiT + bi ; e[m] = xp.cn/||xp|| ----------------
// BM=128, BN=256(full), BK=32, 256 threads, 16x8 micro-tile, T14 reg prefetch.
// As[32][132] col-major(padded): A-frag = 4x ds_read_b128 BROADCAST (2 addr/wave, free);
// staging writes 4-way conflicted scalars - hidden on LDS pipe under 256cy FMA/kk.
// __launch_bounds__(256,2): VGPR budget 256 - (256,3) caps at 168 and SPILLS acc (round-3 9.6GB scratch)
__global__ __launch_bounds__(256, 2) void gemm1_kernel(
    const float* __restrict__ x, const float* __restrict__ WiT,
    const float* __restrict__ bi, const float* __restrict__ alpha,
    const float* __restrict__ dw, const float* __restrict__ db,
    const float* __restrict__ cn, float* __restrict__ xp, float* __restrict__ e)
{
    __shared__ float As[32*132];   // [kk][m], pad 132 keeps 16B align
    __shared__ float Bs[32*256];   // [kk][n]
    const int tid = threadIdx.x;
    const int tn2 = tid & 31;      // cols tn2*4..+3 and 128+tn2*4..+3
    const int tm2 = tid >> 5;      // rows tm2*16..+15
    const int m0 = blockIdx.x * 128;
    const int b  = m0 >> 13;
    const float al = alpha[0];
    const int ar = tid >> 3;             // A stage row 0..31 (+it*32)
    const int ak = (tid & 7) * 4;        // A stage k 0,4,..,28
    const int br = tid >> 6;             // B stage row (+it*4)
    const int bc = (tid & 63) * 4;

    float acc[16][8];
    #pragma unroll
    for (int i = 0; i < 16; i++)
        #pragma unroll
        for (int j = 0; j < 8; j++) acc[i][j] = 0.f;

    // prologue prefetch k0=0
    float4 xa[4], wb[8];
    #pragma unroll
    for (int it = 0; it < 4; it++)
        xa[it] = *(const float4*)&x[(size_t)(m0 + ar + it*32)*C_ + ak];
    #pragma unroll
    for (int it = 0; it < 8; it++)
        wb[it] = *(const float4*)&WiT[(size_t)(br + it*4)*C_ + bc];

    for (int k0 = 0; k0 < C_; k0 += 32) {
        // stage from regs (dyt transform on A), transpose into col-major As
        float4 w4 = *(const float4*)&dw[k0 + ak];
        float4 b4 = *(const float4*)&db[k0 + ak];
        #pragma unroll
        for (int it = 0; it < 4; it++) {
            float4 v = xa[it];
            int m = ar + it*32;
            As[(ak+0)*132 + m] = tanhf(al*v.x)*w4.x + b4.x;
            As[(ak+1)*132 + m] = tanhf(al*v.y)*w4.y + b4.y;
            As[(ak+2)*132 + m] = tanhf(al*v.z)*w4.z + b4.z;
            As[(ak+3)*132 + m] = tanhf(al*v.w)*w4.w + b4.w;
        }
        #pragma unroll
        for (int it = 0; it < 8; it++)
            *(float4*)&Bs[(br + it*4)*256 + bc] = wb[it];
        __syncthreads();
        // prefetch next tile (hides HBM/L2 latency under compute)
        if (k0 + 32 < C_) {
            #pragma unroll
            for (int it = 0; it < 4; it++)
                xa[it] = *(const float4*)&x[(size_t)(m0 + ar + it*32)*C_ + k0 + 32 + ak];
            #pragma unroll
            for (int it = 0; it < 8; it++)
                wb[it] = *(const float4*)&WiT[(size_t)(k0 + 32 + br + it*4)*C_ + bc];
        }
        #pragma unroll 2
        for (int kk = 0; kk < 32; kk++) {
            float a[16];
            *(float4*)&a[0]  = *(const float4*)&As[kk*132 + tm2*16];
            *(float4*)&a[4]  = *(const float4*)&As[kk*132 + tm2*16 + 4];
            *(float4*)&a[8]  = *(const float4*)&As[kk*132 + tm2*16 + 8];
            *(float4*)&a[12] = *(const float4*)&As[kk*132 + tm2*16 + 12];
            float4 b0 = *(const float4*)&Bs[kk*256 + tn2*4];
            float4 b1 = *(const float4*)&Bs[kk*256 + tn2*4 + 128];
            #pragma unroll
            for (int i = 0; i < 16; i++) {
                acc[i][0] = fmaf(a[i], b0.x, acc[i][0]);
                acc[i][1] = fmaf(a[i], b0.y, acc[i][1]);
                acc[i][2] = fmaf(a[i], b0.z, acc[i][2]);
                acc[i][3] = fmaf(a[i], b0.w, acc[i][3]);
                acc[i][4] = fmaf(a[i], b1.x, acc[i][4]);
                acc[i][5] = fmaf(a[i], b1.y, acc[i][5]);
                acc[i][6] = fmaf(a[i], b1.z, acc[i][6]);
                acc[i][7] = fmaf(a[i], b1.w, acc[i][7]);
            }
        }
        __syncthreads();
    }
    float4 bi0 = *(const float4*)&bi[tn2*4];
    float4 bi1 = *(const float4*)&bi[tn2*4 + 128];
    float4 c0  = *(const float4*)&cn[b*C_ + tn2*4];
    float4 c1  = *(const float4*)&cn[b*C_ + tn2*4 + 128];
    #pragma unroll
    for (int i = 0; i < 16; i++) {
        size_t row = m0 + tm2*16 + i;
        float4 o0 = make_float4(acc[i][0]+bi0.x, acc[i][1]+bi0.y, acc[i][2]+bi0.z, acc[i][3]+bi0.w);
        float4 o1 = make_float4(acc[i][4]+bi1.x, acc[i][5]+bi1.y, acc[i][6]+bi1.z, acc[i][7]+bi1.w);
        *(float4*)&xp[row*C_ + tn2*4]       = o0;
        *(float4*)&xp[row*C_ + tn2*4 + 128] = o1;
        float dt = o0.x*c0.x + o0.y*c0.y + o0.z*c0.z + o0.w*c0.w
                 + o1.x*c1.x + o1.y*c1.y + o1.z*c1.z + o1.w*c1.w;
        float ss = o0.x*o0.x + o0.y*o0.y + o0.z*o0.z + o0.w*o0.w
                 + o1.x*o1.x + o1.y*o1.y + o1.z*o1.z + o1.w*o1.w;
        #pragma unroll
        for (int off = 16; off; off >>= 1) {
            dt += __shfl_xor(dt, off);
            ss += __shfl_xor(ss, off);
        }
        if (tn2 == 0) e[row] = dt / fmaxf(sqrtf(ss), 1e-12f);
    }
}

// ---------------- softmax per batch; emit sim + u64 keys (sim desc, idx asc) ----------------
__global__ __launch_bounds__(1024) void softmax_kernel(
    const float* __restrict__ e, float* __restrict__ sim, unsigned long long* __restrict__ kw)
{
    __shared__ float scratch[32];
    const int b = blockIdx.x, tid = threadIdx.x;
    const int lane = tid & 63, wid = tid >> 6; // 16 waves
    const float* eb = e + (size_t)b*L_;
    float ev[8];
    #pragma unroll
    for (int s = 0; s < 8; s++) ev[s] = eb[tid + s*1024];
    float mx = ev[0];
    #pragma unroll
    for (int s = 1; s < 8; s++) mx = fmaxf(mx, ev[s]);
    #pragma unroll
    for (int off = 32; off; off >>= 1) mx = fmaxf(mx, __shfl_xor(mx, off));
    if (lane == 0) scratch[wid] = mx;
    __syncthreads();
    if (tid == 0) {
        float m2 = scratch[0];
        for (int i = 1; i < 16; i++) m2 = fmaxf(m2, scratch[i]);
        scratch[20] = m2;
    }
    __syncthreads();
    mx = scratch[20];
    float pv[8], sum = 0.f;
    #pragma unroll
    for (int s = 0; s < 8; s++) { pv[s] = expf(ev[s] - mx); sum += pv[s]; }
    #pragma unroll
    for (int off = 32; off; off >>= 1) sum += __shfl_xor(sum, off);
    __syncthreads();
    if (lane == 0) scratch[wid] = sum;
    __syncthreads();
    if (tid == 0) {
        float s2 = 0.f;
        for (int i = 0; i < 16; i++) s2 += scratch[i];
        scratch[21] = s2;
    }
    __syncthreads();
    float inv = 1.0f / scratch[21];
    #pragma unroll
    for (int s = 0; s < 8; s++) {
        int l = tid + s*1024;
        float sm = pv[s] * inv;
        sim[(size_t)b*L_ + l] = sm;
        kw[(size_t)b*L_ + l] =
            ((unsigned long long)__float_as_uint(sm) << 32) | (unsigned)(0xFFFFFFFFu - l);
    }
}

// ---------------- sort 1024-element chunks descending (bitonic in LDS) ----------------
__global__ __launch_bounds__(256) void sort1k_kernel(unsigned long long* __restrict__ keys)
{
    __shared__ unsigned long long k[1024];
    size_t base = (size_t)blockIdx.x * 1024;
    int tid = threadIdx.x;
    #pragma unroll
    for (int s = 0; s < 4; s++) k[tid + s*256] = keys[base + tid + s*256];
    __syncthreads();
    for (int ksz = 2; ksz <= 1024; ksz <<= 1) {
        for (int j = ksz >> 1; j > 0; j >>= 1) {
            #pragma unroll
            for (int s = 0; s < 2; s++) {
                int p = tid + s*256;                       // pair 0..511
                int i = ((p & ~(j-1)) << 1) | (p & (j-1)); // bit j clear
                int ix = i | j;
                unsigned long long a = k[i], c = k[ix];
                bool desc = ((i & ksz) == 0);
                if (desc ? (a < c) : (a > c)) { k[i] = c; k[ix] = a; }
            }
            __syncthreads();
        }
    }
    #pragma unroll
    for (int s = 0; s < 4; s++) keys[base + tid + s*256] = k[tid + s*256];
}

// ---------------- merge pass, tile-parallel: fixed 2048-output tiles, merge-path ----------------
// desc runs, distinct keys. grid = B_*L_/2048 blocks per pass regardless of run size.
#define MT 2048
__global__ __launch_bounds__(256) void merge_kernel(
    const unsigned long long* __restrict__ src, unsigned long long* __restrict__ dst, int run)
{
    const size_t tile = blockIdx.x;
    const size_t pairSpan = (size_t)2 * run;
    const size_t p = tile * MT / pairSpan;
    const int o = (int)(tile * MT % pairSpan);
    const unsigned long long* A  = src + p * pairSpan;
    const unsigned long long* Bv = A + run;
    unsigned long long* D = dst + p * pairSpan;

    int q0 = o + threadIdx.x * (MT/256);       // 8 outputs per thread
    int lo = (q0 > run) ? (q0 - run) : 0;
    int hi = (q0 < run) ? q0 : run;
    while (lo < hi) {
        int mid = (lo + hi) >> 1;
        if (A[mid] >= Bv[q0 - 1 - mid]) lo = mid + 1; else hi = mid;
    }
    int a = lo, bq = q0 - lo;
    #pragma unroll
    for (int q = 0; q < MT/256; q++) {
        unsigned long long va = (a < run) ? A[a] : 0ULL;
        unsigned long long vb = (bq < run) ? Bv[bq] : 0ULL;
        bool takeA = (bq >= run) || ((a < run) && (va > vb));
        D[q0 + q] = takeA ? va : vb;
        if (takeA) a++; else bq++;
    }
}

// ---------------- emit top-KTOP indices per batch ----------------
__global__ void emit_idx_kernel(const unsigned long long* __restrict__ kw, int* __restrict__ idxo)
{
    int b = blockIdx.x;
    for (int t = threadIdx.x; t < KTOP; t += blockDim.x)
        idxo[b*KTOP + t] = (int)(0xFFFFFFFFu - (unsigned)(kw[(size_t)b*L_ + t] & 0xFFFFFFFFu));
}

// ---------------- y: tiled over 32 consecutive t with 51-row LDS window ----------------
#define TT 32
__global__ __launch_bounds__(256) void y_kernel(const float* __restrict__ xp,
    const int* __restrict__ idx, const float* __restrict__ conv_w,
    const float* __restrict__ cf, float* __restrict__ y)
{
    __shared__ float rows[(TT + JT - 1) * C_];   // 51 rows x 1KB = 51KB
    const int b = blockIdx.y;
    const int t0 = blockIdx.x * TT;
    const int tid = threadIdx.x;
    const int c4 = (tid & 63) * 4;
    const int tg = tid >> 6;
    const int* idxb = idx + b*KTOP;

    for (int s = tid; s < (TT + JT - 1) * 64; s += 256) {
        int r = s >> 6, cq = (s & 63) * 4;
        int gi = t0 - (JT - 1) + r;
        float4 v = make_float4(0.f, 0.f, 0.f, 0.f);
        if (gi >= 0 && gi < KTOP) {
            int l = idxb[gi];
            v = *(const float4*)&xp[((size_t)b*L_ + l)*C_ + cq];
        }
        *(float4*)&rows[r*C_ + cq] = v;
    }
    float4 cfr[JT];
    #pragma unroll
    for (int j = 0; j < JT; j++) cfr[j] = *(const float4*)&cf[j*C_ + c4];
    float4 cw = *(const float4*)&conv_w[c4];
    __syncthreads();

    #pragma unroll
    for (int u = 0; u < TT/4; u++) {
        int tl = tg + u*4;
        int t = t0 + tl;
        if (t < KTOP) {
            float4 acc = make_float4(0.f, 0.f, 0.f, 0.f);
            #pragma unroll
            for (int j = 0; j < JT; j++) {
                const float4 v = *(const float4*)&rows[(tl + JT - 1 - j)*C_ + c4];
                acc.x = fmaf(cfr[j].x, v.x, acc.x);
                acc.y = fmaf(cfr[j].y, v.y, acc.y);
                acc.z = fmaf(cfr[j].z, v.z, acc.z);
                acc.w = fmaf(cfr[j].w, v.w, acc.w);
            }
            acc.x *= cw.x; acc.y *= cw.y; acc.z *= cw.z; acc.w *= cw.w;
            *(float4*)&y[((size_t)b*KTOP + t)*C_ + c4] = acc;
        }
    }
}

// ---------------- residual copy ----------------
__global__ void copy_kernel(const float4* __restrict__ src, float4* __restrict__ dst)
{
    size_t n4 = (size_t)M1*C_/4;
    for (size_t i = (size_t)blockIdx.x*blockDim.x + threadIdx.x; i < n4;
         i += (size_t)gridDim.x*blockDim.x)
        dst[i] = src[i];
}

// ---------------- GEMM2 + scatter epilogue: out[b,l,:] = x[b,l,:] + y@WoT + bo ----------------
__global__ __launch_bounds__(256, 2) void gemm2_kernel(
    const float* __restrict__ y, const float* __restrict__ WoT,
    const float* __restrict__ bo, const float* __restrict__ x,
    const int* __restrict__ idx, float* __restrict__ out0)
{
    __shared__ float As[32*132];
    __shared__ float Bs[32*256];
    const int tid = threadIdx.x;
    const int tn2 = tid & 31;
    const int tm2 = tid >> 5;
    const int m0 = blockIdx.x * 128;
    const int ar = tid >> 3;
    const int ak = (tid & 7) * 4;
    const int br = tid >> 6;
    const int bc = (tid & 63) * 4;

    float acc[16][8];
    #pragma unroll
    for (int i = 0; i < 16; i++)
        #pragma unroll
        for (int j = 0; j < 8; j++) acc[i][j] = 0.f;

    float4 xa[4], wb[8];
    #pragma unroll
    for (int it = 0; it < 4; it++) {
        int m = m0 + ar + it*32;
        xa[it] = (m < M2) ? *(const float4*)&y[(size_t)m*C_ + ak]
                          : make_float4(0.f, 0.f, 0.f, 0.f);
    }
    #pragma unroll
    for (int it = 0; it < 8; it++)
        wb[it] = *(const float4*)&WoT[(size_t)(br + it*4)*C_ + bc];

    for (int k0 = 0; k0 < C_; k0 += 32) {
        #pragma unroll
        for (int it = 0; it < 4; it++) {
            float4 v = xa[it];
            int m = ar + it*32;
            As[(ak+0)*132 + m] = v.x;
            As[(ak+1)*132 + m] = v.y;
            As[(ak+2)*132 + m] = v.z;
            As[(ak+3)*132 + m] = v.w;
        }
        #pragma unroll
        for (int it = 0; it < 8; it++)
            *(float4*)&Bs[(br + it*4)*256 + bc] = wb[it];
        __syncthreads();
        if (k0 + 32 < C_) {
            #pragma unroll
            for (int it = 0; it < 4; it++) {
                int m = m0 + ar + it*32;
                xa[it] = (m < M2) ? *(const float4*)&y[(size_t)m*C_ + k0 + 32 + ak]
                                  : make_float4(0.f, 0.f, 0.f, 0.f);
            }
            #pragma unroll
            for (int it = 0; it < 8; it++)
                wb[it] = *(const float4*)&WoT[(size_t)(k0 + 32 + br + it*4)*C_ + bc];
        }
        #pragma unroll 2
        for (int kk = 0; kk < 32; kk++) {
            float a[16];
            *(float4*)&a[0]  = *(const float4*)&As[kk*132 + tm2*16];
            *(float4*)&a[4]  = *(const float4*)&As[kk*132 + tm2*16 + 4];
            *(float4*)&a[8]  = *(const float4*)&As[kk*132 + tm2*16 + 8];
            *(float4*)&a[12] = *(const float4*)&As[kk*132 + tm2*16 + 12];
            float4 b0 = *(const float4*)&Bs[kk*256 + tn2*4];
            float4 b1 = *(const float4*)&Bs[kk*256 + tn2*4 + 128];
            #pragma unroll
            for (int i = 0; i < 16; i++) {
                acc[i][0] = fmaf(a[i], b0.x, acc[i][0]);
                acc[i][1] = fmaf(a[i], b0.y, acc[i][1]);
                acc[i][2] = fmaf(a[i], b0.z, acc[i][2]);
                acc[i][3] = fmaf(a[i], b0.w, acc[i][3]);
                acc[i][4] = fmaf(a[i], b1.x, acc[i][4]);
                acc[i][5] = fmaf(a[i], b1.y, acc[i][5]);
                acc[i][6] = fmaf(a[i], b1.z, acc[i][6]);
                acc[i][7] = fmaf(a[i], b1.w, acc[i][7]);
            }
        }
        __syncthreads();
    }
    float4 bo0 = *(const float4*)&bo[tn2*4];
    float4 bo1 = *(const float4*)&bo[tn2*4 + 128];
    #pragma unroll
    for (int i = 0; i < 16; i++) {
        int m = m0 + tm2*16 + i;
        if (m < M2) {
            int b = m / KTOP, t = m - b*KTOP;
            int l = idx[b*KTOP + t];
            size_t base = ((size_t)b*L_ + l)*C_;
            float4 x0 = *(const float4*)&x[base + tn2*4];
            float4 x1 = *(const float4*)&x[base + tn2*4 + 128];
            float4 o0 = make_float4(acc[i][0]+bo0.x+x0.x, acc[i][1]+bo0.y+x0.y,
                                    acc[i][2]+bo0.z+x0.z, acc[i][3]+bo0.w+x0.w);
            float4 o1 = make_float4(acc[i][4]+bo1.x+x1.x, acc[i][5]+bo1.y+x1.y,
                                    acc[i][6]+bo1.z+x1.z, acc[i][7]+bo1.w+x1.w);
            *(float4*)&out0[base + tn2*4]       = o0;
            *(float4*)&out0[base + tn2*4 + 128] = o1;
        }
    }
}

extern "C" void kernel_launch(void* const* d_in, const int* in_sizes, int n_in,
                              void* d_out, int out_size, void* d_ws, size_t ws_size,
                              hipStream_t stream)
{
    const float* x      = (const float*)d_in[0];
    const float* alpha  = (const float*)d_in[1];
    const float* dyt_w  = (const float*)d_in[2];
    const float* dyt_b  = (const float*)d_in[3];
    const float* Wi     = (const float*)d_in[4];
    const float* bi     = (const float*)d_in[5];
    const float* conv_w = (const float*)d_in[6];
    const float* A      = (const float*)d_in[7];
    const float* Bp     = (const float*)d_in[8];
    const float* Cp     = (const float*)d_in[9];
    const float* Wo     = (const float*)d_in[10];
    const float* bo     = (const float*)d_in[11];

    float* ws  = (float*)d_ws;
    float* xp  = ws + XP_OFF;
    float* yb  = ws + Y_OFF;
    float* e   = ws + E_OFF;
    float* cn  = ws + CN_OFF;
    float* cf  = ws + CF_OFF;
    int*   idx = (int*)(ws + IDX_OFF);
    float* WiT = ws + WIT_OFF;
    float* WoT = ws + WOT_OFF;
    // key buffers alias yb (dead until y_kernel): 2 x 1MB
    unsigned long long* kw1 = (unsigned long long*)(ws + Y_OFF);
    unsigned long long* kw2 = kw1 + (size_t)B_*L_;

    float* out0 = (float*)d_out;
    float* sim  = out0 + (size_t)M1*C_;

    transpose_kernel<<<dim3(8,8,2), dim3(32,8), 0, stream>>>(Wi, Wo, WiT, WoT);
    coef_kernel<<<1, 256, 0, stream>>>(A, Bp, Cp, cf);
    center2_kernel<<<B_, 256, 0, stream>>>(x, WiT, bi, alpha, dyt_w, dyt_b, cn);
    gemm1_kernel<<<M1/128, 256, 0, stream>>>(x, WiT, bi, alpha, dyt_w, dyt_b, cn, xp, e);
    softmax_kernel<<<B_, 1024, 0, stream>>>(e, sim, kw1);
    sort1k_kernel<<<B_*L_/1024, 256, 0, stream>>>(kw1);
    merge_kernel<<<B_*L_/MT, 256, 0, stream>>>(kw1, kw2, 1024);
    merge_kernel<<<B_*L_/MT, 256, 0, stream>>>(kw2, kw1, 2048);
    merge_kernel<<<B_*L_/MT, 256, 0, stream>>>(kw1, kw2, 4096);
    emit_idx_kernel<<<B_, 256, 0, stream>>>(kw2, idx);
    y_kernel<<<dim3((KTOP + TT - 1)/TT, B_), 256, 0, stream>>>(xp, idx, conv_w, cf, yb);
    copy_kernel<<<2048, 256, 0, stream>>>((const float4*)x, (float4*)out0);
    gemm2_kernel<<<(M2 + 127)/128, 256, 0, stream>>>(yb, WoT, bo, x, idx, out0);
}

// Round 7
// 669.772 us; speedup vs baseline: 1.0468x; 1.0468x over previous
//
#include <hip/hip_runtime.h>
#include <math.h>

#define B_ 16
#define L_ 8192
#define C_ 256
#define KTOP 2457            // max(1, int(8192*0.3))
#define JT 20                // recurrence taps; ||A||^20 ~ 1e-16 -> exact at fp32
#define M1 (B_*L_)           // 131072
#define M2 (B_*KTOP)         // 39312

// workspace layout in floats
#define XP_OFF  ((size_t)0)
#define Y_OFF   (XP_OFF + (size_t)M1*C_)        // 33554432
#define E_OFF   (Y_OFF  + (size_t)M2*C_)        // 43618304
#define CN_OFF  (E_OFF  + (size_t)M1)           // 43749376
#define CF_OFF  (CN_OFF + (size_t)B_*C_)        // 43753472
#define IDX_OFF (CF_OFF + (size_t)JT*C_)        // 43758592 (ints)
#define WIT_OFF (IDX_OFF + (size_t)M2)          // 43797904
#define WOT_OFF (WIT_OFF + (size_t)C_*C_)       // 43863440
// u64 key buffers alias the (not-yet-written) yb region: keys die before y_kernel writes yb

// ---------------- transpose Wi/Wo (256x256 each) into [K][N] layout ----------------
__global__ void transpose_kernel(const float* __restrict__ Wi, const float* __restrict__ Wo,
                                 float* __restrict__ WiT, float* __restrict__ WoT)
{
    __shared__ float t[32][33];
    const float* src = blockIdx.z ? Wo : Wi;
    float* dst = blockIdx.z ? WoT : WiT;
    int r0 = blockIdx.y * 32, c0 = blockIdx.x * 32;
    int tx = threadIdx.x, ty = threadIdx.y;      // 32 x 8
    #pragma unroll
    for (int r = 0; r < 4; r++)
        t[ty + r*8][tx] = src[(size_t)(r0 + ty + r*8)*C_ + c0 + tx];
    __syncthreads();
    #pragma unroll
    for (int r = 0; r < 4; r++)
        dst[(size_t)(c0 + ty + r*8)*C_ + r0 + tx] = t[tx][ty + r*8];
}

// ---------------- coef: cf[j][c] = sigmoid(Cp[c,:]) . (A^j sigmoid(Bp)) ----------------
__global__ void coef_kernel(const float* __restrict__ A, const float* __restrict__ Bp,
                            const float* __restrict__ Cp, float* __restrict__ cf)
{
    int c = threadIdx.x;                       // 256 threads
    __shared__ float As[256];
    __shared__ float v0[16];
    As[c] = A[c];
    if (c < 16) v0[c] = 1.0f / (1.0f + expf(-Bp[c]));
    float sC[16];
    #pragma unroll
    for (int i = 0; i < 16; i++) sC[i] = 1.0f / (1.0f + expf(-Cp[c*16 + i]));
    __syncthreads();
    float v[16];
    #pragma unroll
    for (int i = 0; i < 16; i++) v[i] = v0[i];
    for (int j = 0; j < JT; j++) {
        float d = 0.f;
        #pragma unroll
        for (int i = 0; i < 16; i++) d += sC[i] * v[i];
        cf[j*C_ + c] = d;
        float nv[16];
        #pragma unroll
        for (int i = 0; i < 16; i++) {
            float s = 0.f;
            #pragma unroll
            for (int m = 0; m < 16; m++) s += As[i*16 + m] * v[m];
            nv[i] = s;
        }
        #pragma unroll
        for (int i = 0; i < 16; i++) v[i] = nv[i];
    }
}

// ---------------- center2: cn[b,:] = normalize(dyt(x[b,L/2,:]) @ WiT + bi) ----------------
__global__ void center2_kernel(const float* __restrict__ x, const float* __restrict__ WiT,
                               const float* __restrict__ bi, const float* __restrict__ alpha,
                               const float* __restrict__ dw, const float* __restrict__ db,
                               float* __restrict__ cn)
{
    __shared__ float xn[256];
    __shared__ float red[4];
    int b = blockIdx.x, c = threadIdx.x;       // 256 threads
    float al = alpha[0];
    size_t base = ((size_t)b*L_ + L_/2)*C_;
    xn[c] = tanhf(al*x[base + c])*dw[c] + db[c];
    __syncthreads();
    float s = bi[c];
    #pragma unroll 8
    for (int k = 0; k < 256; k++) s = fmaf(xn[k], WiT[(size_t)k*C_ + c], s);
    float ss = s*s;
    #pragma unroll
    for (int off = 32; off; off >>= 1) ss += __shfl_xor(ss, off);
    if ((c & 63) == 0) red[c >> 6] = ss;
    __syncthreads();
    float tot = red[0] + red[1] + red[2] + red[3];
    float inv = 1.0f / fmaxf(sqrtf(tot), 1e-12f);
    cn[b*C_ + c] = s * inv;
}

// ---------------- GEMM1 + fused e: xp = dyt(x)@WiT + bi ; e[m] = xp.cn/||xp|| ----------------
// BM=128, BN=256(full), BK=32, 256 threads, 16x8 micro-tile.
// As[32][132] col-major(padded): A-frag = 4x ds_read_b128 BROADCAST (2 addr/wave, free);
// B-frag split-column (tn2*4 and +128): conflict-free. ~48 LDS cyc/wave/kk vs 256 VALU -> VALU-bound.
// NO cross-loop register prefetch: round-6 showed it spills silently (VGPR stays 112,
// WRITE_SIZE +208MB scratch traffic). Direct global->LDS staging only.
// __launch_bounds__(256,2): VGPR budget 256 - (256,3) caps at 168 and SPILLS acc (round-3 9.6GB scratch)
__global__ __launch_bounds__(256, 2) void gemm1_kernel(
    const float* __restrict__ x, const float* __restrict__ WiT,
    const float* __restrict__ bi, const float* __restrict__ alpha,
    const float* __restrict__ dw, const float* __restrict__ db,
    const float* __restrict__ cn, float* __restrict__ xp, float* __restrict__ e)
{
    __shared__ float As[32*132];   // [kk][m], pad 132 keeps 16B align
    __shared__ float Bs[32*256];   // [kk][n]
    const int tid = threadIdx.x;
    const int tn2 = tid & 31;      // cols tn2*4..+3 and 128+tn2*4..+3
    const int tm2 = tid >> 5;      // rows tm2*16..+15
    const int m0 = blockIdx.x * 128;
    const int b  = m0 >> 13;
    const float al = alpha[0];

    float acc[16][8];
    #pragma unroll
    for (int i = 0; i < 16; i++)
        #pragma unroll
        for (int j = 0; j < 8; j++) acc[i][j] = 0.f;

    for (int k0 = 0; k0 < C_; k0 += 32) {
        // A stage: 128x32 tile, dyt transform, transpose into col-major As
        #pragma unroll
        for (int it = 0; it < 4; it++) {
            int i2 = tid + it*256;
            int ar = i2 >> 3;              // row 0..127
            int ak = (i2 & 7) * 4;         // k 0,4,..,28
            float4 v  = *(const float4*)&x[(size_t)(m0 + ar)*C_ + k0 + ak];
            float4 w4 = *(const float4*)&dw[k0 + ak];
            float4 b4 = *(const float4*)&db[k0 + ak];
            As[(ak+0)*132 + ar] = tanhf(al*v.x)*w4.x + b4.x;
            As[(ak+1)*132 + ar] = tanhf(al*v.y)*w4.y + b4.y;
            As[(ak+2)*132 + ar] = tanhf(al*v.z)*w4.z + b4.z;
            As[(ak+3)*132 + ar] = tanhf(al*v.w)*w4.w + b4.w;
        }
        // B stage: row copy (contiguous, conflict-free)
        #pragma unroll
        for (int it = 0; it < 8; it++) {
            int i2 = tid + it*256;
            int br = i2 >> 6;
            int bc = (i2 & 63) * 4;
            *(float4*)&Bs[br*256 + bc] = *(const float4*)&WiT[(size_t)(k0 + br)*C_ + bc];
        }
        __syncthreads();
        #pragma unroll 2
        for (int kk = 0; kk < 32; kk++) {
            float a[16];
            *(float4*)&a[0]  = *(const float4*)&As[kk*132 + tm2*16];
            *(float4*)&a[4]  = *(const float4*)&As[kk*132 + tm2*16 + 4];
            *(float4*)&a[8]  = *(const float4*)&As[kk*132 + tm2*16 + 8];
            *(float4*)&a[12] = *(const float4*)&As[kk*132 + tm2*16 + 12];
            float4 b0 = *(const float4*)&Bs[kk*256 + tn2*4];
            float4 b1 = *(const float4*)&Bs[kk*256 + tn2*4 + 128];
            #pragma unroll
            for (int i = 0; i < 16; i++) {
                acc[i][0] = fmaf(a[i], b0.x, acc[i][0]);
                acc[i][1] = fmaf(a[i], b0.y, acc[i][1]);
                acc[i][2] = fmaf(a[i], b0.z, acc[i][2]);
                acc[i][3] = fmaf(a[i], b0.w, acc[i][3]);
                acc[i][4] = fmaf(a[i], b1.x, acc[i][4]);
                acc[i][5] = fmaf(a[i], b1.y, acc[i][5]);
                acc[i][6] = fmaf(a[i], b1.z, acc[i][6]);
                acc[i][7] = fmaf(a[i], b1.w, acc[i][7]);
            }
        }
        __syncthreads();
    }
    float4 bi0 = *(const float4*)&bi[tn2*4];
    float4 bi1 = *(const float4*)&bi[tn2*4 + 128];
    float4 c0  = *(const float4*)&cn[b*C_ + tn2*4];
    float4 c1  = *(const float4*)&cn[b*C_ + tn2*4 + 128];
    #pragma unroll
    for (int i = 0; i < 16; i++) {
        size_t row = m0 + tm2*16 + i;
        float4 o0 = make_float4(acc[i][0]+bi0.x, acc[i][1]+bi0.y, acc[i][2]+bi0.z, acc[i][3]+bi0.w);
        float4 o1 = make_float4(acc[i][4]+bi1.x, acc[i][5]+bi1.y, acc[i][6]+bi1.z, acc[i][7]+bi1.w);
        *(float4*)&xp[row*C_ + tn2*4]       = o0;
        *(float4*)&xp[row*C_ + tn2*4 + 128] = o1;
        float dt = o0.x*c0.x + o0.y*c0.y + o0.z*c0.z + o0.w*c0.w
                 + o1.x*c1.x + o1.y*c1.y + o1.z*c1.z + o1.w*c1.w;
        float ss = o0.x*o0.x + o0.y*o0.y + o0.z*o0.z + o0.w*o0.w
                 + o1.x*o1.x + o1.y*o1.y + o1.z*o1.z + o1.w*o1.w;
        #pragma unroll
        for (int off = 16; off; off >>= 1) {
            dt += __shfl_xor(dt, off);
            ss += __shfl_xor(ss, off);
        }
        if (tn2 == 0) e[row] = dt / fmaxf(sqrtf(ss), 1e-12f);
    }
}

// ---------------- softmax per batch; emit sim + u64 keys (sim desc, idx asc) ----------------
__global__ __launch_bounds__(1024) void softmax_kernel(
    const float* __restrict__ e, float* __restrict__ sim, unsigned long long* __restrict__ kw)
{
    __shared__ float scratch[32];
    const int b = blockIdx.x, tid = threadIdx.x;
    const int lane = tid & 63, wid = tid >> 6; // 16 waves
    const float* eb = e + (size_t)b*L_;
    float ev[8];
    #pragma unroll
    for (int s = 0; s < 8; s++) ev[s] = eb[tid + s*1024];
    float mx = ev[0];
    #pragma unroll
    for (int s = 1; s < 8; s++) mx = fmaxf(mx, ev[s]);
    #pragma unroll
    for (int off = 32; off; off >>= 1) mx = fmaxf(mx, __shfl_xor(mx, off));
    if (lane == 0) scratch[wid] = mx;
    __syncthreads();
    if (tid == 0) {
        float m2 = scratch[0];
        for (int i = 1; i < 16; i++) m2 = fmaxf(m2, scratch[i]);
        scratch[20] = m2;
    }
    __syncthreads();
    mx = scratch[20];
    float pv[8], sum = 0.f;
    #pragma unroll
    for (int s = 0; s < 8; s++) { pv[s] = expf(ev[s] - mx); sum += pv[s]; }
    #pragma unroll
    for (int off = 32; off; off >>= 1) sum += __shfl_xor(sum, off);
    __syncthreads();
    if (lane == 0) scratch[wid] = sum;
    __syncthreads();
    if (tid == 0) {
        float s2 = 0.f;
        for (int i = 0; i < 16; i++) s2 += scratch[i];
        scratch[21] = s2;
    }
    __syncthreads();
    float inv = 1.0f / scratch[21];
    #pragma unroll
    for (int s = 0; s < 8; s++) {
        int l = tid + s*1024;
        float sm = pv[s] * inv;
        sim[(size_t)b*L_ + l] = sm;
        kw[(size_t)b*L_ + l] =
            ((unsigned long long)__float_as_uint(sm) << 32) | (unsigned)(0xFFFFFFFFu - l);
    }
}

// ---------------- sort 1024-element chunks descending (bitonic in LDS) ----------------
__global__ __launch_bounds__(256) void sort1k_kernel(unsigned long long* __restrict__ keys)
{
    __shared__ unsigned long long k[1024];
    size_t base = (size_t)blockIdx.x * 1024;
    int tid = threadIdx.x;
    #pragma unroll
    for (int s = 0; s < 4; s++) k[tid + s*256] = keys[base + tid + s*256];
    __syncthreads();
    for (int ksz = 2; ksz <= 1024; ksz <<= 1) {
        for (int j = ksz >> 1; j > 0; j >>= 1) {
            #pragma unroll
            for (int s = 0; s < 2; s++) {
                int p = tid + s*256;                       // pair 0..511
                int i = ((p & ~(j-1)) << 1) | (p & (j-1)); // bit j clear
                int ix = i | j;
                unsigned long long a = k[i], c = k[ix];
                bool desc = ((i & ksz) == 0);
                if (desc ? (a < c) : (a > c)) { k[i] = c; k[ix] = a; }
            }
            __syncthreads();
        }
    }
    #pragma unroll
    for (int s = 0; s < 4; s++) keys[base + tid + s*256] = k[tid + s*256];
}

// ---------------- merge pass, tile-parallel: fixed 2048-output tiles, merge-path ----------------
// desc runs, distinct keys. grid = B_*L_/2048 blocks per pass regardless of run size.
#define MT 2048
__global__ __launch_bounds__(256) void merge_kernel(
    const unsigned long long* __restrict__ src, unsigned long long* __restrict__ dst, int run)
{
    const size_t tile = blockIdx.x;
    const size_t pairSpan = (size_t)2 * run;
    const size_t p = tile * MT / pairSpan;
    const int o = (int)(tile * MT % pairSpan);
    const unsigned long long* A  = src + p * pairSpan;
    const unsigned long long* Bv = A + run;
    unsigned long long* D = dst + p * pairSpan;

    int q0 = o + threadIdx.x * (MT/256);       // 8 outputs per thread
    int lo = (q0 > run) ? (q0 - run) : 0;
    int hi = (q0 < run) ? q0 : run;
    while (lo < hi) {
        int mid = (lo + hi) >> 1;
        if (A[mid] >= Bv[q0 - 1 - mid]) lo = mid + 1; else hi = mid;
    }
    int a = lo, bq = q0 - lo;
    #pragma unroll
    for (int q = 0; q < MT/256; q++) {
        unsigned long long va = (a < run) ? A[a] : 0ULL;
        unsigned long long vb = (bq < run) ? Bv[bq] : 0ULL;
        bool takeA = (bq >= run) || ((a < run) && (va > vb));
        D[q0 + q] = takeA ? va : vb;
        if (takeA) a++; else bq++;
    }
}

// ---------------- emit top-KTOP indices per batch ----------------
__global__ void emit_idx_kernel(const unsigned long long* __restrict__ kw, int* __restrict__ idxo)
{
    int b = blockIdx.x;
    for (int t = threadIdx.x; t < KTOP; t += blockDim.x)
        idxo[b*KTOP + t] = (int)(0xFFFFFFFFu - (unsigned)(kw[(size_t)b*L_ + t] & 0xFFFFFFFFu));
}

// ---------------- y: tiled over 32 consecutive t with 51-row LDS window ----------------
#define TT 32
__global__ __launch_bounds__(256) void y_kernel(const float* __restrict__ xp,
    const int* __restrict__ idx, const float* __restrict__ conv_w,
    const float* __restrict__ cf, float* __restrict__ y)
{
    __shared__ float rows[(TT + JT - 1) * C_];   // 51 rows x 1KB = 51KB
    const int b = blockIdx.y;
    const int t0 = blockIdx.x * TT;
    const int tid = threadIdx.x;
    const int c4 = (tid & 63) * 4;
    const int tg = tid >> 6;
    const int* idxb = idx + b*KTOP;

    for (int s = tid; s < (TT + JT - 1) * 64; s += 256) {
        int r = s >> 6, cq = (s & 63) * 4;
        int gi = t0 - (JT - 1) + r;
        float4 v = make_float4(0.f, 0.f, 0.f, 0.f);
        if (gi >= 0 && gi < KTOP) {
            int l = idxb[gi];
            v = *(const float4*)&xp[((size_t)b*L_ + l)*C_ + cq];
        }
        *(float4*)&rows[r*C_ + cq] = v;
    }
    float4 cfr[JT];
    #pragma unroll
    for (int j = 0; j < JT; j++) cfr[j] = *(const float4*)&cf[j*C_ + c4];
    float4 cw = *(const float4*)&conv_w[c4];
    __syncthreads();

    #pragma unroll
    for (int u = 0; u < TT/4; u++) {
        int tl = tg + u*4;
        int t = t0 + tl;
        if (t < KTOP) {
            float4 acc = make_float4(0.f, 0.f, 0.f, 0.f);
            #pragma unroll
            for (int j = 0; j < JT; j++) {
                const float4 v = *(const float4*)&rows[(tl + JT - 1 - j)*C_ + c4];
                acc.x = fmaf(cfr[j].x, v.x, acc.x);
                acc.y = fmaf(cfr[j].y, v.y, acc.y);
                acc.z = fmaf(cfr[j].z, v.z, acc.z);
                acc.w = fmaf(cfr[j].w, v.w, acc.w);
            }
            acc.x *= cw.x; acc.y *= cw.y; acc.z *= cw.z; acc.w *= cw.w;
            *(float4*)&y[((size_t)b*KTOP + t)*C_ + c4] = acc;
        }
    }
}

// ---------------- residual copy ----------------
__global__ void copy_kernel(const float4* __restrict__ src, float4* __restrict__ dst)
{
    size_t n4 = (size_t)M1*C_/4;
    for (size_t i = (size_t)blockIdx.x*blockDim.x + threadIdx.x; i < n4;
         i += (size_t)gridDim.x*blockDim.x)
        dst[i] = src[i];
}

// ---------------- GEMM2 + scatter epilogue: out[b,l,:] = x[b,l,:] + y@WoT + bo ----------------
__global__ __launch_bounds__(256, 2) void gemm2_kernel(
    const float* __restrict__ y, const float* __restrict__ WoT,
    const float* __restrict__ bo, const float* __restrict__ x,
    const int* __restrict__ idx, float* __restrict__ out0)
{
    __shared__ float As[32*132];
    __shared__ float Bs[32*256];
    const int tid = threadIdx.x;
    const int tn2 = tid & 31;
    const int tm2 = tid >> 5;
    const int m0 = blockIdx.x * 128;

    float acc[16][8];
    #pragma unroll
    for (int i = 0; i < 16; i++)
        #pragma unroll
        for (int j = 0; j < 8; j++) acc[i][j] = 0.f;

    for (int k0 = 0; k0 < C_; k0 += 32) {
        #pragma unroll
        for (int it = 0; it < 4; it++) {
            int i2 = tid + it*256;
            int ar = i2 >> 3;
            int ak = (i2 & 7) * 4;
            int m = m0 + ar;
            float4 v = (m < M2) ? *(const float4*)&y[(size_t)m*C_ + k0 + ak]
                                : make_float4(0.f, 0.f, 0.f, 0.f);
            As[(ak+0)*132 + ar] = v.x;
            As[(ak+1)*132 + ar] = v.y;
            As[(ak+2)*132 + ar] = v.z;
            As[(ak+3)*132 + ar] = v.w;
        }
        #pragma unroll
        for (int it = 0; it < 8; it++) {
            int i2 = tid + it*256;
            int br = i2 >> 6;
            int bc = (i2 & 63) * 4;
            *(float4*)&Bs[br*256 + bc] = *(const float4*)&WoT[(size_t)(k0 + br)*C_ + bc];
        }
        __syncthreads();
        #pragma unroll 2
        for (int kk = 0; kk < 32; kk++) {
            float a[16];
            *(float4*)&a[0]  = *(const float4*)&As[kk*132 + tm2*16];
            *(float4*)&a[4]  = *(const float4*)&As[kk*132 + tm2*16 + 4];
            *(float4*)&a[8]  = *(const float4*)&As[kk*132 + tm2*16 + 8];
            *(float4*)&a[12] = *(const float4*)&As[kk*132 + tm2*16 + 12];
            float4 b0 = *(const float4*)&Bs[kk*256 + tn2*4];
            float4 b1 = *(const float4*)&Bs[kk*256 + tn2*4 + 128];
            #pragma unroll
            for (int i = 0; i < 16; i++) {
                acc[i][0] = fmaf(a[i], b0.x, acc[i][0]);
                acc[i][1] = fmaf(a[i], b0.y, acc[i][1]);
                acc[i][2] = fmaf(a[i], b0.z, acc[i][2]);
                acc[i][3] = fmaf(a[i], b0.w, acc[i][3]);
                acc[i][4] = fmaf(a[i], b1.x, acc[i][4]);
                acc[i][5] = fmaf(a[i], b1.y, acc[i][5]);
                acc[i][6] = fmaf(a[i], b1.z, acc[i][6]);
                acc[i][7] = fmaf(a[i], b1.w, acc[i][7]);
            }
        }
        __syncthreads();
    }
    float4 bo0 = *(const float4*)&bo[tn2*4];
    float4 bo1 = *(const float4*)&bo[tn2*4 + 128];
    #pragma unroll
    for (int i = 0; i < 16; i++) {
        int m = m0 + tm2*16 + i;
        if (m < M2) {
            int b = m / KTOP, t = m - b*KTOP;
            int l = idx[b*KTOP + t];
            size_t base = ((size_t)b*L_ + l)*C_;
            float4 x0 = *(const float4*)&x[base + tn2*4];
            float4 x1 = *(const float4*)&x[base + tn2*4 + 128];
            float4 o0 = make_float4(acc[i][0]+bo0.x+x0.x, acc[i][1]+bo0.y+x0.y,
                                    acc[i][2]+bo0.z+x0.z, acc[i][3]+bo0.w+x0.w);
            float4 o1 = make_float4(acc[i][4]+bo1.x+x1.x, acc[i][5]+bo1.y+x1.y,
                                    acc[i][6]+bo1.z+x1.z, acc[i][7]+bo1.w+x1.w);
            *(float4*)&out0[base + tn2*4]       = o0;
            *(float4*)&out0[base + tn2*4 + 128] = o1;
        }
    }
}

extern "C" void kernel_launch(void* const* d_in, const int* in_sizes, int n_in,
                              void* d_out, int out_size, void* d_ws, size_t ws_size,
                              hipStream_t stream)
{
    const float* x      = (const float*)d_in[0];
    const float* alpha  = (const float*)d_in[1];
    const float* dyt_w  = (const float*)d_in[2];
    const float* dyt_b  = (const float*)d_in[3];
    const float* Wi     = (const float*)d_in[4];
    const float* bi     = (const float*)d_in[5];
    const float* conv_w = (const float*)d_in[6];
    const float* A      = (const float*)d_in[7];
    const float* Bp     = (const float*)d_in[8];
    const float* Cp     = (const float*)d_in[9];
    const float* Wo     = (const float*)d_in[10];
    const float* bo     = (const float*)d_in[11];

    float* ws  = (float*)d_ws;
    float* xp  = ws + XP_OFF;
    float* yb  = ws + Y_OFF;
    float* e   = ws + E_OFF;
    float* cn  = ws + CN_OFF;
    float* cf  = ws + CF_OFF;
    int*   idx = (int*)(ws + IDX_OFF);
    float* WiT = ws + WIT_OFF;
    float* WoT = ws + WOT_OFF;
    // key buffers alias yb (dead until y_kernel): 2 x 1MB
    unsigned long long* kw1 = (unsigned long long*)(ws + Y_OFF);
    unsigned long long* kw2 = kw1 + (size_t)B_*L_;

    float* out0 = (float*)d_out;
    float* sim  = out0 + (size_t)M1*C_;

    transpose_kernel<<<dim3(8,8,2), dim3(32,8), 0, stream>>>(Wi, Wo, WiT, WoT);
    coef_kernel<<<1, 256, 0, stream>>>(A, Bp, Cp, cf);
    center2_kernel<<<B_, 256, 0, stream>>>(x, WiT, bi, alpha, dyt_w, dyt_b, cn);
    gemm1_kernel<<<M1/128, 256, 0, stream>>>(x, WiT, bi, alpha, dyt_w, dyt_b, cn, xp, e);
    softmax_kernel<<<B_, 1024, 0, stream>>>(e, sim, kw1);
    sort1k_kernel<<<B_*L_/1024, 256, 0, stream>>>(kw1);
    merge_kernel<<<B_*L_/MT, 256, 0, stream>>>(kw1, kw2, 1024);
    merge_kernel<<<B_*L_/MT, 256, 0, stream>>>(kw2, kw1, 2048);
    merge_kernel<<<B_*L_/MT, 256, 0, stream>>>(kw1, kw2, 4096);
    emit_idx_kernel<<<B_, 256, 0, stream>>>(kw2, idx);
    y_kernel<<<dim3((KTOP + TT - 1)/TT, B_), 256, 0, stream>>>(xp, idx, conv_w, cf, yb);
    copy_kernel<<<2048, 256, 0, stream>>>((const float4*)x, (float4*)out0);
    gemm2_kernel<<<(M2 + 127)/128, 256, 0, stream>>>(yb, WoT, bo, x, idx, out0);
}

// Round 8
// 523.504 us; speedup vs baseline: 1.3393x; 1.2794x over previous
//
#include <hip/hip_runtime.h>
#include <math.h>

#define B_ 16
#define L_ 8192
#define C_ 256
#define KTOP 2457            // max(1, int(8192*0.3))
#define JT 20                // recurrence taps; ||A||^20 ~ 1e-16 -> exact at fp32
#define M1 (B_*L_)           // 131072
#define M2 (B_*KTOP)         // 39312

// workspace layout in floats
#define XP_OFF  ((size_t)0)
#define Y_OFF   (XP_OFF + (size_t)M1*C_)        // 33554432 (yb: M2*C_ floats)
#define CN_OFF  (Y_OFF  + (size_t)M2*C_)
#define CF_OFF  (CN_OFF + (size_t)B_*C_)
#define IDX_OFF (CF_OFF + (size_t)JT*C_)        // ints
#define WIT_OFF (IDX_OFF + (size_t)M2)
#define WOT_OFF (WIT_OFF + (size_t)C_*C_)
// Y region sub-lease (all die before y_kernel writes yb):
//   kw1 = Y_OFF..+262143 (131072 u64), kw2 next 262144 floats,
//   dtp = Y_OFF+524288 (2*M1 floats), ssp = Y_OFF+786432... see kernel_launch.

// ---------------- prep: transpose Wi/Wo + coef + center2, one launch ----------------
// blocks 0..127: transpose tiles; 128: coef; 129..144: center2 per batch (reads Wi directly).
__global__ __launch_bounds__(256) void prep_kernel(
    const float* __restrict__ Wi, const float* __restrict__ Wo,
    float* __restrict__ WiT, float* __restrict__ WoT,
    const float* __restrict__ A, const float* __restrict__ Bp, const float* __restrict__ Cp,
    float* __restrict__ cf,
    const float* __restrict__ x, const float* __restrict__ bi, const float* __restrict__ alpha,
    const float* __restrict__ dw, const float* __restrict__ db, float* __restrict__ cn)
{
    __shared__ float shm[1089];
    const int bid = blockIdx.x, tid = threadIdx.x;
    if (bid < 128) {
        // transpose 32x32 tile
        const int z = bid >> 6, rem = bid & 63;
        const int r0 = (rem >> 3) * 32, c0 = (rem & 7) * 32;
        const float* src = z ? Wo : Wi;
        float* dst = z ? WoT : WiT;
        float (*t)[33] = (float(*)[33])shm;
        int tx = tid & 31, ty = tid >> 5;
        #pragma unroll
        for (int r = 0; r < 4; r++)
            t[ty + r*8][tx] = src[(size_t)(r0 + ty + r*8)*C_ + c0 + tx];
        __syncthreads();
        #pragma unroll
        for (int r = 0; r < 4; r++)
            dst[(size_t)(c0 + ty + r*8)*C_ + r0 + tx] = t[tx][ty + r*8];
    } else if (bid == 128) {
        // coef
        int c = tid;
        float* As = shm;
        float* v0 = shm + 256;
        As[c] = A[c];
        if (c < 16) v0[c] = 1.0f / (1.0f + expf(-Bp[c]));
        float sC[16];
        #pragma unroll
        for (int i = 0; i < 16; i++) sC[i] = 1.0f / (1.0f + expf(-Cp[c*16 + i]));
        __syncthreads();
        float v[16];
        #pragma unroll
        for (int i = 0; i < 16; i++) v[i] = v0[i];
        for (int j = 0; j < JT; j++) {
            float d = 0.f;
            #pragma unroll
            for (int i = 0; i < 16; i++) d += sC[i] * v[i];
            cf[j*C_ + c] = d;
            float nv[16];
            #pragma unroll
            for (int i = 0; i < 16; i++) {
                float s = 0.f;
                #pragma unroll
                for (int m = 0; m < 16; m++) s += As[i*16 + m] * v[m];
                nv[i] = s;
            }
            #pragma unroll
            for (int i = 0; i < 16; i++) v[i] = nv[i];
        }
    } else {
        // center2 for batch bid-129: cn = normalize(dyt(x[b,L/2,:]) @ Wi^T_col + bi)
        int b = bid - 129, c = tid;
        float* xn = shm;
        float* red = shm + 256;
        float al = alpha[0];
        size_t base = ((size_t)b*L_ + L_/2)*C_;
        xn[c] = tanhf(al*x[base + c])*dw[c] + db[c];
        __syncthreads();
        float s = bi[c];
        #pragma unroll 8
        for (int k = 0; k < 256; k++) s = fmaf(xn[k], Wi[(size_t)c*C_ + k], s);
        float ss = s*s;
        #pragma unroll
        for (int off = 32; off; off >>= 1) ss += __shfl_xor(ss, off);
        if ((c & 63) == 0) red[c >> 6] = ss;
        __syncthreads();
        float tot = red[0] + red[1] + red[2] + red[3];
        float inv = 1.0f / fmaxf(sqrtf(tot), 1e-12f);
        cn[b*C_ + c] = s * inv;
    }
}

// ---------------- GEMM1: xp = dyt(x)@WiT + bi over a 128x128 tile; partial dt/ss ----------------
// BM=128, BN=128, BK=32, 256 threads, 8x8 micro-tile, double-buffered LDS (1 barrier/K-tile),
// T3-minimal pipeline: issue loads(t+1) -> compute(t) -> write LDS(t+1) -> barrier.
// Reg budget: acc 64 + prefetch 32 + frags 16 + addr ~24 = ~136 << 256 (no spill; canary=WRITE_SIZE).
__global__ __launch_bounds__(256, 2) void gemm1_kernel(
    const float* __restrict__ x, const float* __restrict__ WiT,
    const float* __restrict__ bi, const float* __restrict__ alpha,
    const float* __restrict__ dw, const float* __restrict__ db,
    const float* __restrict__ cn, float* __restrict__ xp,
    float* __restrict__ dtp, float* __restrict__ ssp)
{
    __shared__ float As[2][32*132];   // [kk][m] col-major padded
    __shared__ float Bs[2][32*128];   // [kk][n]
    const int tid = threadIdx.x;
    const int tm2 = tid >> 4;          // 0..15 -> rows tm2*8..+7
    const int tn2 = tid & 15;          // 0..15 -> cols tn2*4, +64
    const int m0 = blockIdx.x * 128;
    const int n0 = blockIdx.y * 128;
    const int b  = m0 >> 13;
    const float al = alpha[0];

    float acc[8][8];
    #pragma unroll
    for (int i = 0; i < 8; i++)
        #pragma unroll
        for (int j = 0; j < 8; j++) acc[i][j] = 0.f;

    float4 xa[4], wv[4];
    #pragma unroll
    for (int it = 0; it < 4; it++) {
        int i2 = tid + it*256;
        xa[it] = *(const float4*)&x[(size_t)(m0 + (i2>>3))*C_ + ((i2&7)*4)];
        wv[it] = *(const float4*)&WiT[(size_t)(i2>>5)*C_ + n0 + ((i2&31)*4)];
    }
    #pragma unroll
    for (int it = 0; it < 4; it++) {
        int i2 = tid + it*256;
        int ar = i2>>3, ak = (i2&7)*4;
        float4 v = xa[it];
        float4 w = *(const float4*)&dw[ak];
        float4 bb = *(const float4*)&db[ak];
        As[0][(ak+0)*132 + ar] = tanhf(al*v.x)*w.x + bb.x;
        As[0][(ak+1)*132 + ar] = tanhf(al*v.y)*w.y + bb.y;
        As[0][(ak+2)*132 + ar] = tanhf(al*v.z)*w.z + bb.z;
        As[0][(ak+3)*132 + ar] = tanhf(al*v.w)*w.w + bb.w;
        *(float4*)&Bs[0][(i2>>5)*128 + (i2&31)*4] = wv[it];
    }
    __syncthreads();
    int cur = 0;
    for (int k0 = 0; k0 < C_; k0 += 32) {
        if (k0 + 32 < C_) {
            #pragma unroll
            for (int it = 0; it < 4; it++) {
                int i2 = tid + it*256;
                xa[it] = *(const float4*)&x[(size_t)(m0 + (i2>>3))*C_ + k0 + 32 + ((i2&7)*4)];
                wv[it] = *(const float4*)&WiT[(size_t)(k0 + 32 + (i2>>5))*C_ + n0 + ((i2&31)*4)];
            }
        }
        #pragma unroll 2
        for (int kk = 0; kk < 32; kk++) {
            float a[8], bf[8];
            *(float4*)&a[0]  = *(const float4*)&As[cur][kk*132 + tm2*8];
            *(float4*)&a[4]  = *(const float4*)&As[cur][kk*132 + tm2*8 + 4];
            *(float4*)&bf[0] = *(const float4*)&Bs[cur][kk*128 + tn2*4];
            *(float4*)&bf[4] = *(const float4*)&Bs[cur][kk*128 + tn2*4 + 64];
            #pragma unroll
            for (int i = 0; i < 8; i++)
                #pragma unroll
                for (int j = 0; j < 8; j++)
                    acc[i][j] = fmaf(a[i], bf[j], acc[i][j]);
        }
        if (k0 + 32 < C_) {
            int nxt = cur ^ 1;
            #pragma unroll
            for (int it = 0; it < 4; it++) {
                int i2 = tid + it*256;
                int ar = i2>>3, ak = (i2&7)*4;
                float4 v = xa[it];
                float4 w = *(const float4*)&dw[k0 + 32 + ak];
                float4 bb = *(const float4*)&db[k0 + 32 + ak];
                As[nxt][(ak+0)*132 + ar] = tanhf(al*v.x)*w.x + bb.x;
                As[nxt][(ak+1)*132 + ar] = tanhf(al*v.y)*w.y + bb.y;
                As[nxt][(ak+2)*132 + ar] = tanhf(al*v.z)*w.z + bb.z;
                As[nxt][(ak+3)*132 + ar] = tanhf(al*v.w)*w.w + bb.w;
                *(float4*)&Bs[nxt][(i2>>5)*128 + (i2&31)*4] = wv[it];
            }
            cur = nxt;
        }
        __syncthreads();
    }
    float4 bi0 = *(const float4*)&bi[n0 + tn2*4];
    float4 bi1 = *(const float4*)&bi[n0 + 64 + tn2*4];
    float4 c0  = *(const float4*)&cn[b*C_ + n0 + tn2*4];
    float4 c1  = *(const float4*)&cn[b*C_ + n0 + 64 + tn2*4];
    #pragma unroll
    for (int i = 0; i < 8; i++) {
        size_t row = m0 + tm2*8 + i;
        float4 o0 = make_float4(acc[i][0]+bi0.x, acc[i][1]+bi0.y, acc[i][2]+bi0.z, acc[i][3]+bi0.w);
        float4 o1 = make_float4(acc[i][4]+bi1.x, acc[i][5]+bi1.y, acc[i][6]+bi1.z, acc[i][7]+bi1.w);
        *(float4*)&xp[row*C_ + n0 + tn2*4]      = o0;
        *(float4*)&xp[row*C_ + n0 + 64 + tn2*4] = o1;
        float dt = o0.x*c0.x + o0.y*c0.y + o0.z*c0.z + o0.w*c0.w
                 + o1.x*c1.x + o1.y*c1.y + o1.z*c1.z + o1.w*c1.w;
        float ss = o0.x*o0.x + o0.y*o0.y + o0.z*o0.z + o0.w*o0.w
                 + o1.x*o1.x + o1.y*o1.y + o1.z*o1.z + o1.w*o1.w;
        #pragma unroll
        for (int off = 8; off; off >>= 1) {
            dt += __shfl_xor(dt, off);
            ss += __shfl_xor(ss, off);
        }
        if (tn2 == 0) {
            dtp[(size_t)blockIdx.y*M1 + row] = dt;
            ssp[(size_t)blockIdx.y*M1 + row] = ss;
        }
    }
}

// ---------------- softmax per batch (e recombined from partials); emit sim + u64 keys ----------------
__global__ __launch_bounds__(1024) void softmax_kernel(
    const float* __restrict__ dtp, const float* __restrict__ ssp,
    float* __restrict__ sim, unsigned long long* __restrict__ kw)
{
    __shared__ float scratch[32];
    const int b = blockIdx.x, tid = threadIdx.x;
    const int lane = tid & 63, wid = tid >> 6; // 16 waves
    float ev[8];
    #pragma unroll
    for (int s = 0; s < 8; s++) {
        size_t m = (size_t)b*L_ + tid + s*1024;
        float dt = dtp[m] + dtp[M1 + m];
        float ssv = ssp[m] + ssp[M1 + m];
        ev[s] = dt / fmaxf(sqrtf(ssv), 1e-12f);
    }
    float mx = ev[0];
    #pragma unroll
    for (int s = 1; s < 8; s++) mx = fmaxf(mx, ev[s]);
    #pragma unroll
    for (int off = 32; off; off >>= 1) mx = fmaxf(mx, __shfl_xor(mx, off));
    if (lane == 0) scratch[wid] = mx;
    __syncthreads();
    if (tid == 0) {
        float m2 = scratch[0];
        for (int i = 1; i < 16; i++) m2 = fmaxf(m2, scratch[i]);
        scratch[20] = m2;
    }
    __syncthreads();
    mx = scratch[20];
    float pv[8], sum = 0.f;
    #pragma unroll
    for (int s = 0; s < 8; s++) { pv[s] = expf(ev[s] - mx); sum += pv[s]; }
    #pragma unroll
    for (int off = 32; off; off >>= 1) sum += __shfl_xor(sum, off);
    __syncthreads();
    if (lane == 0) scratch[wid] = sum;
    __syncthreads();
    if (tid == 0) {
        float s2 = 0.f;
        for (int i = 0; i < 16; i++) s2 += scratch[i];
        scratch[21] = s2;
    }
    __syncthreads();
    float inv = 1.0f / scratch[21];
    #pragma unroll
    for (int s = 0; s < 8; s++) {
        int l = tid + s*1024;
        float sm = pv[s] * inv;
        sim[(size_t)b*L_ + l] = sm;
        kw[(size_t)b*L_ + l] =
            ((unsigned long long)__float_as_uint(sm) << 32) | (unsigned)(0xFFFFFFFFu - l);
    }
}

// ---------------- sort 1024-element chunks descending (bitonic in LDS) ----------------
__global__ __launch_bounds__(256) void sort1k_kernel(unsigned long long* __restrict__ keys)
{
    __shared__ unsigned long long k[1024];
    size_t base = (size_t)blockIdx.x * 1024;
    int tid = threadIdx.x;
    #pragma unroll
    for (int s = 0; s < 4; s++) k[tid + s*256] = keys[base + tid + s*256];
    __syncthreads();
    for (int ksz = 2; ksz <= 1024; ksz <<= 1) {
        for (int j = ksz >> 1; j > 0; j >>= 1) {
            #pragma unroll
            for (int s = 0; s < 2; s++) {
                int p = tid + s*256;                       // pair 0..511
                int i = ((p & ~(j-1)) << 1) | (p & (j-1)); // bit j clear
                int ix = i | j;
                unsigned long long a = k[i], c = k[ix];
                bool desc = ((i & ksz) == 0);
                if (desc ? (a < c) : (a > c)) { k[i] = c; k[ix] = a; }
            }
            __syncthreads();
        }
    }
    #pragma unroll
    for (int s = 0; s < 4; s++) keys[base + tid + s*256] = k[tid + s*256];
}

// ---------------- merge pass, tile-parallel: fixed 2048-output tiles, merge-path ----------------
#define MT 2048
__global__ __launch_bounds__(256) void merge_kernel(
    const unsigned long long* __restrict__ src, unsigned long long* __restrict__ dst, int run)
{
    const size_t tile = blockIdx.x;
    const size_t pairSpan = (size_t)2 * run;
    const size_t p = tile * MT / pairSpan;
    const int o = (int)(tile * MT % pairSpan);
    const unsigned long long* A  = src + p * pairSpan;
    const unsigned long long* Bv = A + run;
    unsigned long long* D = dst + p * pairSpan;

    int q0 = o + threadIdx.x * (MT/256);       // 8 outputs per thread
    int lo = (q0 > run) ? (q0 - run) : 0;
    int hi = (q0 < run) ? q0 : run;
    while (lo < hi) {
        int mid = (lo + hi) >> 1;
        if (A[mid] >= Bv[q0 - 1 - mid]) lo = mid + 1; else hi = mid;
    }
    int a = lo, bq = q0 - lo;
    #pragma unroll
    for (int q = 0; q < MT/256; q++) {
        unsigned long long va = (a < run) ? A[a] : 0ULL;
        unsigned long long vb = (bq < run) ? Bv[bq] : 0ULL;
        bool takeA = (bq >= run) || ((a < run) && (va > vb));
        D[q0 + q] = takeA ? va : vb;
        if (takeA) a++; else bq++;
    }
}

// ---------------- final merge (runs of 4096) producing only top-KTOP indices ----------------
// 2 tiles per batch (positions 0..4095 >= KTOP=2457); writes idx directly, no key output.
__global__ __launch_bounds__(256) void merge_top_kernel(
    const unsigned long long* __restrict__ src, int* __restrict__ idxo)
{
    const int tile = blockIdx.x;               // 0..31
    const int p = tile >> 1;                   // batch
    const int o = (tile & 1) * MT;             // 0 or 2048
    const int run = 4096;
    const unsigned long long* A  = src + (size_t)p * L_;
    const unsigned long long* Bv = A + run;

    int q0 = o + threadIdx.x * (MT/256);
    int lo = (q0 > run) ? (q0 - run) : 0;
    int hi = (q0 < run) ? q0 : run;
    while (lo < hi) {
        int mid = (lo + hi) >> 1;
        if (A[mid] >= Bv[q0 - 1 - mid]) lo = mid + 1; else hi = mid;
    }
    int a = lo, bq = q0 - lo;
    #pragma unroll
    for (int q = 0; q < MT/256; q++) {
        unsigned long long va = (a < run) ? A[a] : 0ULL;
        unsigned long long vb = (bq < run) ? Bv[bq] : 0ULL;
        bool takeA = (bq >= run) || ((a < run) && (va > vb));
        unsigned long long v = takeA ? va : vb;
        if (q0 + q < KTOP)
            idxo[p*KTOP + q0 + q] = (int)(0xFFFFFFFFu - (unsigned)(v & 0xFFFFFFFFu));
        if (takeA) a++; else bq++;
    }
}

// ---------------- y: tiled over 32 consecutive t with 51-row LDS window ----------------
#define TT 32
__global__ __launch_bounds__(256) void y_kernel(const float* __restrict__ xp,
    const int* __restrict__ idx, const float* __restrict__ conv_w,
    const float* __restrict__ cf, float* __restrict__ y)
{
    __shared__ float rows[(TT + JT - 1) * C_];   // 51 rows x 1KB = 51KB
    const int b = blockIdx.y;
    const int t0 = blockIdx.x * TT;
    const int tid = threadIdx.x;
    const int c4 = (tid & 63) * 4;
    const int tg = tid >> 6;
    const int* idxb = idx + b*KTOP;

    for (int s = tid; s < (TT + JT - 1) * 64; s += 256) {
        int r = s >> 6, cq = (s & 63) * 4;
        int gi = t0 - (JT - 1) + r;
        float4 v = make_float4(0.f, 0.f, 0.f, 0.f);
        if (gi >= 0 && gi < KTOP) {
            int l = idxb[gi];
            v = *(const float4*)&xp[((size_t)b*L_ + l)*C_ + cq];
        }
        *(float4*)&rows[r*C_ + cq] = v;
    }
    float4 cfr[JT];
    #pragma unroll
    for (int j = 0; j < JT; j++) cfr[j] = *(const float4*)&cf[j*C_ + c4];
    float4 cw = *(const float4*)&conv_w[c4];
    __syncthreads();

    #pragma unroll
    for (int u = 0; u < TT/4; u++) {
        int tl = tg + u*4;
        int t = t0 + tl;
        if (t < KTOP) {
            float4 acc = make_float4(0.f, 0.f, 0.f, 0.f);
            #pragma unroll
            for (int j = 0; j < JT; j++) {
                const float4 v = *(const float4*)&rows[(tl + JT - 1 - j)*C_ + c4];
                acc.x = fmaf(cfr[j].x, v.x, acc.x);
                acc.y = fmaf(cfr[j].y, v.y, acc.y);
                acc.z = fmaf(cfr[j].z, v.z, acc.z);
                acc.w = fmaf(cfr[j].w, v.w, acc.w);
            }
            acc.x *= cw.x; acc.y *= cw.y; acc.z *= cw.z; acc.w *= cw.w;
            *(float4*)&y[((size_t)b*KTOP + t)*C_ + c4] = acc;
        }
    }
}

// ---------------- residual copy ----------------
__global__ void copy_kernel(const float4* __restrict__ src, float4* __restrict__ dst)
{
    size_t n4 = (size_t)M1*C_/4;
    for (size_t i = (size_t)blockIdx.x*blockDim.x + threadIdx.x; i < n4;
         i += (size_t)gridDim.x*blockDim.x)
        dst[i] = src[i];
}

// ---------------- GEMM2 + scatter epilogue over 128x128 tiles ----------------
__global__ __launch_bounds__(256, 2) void gemm2_kernel(
    const float* __restrict__ y, const float* __restrict__ WoT,
    const float* __restrict__ bo, const float* __restrict__ x,
    const int* __restrict__ idx, float* __restrict__ out0)
{
    __shared__ float As[2][32*132];
    __shared__ float Bs[2][32*128];
    const int tid = threadIdx.x;
    const int tm2 = tid >> 4;
    const int tn2 = tid & 15;
    const int m0 = blockIdx.x * 128;
    const int n0 = blockIdx.y * 128;

    float acc[8][8];
    #pragma unroll
    for (int i = 0; i < 8; i++)
        #pragma unroll
        for (int j = 0; j < 8; j++) acc[i][j] = 0.f;

    float4 xa[4], wv[4];
    #pragma unroll
    for (int it = 0; it < 4; it++) {
        int i2 = tid + it*256;
        int m = m0 + (i2>>3);
        xa[it] = (m < M2) ? *(const float4*)&y[(size_t)m*C_ + ((i2&7)*4)]
                          : make_float4(0.f, 0.f, 0.f, 0.f);
        wv[it] = *(const float4*)&WoT[(size_t)(i2>>5)*C_ + n0 + ((i2&31)*4)];
    }
    #pragma unroll
    for (int it = 0; it < 4; it++) {
        int i2 = tid + it*256;
        int ar = i2>>3, ak = (i2&7)*4;
        float4 v = xa[it];
        As[0][(ak+0)*132 + ar] = v.x;
        As[0][(ak+1)*132 + ar] = v.y;
        As[0][(ak+2)*132 + ar] = v.z;
        As[0][(ak+3)*132 + ar] = v.w;
        *(float4*)&Bs[0][(i2>>5)*128 + (i2&31)*4] = wv[it];
    }
    __syncthreads();
    int cur = 0;
    for (int k0 = 0; k0 < C_; k0 += 32) {
        if (k0 + 32 < C_) {
            #pragma unroll
            for (int it = 0; it < 4; it++) {
                int i2 = tid + it*256;
                int m = m0 + (i2>>3);
                xa[it] = (m < M2) ? *(const float4*)&y[(size_t)m*C_ + k0 + 32 + ((i2&7)*4)]
                                  : make_float4(0.f, 0.f, 0.f, 0.f);
                wv[it] = *(const float4*)&WoT[(size_t)(k0 + 32 + (i2>>5))*C_ + n0 + ((i2&31)*4)];
            }
        }
        #pragma unroll 2
        for (int kk = 0; kk < 32; kk++) {
            float a[8], bf[8];
            *(float4*)&a[0]  = *(const float4*)&As[cur][kk*132 + tm2*8];
            *(float4*)&a[4]  = *(const float4*)&As[cur][kk*132 + tm2*8 + 4];
            *(float4*)&bf[0] = *(const float4*)&Bs[cur][kk*128 + tn2*4];
            *(float4*)&bf[4] = *(const float4*)&Bs[cur][kk*128 + tn2*4 + 64];
            #pragma unroll
            for (int i = 0; i < 8; i++)
                #pragma unroll
                for (int j = 0; j < 8; j++)
                    acc[i][j] = fmaf(a[i], bf[j], acc[i][j]);
        }
        if (k0 + 32 < C_) {
            int nxt = cur ^ 1;
            #pragma unroll
            for (int it = 0; it < 4; it++) {
                int i2 = tid + it*256;
                int ar = i2>>3, ak = (i2&7)*4;
                float4 v = xa[it];
                As[nxt][(ak+0)*132 + ar] = v.x;
                As[nxt][(ak+1)*132 + ar] = v.y;
                As[nxt][(ak+2)*132 + ar] = v.z;
                As[nxt][(ak+3)*132 + ar] = v.w;
                *(float4*)&Bs[nxt][(i2>>5)*128 + (i2&31)*4] = wv[it];
            }
            cur = nxt;
        }
        __syncthreads();
    }
    float4 bo0 = *(const float4*)&bo[n0 + tn2*4];
    float4 bo1 = *(const float4*)&bo[n0 + 64 + tn2*4];
    #pragma unroll
    for (int i = 0; i < 8; i++) {
        int m = m0 + tm2*8 + i;
        if (m < M2) {
            int b = m / KTOP, t = m - b*KTOP;
            int l = idx[b*KTOP + t];
            size_t base = ((size_t)b*L_ + l)*C_;
            float4 x0 = *(const float4*)&x[base + n0 + tn2*4];
            float4 x1 = *(const float4*)&x[base + n0 + 64 + tn2*4];
            float4 o0 = make_float4(acc[i][0]+bo0.x+x0.x, acc[i][1]+bo0.y+x0.y,
                                    acc[i][2]+bo0.z+x0.z, acc[i][3]+bo0.w+x0.w);
            float4 o1 = make_float4(acc[i][4]+bo1.x+x1.x, acc[i][5]+bo1.y+x1.y,
                                    acc[i][6]+bo1.z+x1.z, acc[i][7]+bo1.w+x1.w);
            *(float4*)&out0[base + n0 + tn2*4]      = o0;
            *(float4*)&out0[base + n0 + 64 + tn2*4] = o1;
        }
    }
}

extern "C" void kernel_launch(void* const* d_in, const int* in_sizes, int n_in,
                              void* d_out, int out_size, void* d_ws, size_t ws_size,
                              hipStream_t stream)
{
    const float* x      = (const float*)d_in[0];
    const float* alpha  = (const float*)d_in[1];
    const float* dyt_w  = (const float*)d_in[2];
    const float* dyt_b  = (const float*)d_in[3];
    const float* Wi     = (const float*)d_in[4];
    const float* bi     = (const float*)d_in[5];
    const float* conv_w = (const float*)d_in[6];
    const float* A      = (const float*)d_in[7];
    const float* Bp     = (const float*)d_in[8];
    const float* Cp     = (const float*)d_in[9];
    const float* Wo     = (const float*)d_in[10];
    const float* bo     = (const float*)d_in[11];

    float* ws  = (float*)d_ws;
    float* xp  = ws + XP_OFF;
    float* yb  = ws + Y_OFF;
    float* cn  = ws + CN_OFF;
    float* cf  = ws + CF_OFF;
    int*   idx = (int*)(ws + IDX_OFF);
    float* WiT = ws + WIT_OFF;
    float* WoT = ws + WOT_OFF;
    // Y-region sub-lease (all dead before y_kernel writes yb):
    unsigned long long* kw1 = (unsigned long long*)(ws + Y_OFF);   // 131072 u64
    unsigned long long* kw2 = kw1 + (size_t)B_*L_;                 // 131072 u64
    float* dtp = ws + Y_OFF + 524288;                              // 2*M1 floats
    float* ssp = dtp + (size_t)2*M1;                               // 2*M1 floats

    float* out0 = (float*)d_out;
    float* sim  = out0 + (size_t)M1*C_;

    prep_kernel<<<145, 256, 0, stream>>>(Wi, Wo, WiT, WoT, A, Bp, Cp, cf,
                                         x, bi, alpha, dyt_w, dyt_b, cn);
    gemm1_kernel<<<dim3(M1/128, 2), 256, 0, stream>>>(x, WiT, bi, alpha, dyt_w, dyt_b,
                                                      cn, xp, dtp, ssp);
    softmax_kernel<<<B_, 1024, 0, stream>>>(dtp, ssp, sim, kw1);
    sort1k_kernel<<<B_*L_/1024, 256, 0, stream>>>(kw1);
    merge_kernel<<<B_*L_/MT, 256, 0, stream>>>(kw1, kw2, 1024);
    merge_kernel<<<B_*L_/MT, 256, 0, stream>>>(kw2, kw1, 2048);
    merge_top_kernel<<<B_*2, 256, 0, stream>>>(kw1, idx);
    y_kernel<<<dim3((KTOP + TT - 1)/TT, B_), 256, 0, stream>>>(xp, idx, conv_w, cf, yb);
    copy_kernel<<<2048, 256, 0, stream>>>((const float4*)x, (float4*)out0);
    gemm2_kernel<<<dim3((M2 + 127)/128, 2), 256, 0, stream>>>(yb, WoT, bo, x, idx, out0);
}

// Round 9
// 459.101 us; speedup vs baseline: 1.5271x; 1.1403x over previous
//
#include <hip/hip_runtime.h>
#include <math.h>

#define B_ 16
#define L_ 8192
#define C_ 256
#define KTOP 2457            // max(1, int(8192*0.3))
#define JT 20                // recurrence taps; ||A||^20 ~ 1e-16 -> exact at fp32
#define M1 (B_*L_)           // 131072
#define M2 (B_*KTOP)         // 39312

// workspace layout in floats
#define XP_OFF  ((size_t)0)
#define Y_OFF   (XP_OFF + (size_t)M1*C_)        // yb: M2*C_ floats
#define CN_OFF  (Y_OFF  + (size_t)M2*C_)
#define CF_OFF  (CN_OFF + (size_t)B_*C_)
#define IDX_OFF (CF_OFF + (size_t)JT*C_)        // ints
#define WIT_OFF (IDX_OFF + (size_t)M2)
#define WOT_OFF (WIT_OFF + (size_t)C_*C_)
// Y region sub-lease (all die before y_kernel writes yb):
//   kw1 = Y_OFF (131072 u64 = 262144 f), kw2 = +262144 f, e = +524288 (M1 f)

// async global->LDS, 16B per lane, wave-uniform LDS base (m97 pattern)
__device__ __forceinline__ void async_copy16(const float* g, float* l) {
    __builtin_amdgcn_global_load_lds(
        (const __attribute__((address_space(1))) void*)g,
        (__attribute__((address_space(3))) void*)l, 16, 0, 0);
}

// ---------------- prep: transpose Wi/Wo + coef + center2, one launch ----------------
__global__ __launch_bounds__(256) void prep_kernel(
    const float* __restrict__ Wi, const float* __restrict__ Wo,
    float* __restrict__ WiT, float* __restrict__ WoT,
    const float* __restrict__ A, const float* __restrict__ Bp, const float* __restrict__ Cp,
    float* __restrict__ cf,
    const float* __restrict__ x, const float* __restrict__ bi, const float* __restrict__ alpha,
    const float* __restrict__ dw, const float* __restrict__ db, float* __restrict__ cn)
{
    __shared__ float shm[1089];
    const int bid = blockIdx.x, tid = threadIdx.x;
    if (bid < 128) {
        const int z = bid >> 6, rem = bid & 63;
        const int r0 = (rem >> 3) * 32, c0 = (rem & 7) * 32;
        const float* src = z ? Wo : Wi;
        float* dst = z ? WoT : WiT;
        float (*t)[33] = (float(*)[33])shm;
        int tx = tid & 31, ty = tid >> 5;
        #pragma unroll
        for (int r = 0; r < 4; r++)
            t[ty + r*8][tx] = src[(size_t)(r0 + ty + r*8)*C_ + c0 + tx];
        __syncthreads();
        #pragma unroll
        for (int r = 0; r < 4; r++)
            dst[(size_t)(c0 + ty + r*8)*C_ + r0 + tx] = t[tx][ty + r*8];
    } else if (bid == 128) {
        int c = tid;
        float* As = shm;
        float* v0 = shm + 256;
        As[c] = A[c];
        if (c < 16) v0[c] = 1.0f / (1.0f + expf(-Bp[c]));
        float sC[16];
        #pragma unroll
        for (int i = 0; i < 16; i++) sC[i] = 1.0f / (1.0f + expf(-Cp[c*16 + i]));
        __syncthreads();
        float v[16];
        #pragma unroll
        for (int i = 0; i < 16; i++) v[i] = v0[i];
        for (int j = 0; j < JT; j++) {
            float d = 0.f;
            #pragma unroll
            for (int i = 0; i < 16; i++) d += sC[i] * v[i];
            cf[j*C_ + c] = d;
            float nv[16];
            #pragma unroll
            for (int i = 0; i < 16; i++) {
                float s = 0.f;
                #pragma unroll
                for (int m = 0; m < 16; m++) s += As[i*16 + m] * v[m];
                nv[i] = s;
            }
            #pragma unroll
            for (int i = 0; i < 16; i++) v[i] = nv[i];
        }
    } else {
        int b = bid - 129, c = tid;
        float* xn = shm;
        float* red = shm + 256;
        float al = alpha[0];
        size_t base = ((size_t)b*L_ + L_/2)*C_;
        xn[c] = tanhf(al*x[base + c])*dw[c] + db[c];
        __syncthreads();
        float s = bi[c];
        #pragma unroll 8
        for (int k = 0; k < 256; k++) s = fmaf(xn[k], Wi[(size_t)c*C_ + k], s);
        float ss = s*s;
        #pragma unroll
        for (int off = 32; off; off >>= 1) ss += __shfl_xor(ss, off);
        if ((c & 63) == 0) red[c >> 6] = ss;
        __syncthreads();
        float tot = red[0] + red[1] + red[2] + red[3];
        float inv = 1.0f / fmaxf(sqrtf(tot), 1e-12f);
        cn[b*C_ + c] = s * inv;
    }
}

// ---------------- GEMM1 + fused e: xp = dyt(x)@WiT + bi ; e[m] = xp.cn/||xp|| ----------------
// Round-7 proven shape: BM=128, BN=256(full), BK=32, 16x8 micro-tile, single-buffered.
// As[32][132] col-major padded: A-frag = 4x ds_read_b128 broadcast. B staged via
// global_load_lds (wave-uniform row base + lane*16B): no VGPR round-trip, copies in
// flight during A's load+tanh. Canary: WRITE_SIZE ~135MB (spill shows as +100s of MB).
__global__ __launch_bounds__(256, 2) void gemm1_kernel(
    const float* __restrict__ x, const float* __restrict__ WiT,
    const float* __restrict__ bi, const float* __restrict__ alpha,
    const float* __restrict__ dw, const float* __restrict__ db,
    const float* __restrict__ cn, float* __restrict__ xp, float* __restrict__ e)
{
    __shared__ float As[32*132];   // [kk][m], pad 132 keeps 16B align
    __shared__ float Bs[32*256];   // [kk][n], 1KB rows
    const int tid = threadIdx.x;
    const int lane = tid & 63;
    const int wv = tid >> 6;       // 0..3
    const int tn2 = tid & 31;      // cols tn2*4..+3 and 128+tn2*4..+3
    const int tm2 = tid >> 5;      // rows tm2*16..+15
    const int m0 = blockIdx.x * 128;
    const int b  = m0 >> 13;
    const float al = alpha[0];

    float acc[16][8];
    #pragma unroll
    for (int i = 0; i < 16; i++)
        #pragma unroll
        for (int j = 0; j < 8; j++) acc[i][j] = 0.f;

    for (int k0 = 0; k0 < C_; k0 += 32) {
        // B stage: 8 async copies, one 1KB Bs row per wave per it (in flight during A work)
        #pragma unroll
        for (int it = 0; it < 8; it++) {
            int br = wv + it*4;    // wave-uniform
            async_copy16(&WiT[(size_t)(k0 + br)*C_ + lane*4], &Bs[br*256]);
        }
        // A stage: 128x32 tile, dyt transform, transpose into col-major As
        #pragma unroll
        for (int it = 0; it < 4; it++) {
            int i2 = tid + it*256;
            int ar = i2 >> 3;              // row 0..127
            int ak = (i2 & 7) * 4;         // k 0,4,..,28
            float4 v  = *(const float4*)&x[(size_t)(m0 + ar)*C_ + k0 + ak];
            float4 w4 = *(const float4*)&dw[k0 + ak];
            float4 b4 = *(const float4*)&db[k0 + ak];
            As[(ak+0)*132 + ar] = tanhf(al*v.x)*w4.x + b4.x;
            As[(ak+1)*132 + ar] = tanhf(al*v.y)*w4.y + b4.y;
            As[(ak+2)*132 + ar] = tanhf(al*v.z)*w4.z + b4.z;
            As[(ak+3)*132 + ar] = tanhf(al*v.w)*w4.w + b4.w;
        }
        __syncthreads();                   // drains vmcnt (async B) + lgkm (A writes)
        #pragma unroll 2
        for (int kk = 0; kk < 32; kk++) {
            float a[16];
            *(float4*)&a[0]  = *(const float4*)&As[kk*132 + tm2*16];
            *(float4*)&a[4]  = *(const float4*)&As[kk*132 + tm2*16 + 4];
            *(float4*)&a[8]  = *(const float4*)&As[kk*132 + tm2*16 + 8];
            *(float4*)&a[12] = *(const float4*)&As[kk*132 + tm2*16 + 12];
            float4 b0 = *(const float4*)&Bs[kk*256 + tn2*4];
            float4 b1 = *(const float4*)&Bs[kk*256 + tn2*4 + 128];
            #pragma unroll
            for (int i = 0; i < 16; i++) {
                acc[i][0] = fmaf(a[i], b0.x, acc[i][0]);
                acc[i][1] = fmaf(a[i], b0.y, acc[i][1]);
                acc[i][2] = fmaf(a[i], b0.z, acc[i][2]);
                acc[i][3] = fmaf(a[i], b0.w, acc[i][3]);
                acc[i][4] = fmaf(a[i], b1.x, acc[i][4]);
                acc[i][5] = fmaf(a[i], b1.y, acc[i][5]);
                acc[i][6] = fmaf(a[i], b1.z, acc[i][6]);
                acc[i][7] = fmaf(a[i], b1.w, acc[i][7]);
            }
        }
        __syncthreads();
    }
    float4 bi0 = *(const float4*)&bi[tn2*4];
    float4 bi1 = *(const float4*)&bi[tn2*4 + 128];
    float4 c0  = *(const float4*)&cn[b*C_ + tn2*4];
    float4 c1  = *(const float4*)&cn[b*C_ + tn2*4 + 128];
    #pragma unroll
    for (int i = 0; i < 16; i++) {
        size_t row = m0 + tm2*16 + i;
        float4 o0 = make_float4(acc[i][0]+bi0.x, acc[i][1]+bi0.y, acc[i][2]+bi0.z, acc[i][3]+bi0.w);
        float4 o1 = make_float4(acc[i][4]+bi1.x, acc[i][5]+bi1.y, acc[i][6]+bi1.z, acc[i][7]+bi1.w);
        *(float4*)&xp[row*C_ + tn2*4]       = o0;
        *(float4*)&xp[row*C_ + tn2*4 + 128] = o1;
        float dt = o0.x*c0.x + o0.y*c0.y + o0.z*c0.z + o0.w*c0.w
                 + o1.x*c1.x + o1.y*c1.y + o1.z*c1.z + o1.w*c1.w;
        float ss = o0.x*o0.x + o0.y*o0.y + o0.z*o0.z + o0.w*o0.w
                 + o1.x*o1.x + o1.y*o1.y + o1.z*o1.z + o1.w*o1.w;
        #pragma unroll
        for (int off = 16; off; off >>= 1) {
            dt += __shfl_xor(dt, off);
            ss += __shfl_xor(ss, off);
        }
        if (tn2 == 0) e[row] = dt / fmaxf(sqrtf(ss), 1e-12f);
    }
}

// ---------------- softmax per batch; emit sim + u64 keys (sim desc, idx asc) ----------------
__global__ __launch_bounds__(1024) void softmax_kernel(
    const float* __restrict__ e, float* __restrict__ sim, unsigned long long* __restrict__ kw)
{
    __shared__ float scratch[32];
    const int b = blockIdx.x, tid = threadIdx.x;
    const int lane = tid & 63, wid = tid >> 6; // 16 waves
    const float* eb = e + (size_t)b*L_;
    float ev[8];
    #pragma unroll
    for (int s = 0; s < 8; s++) ev[s] = eb[tid + s*1024];
    float mx = ev[0];
    #pragma unroll
    for (int s = 1; s < 8; s++) mx = fmaxf(mx, ev[s]);
    #pragma unroll
    for (int off = 32; off; off >>= 1) mx = fmaxf(mx, __shfl_xor(mx, off));
    if (lane == 0) scratch[wid] = mx;
    __syncthreads();
    if (tid == 0) {
        float m2 = scratch[0];
        for (int i = 1; i < 16; i++) m2 = fmaxf(m2, scratch[i]);
        scratch[20] = m2;
    }
    __syncthreads();
    mx = scratch[20];
    float pv[8], sum = 0.f;
    #pragma unroll
    for (int s = 0; s < 8; s++) { pv[s] = expf(ev[s] - mx); sum += pv[s]; }
    #pragma unroll
    for (int off = 32; off; off >>= 1) sum += __shfl_xor(sum, off);
    __syncthreads();
    if (lane == 0) scratch[wid] = sum;
    __syncthreads();
    if (tid == 0) {
        float s2 = 0.f;
        for (int i = 0; i < 16; i++) s2 += scratch[i];
        scratch[21] = s2;
    }
    __syncthreads();
    float inv = 1.0f / scratch[21];
    #pragma unroll
    for (int s = 0; s < 8; s++) {
        int l = tid + s*1024;
        float sm = pv[s] * inv;
        sim[(size_t)b*L_ + l] = sm;
        kw[(size_t)b*L_ + l] =
            ((unsigned long long)__float_as_uint(sm) << 32) | (unsigned)(0xFFFFFFFFu - l);
    }
}

// ---------------- sort 1024-element chunks descending (bitonic in LDS) ----------------
__global__ __launch_bounds__(256) void sort1k_kernel(unsigned long long* __restrict__ keys)
{
    __shared__ unsigned long long k[1024];
    size_t base = (size_t)blockIdx.x * 1024;
    int tid = threadIdx.x;
    #pragma unroll
    for (int s = 0; s < 4; s++) k[tid + s*256] = keys[base + tid + s*256];
    __syncthreads();
    for (int ksz = 2; ksz <= 1024; ksz <<= 1) {
        for (int j = ksz >> 1; j > 0; j >>= 1) {
            #pragma unroll
            for (int s = 0; s < 2; s++) {
                int p = tid + s*256;
                int i = ((p & ~(j-1)) << 1) | (p & (j-1));
                int ix = i | j;
                unsigned long long a = k[i], c = k[ix];
                bool desc = ((i & ksz) == 0);
                if (desc ? (a < c) : (a > c)) { k[i] = c; k[ix] = a; }
            }
            __syncthreads();
        }
    }
    #pragma unroll
    for (int s = 0; s < 4; s++) keys[base + tid + s*256] = k[tid + s*256];
}

// ---------------- merge pass, tile-parallel: fixed 2048-output tiles, merge-path ----------------
#define MT 2048
__global__ __launch_bounds__(256) void merge_kernel(
    const unsigned long long* __restrict__ src, unsigned long long* __restrict__ dst, int run)
{
    const size_t tile = blockIdx.x;
    const size_t pairSpan = (size_t)2 * run;
    const size_t p = tile * MT / pairSpan;
    const int o = (int)(tile * MT % pairSpan);
    const unsigned long long* A  = src + p * pairSpan;
    const unsigned long long* Bv = A + run;
    unsigned long long* D = dst + p * pairSpan;

    int q0 = o + threadIdx.x * (MT/256);
    int lo = (q0 > run) ? (q0 - run) : 0;
    int hi = (q0 < run) ? q0 : run;
    while (lo < hi) {
        int mid = (lo + hi) >> 1;
        if (A[mid] >= Bv[q0 - 1 - mid]) lo = mid + 1; else hi = mid;
    }
    int a = lo, bq = q0 - lo;
    #pragma unroll
    for (int q = 0; q < MT/256; q++) {
        unsigned long long va = (a < run) ? A[a] : 0ULL;
        unsigned long long vb = (bq < run) ? Bv[bq] : 0ULL;
        bool takeA = (bq >= run) || ((a < run) && (va > vb));
        D[q0 + q] = takeA ? va : vb;
        if (takeA) a++; else bq++;
    }
}

// ---------------- final merge (runs of 4096) producing only top-KTOP indices ----------------
__global__ __launch_bounds__(256) void merge_top_kernel(
    const unsigned long long* __restrict__ src, int* __restrict__ idxo)
{
    const int tile = blockIdx.x;               // 0..31
    const int p = tile >> 1;
    const int o = (tile & 1) * MT;
    const int run = 4096;
    const unsigned long long* A  = src + (size_t)p * L_;
    const unsigned long long* Bv = A + run;

    int q0 = o + threadIdx.x * (MT/256);
    int lo = (q0 > run) ? (q0 - run) : 0;
    int hi = (q0 < run) ? q0 : run;
    while (lo < hi) {
        int mid = (lo + hi) >> 1;
        if (A[mid] >= Bv[q0 - 1 - mid]) lo = mid + 1; else hi = mid;
    }
    int a = lo, bq = q0 - lo;
    #pragma unroll
    for (int q = 0; q < MT/256; q++) {
        unsigned long long va = (a < run) ? A[a] : 0ULL;
        unsigned long long vb = (bq < run) ? Bv[bq] : 0ULL;
        bool takeA = (bq >= run) || ((a < run) && (va > vb));
        unsigned long long v = takeA ? va : vb;
        if (q0 + q < KTOP)
            idxo[p*KTOP + q0 + q] = (int)(0xFFFFFFFFu - (unsigned)(v & 0xFFFFFFFFu));
        if (takeA) a++; else bq++;
    }
}

// ---------------- y: tiled over 32 consecutive t with 51-row LDS window ----------------
#define TT 32
__global__ __launch_bounds__(256) void y_kernel(const float* __restrict__ xp,
    const int* __restrict__ idx, const float* __restrict__ conv_w,
    const float* __restrict__ cf, float* __restrict__ y)
{
    __shared__ float rows[(TT + JT - 1) * C_];   // 51 rows x 1KB = 51KB
    const int b = blockIdx.y;
    const int t0 = blockIdx.x * TT;
    const int tid = threadIdx.x;
    const int c4 = (tid & 63) * 4;
    const int tg = tid >> 6;
    const int* idxb = idx + b*KTOP;

    for (int s = tid; s < (TT + JT - 1) * 64; s += 256) {
        int r = s >> 6, cq = (s & 63) * 4;
        int gi = t0 - (JT - 1) + r;
        float4 v = make_float4(0.f, 0.f, 0.f, 0.f);
        if (gi >= 0 && gi < KTOP) {
            int l = idxb[gi];
            v = *(const float4*)&xp[((size_t)b*L_ + l)*C_ + cq];
        }
        *(float4*)&rows[r*C_ + cq] = v;
    }
    float4 cfr[JT];
    #pragma unroll
    for (int j = 0; j < JT; j++) cfr[j] = *(const float4*)&cf[j*C_ + c4];
    float4 cw = *(const float4*)&conv_w[c4];
    __syncthreads();

    #pragma unroll
    for (int u = 0; u < TT/4; u++) {
        int tl = tg + u*4;
        int t = t0 + tl;
        if (t < KTOP) {
            float4 acc = make_float4(0.f, 0.f, 0.f, 0.f);
            #pragma unroll
            for (int j = 0; j < JT; j++) {
                const float4 v = *(const float4*)&rows[(tl + JT - 1 - j)*C_ + c4];
                acc.x = fmaf(cfr[j].x, v.x, acc.x);
                acc.y = fmaf(cfr[j].y, v.y, acc.y);
                acc.z = fmaf(cfr[j].z, v.z, acc.z);
                acc.w = fmaf(cfr[j].w, v.w, acc.w);
            }
            acc.x *= cw.x; acc.y *= cw.y; acc.z *= cw.z; acc.w *= cw.w;
            *(float4*)&y[((size_t)b*KTOP + t)*C_ + c4] = acc;
        }
    }
}

// ---------------- residual copy ----------------
__global__ void copy_kernel(const float4* __restrict__ src, float4* __restrict__ dst)
{
    size_t n4 = (size_t)M1*C_/4;
    for (size_t i = (size_t)blockIdx.x*blockDim.x + threadIdx.x; i < n4;
         i += (size_t)gridDim.x*blockDim.x)
        dst[i] = src[i];
}

// ---------------- GEMM2 + scatter epilogue over 128x128 tiles ----------------
// Double-buffered; A (y) reg-prefetch (proven no-spill at 88 VGPR); B (WoT) async
// global_load_lds into the nxt buffer issued BEFORE compute -> loads in flight under FMA.
__global__ __launch_bounds__(256, 2) void gemm2_kernel(
    const float* __restrict__ y, const float* __restrict__ WoT,
    const float* __restrict__ bo, const float* __restrict__ x,
    const int* __restrict__ idx, float* __restrict__ out0)
{
    __shared__ float As[2][32*132];
    __shared__ float Bs[2][32*128];   // 512B rows; wave covers 1KB = 2 rows
    const int tid = threadIdx.x;
    const int lane = tid & 63;
    const int wv = tid >> 6;
    const int tm2 = tid >> 4;
    const int tn2 = tid & 15;
    const int m0 = blockIdx.x * 128;
    const int n0 = blockIdx.y * 128;

    float acc[8][8];
    #pragma unroll
    for (int i = 0; i < 8; i++)
        #pragma unroll
        for (int j = 0; j < 8; j++) acc[i][j] = 0.f;

    float4 xa[4];
    #pragma unroll
    for (int it = 0; it < 4; it++) {
        int i2 = tid + it*256;
        int m = m0 + (i2>>3);
        xa[it] = (m < M2) ? *(const float4*)&y[(size_t)m*C_ + ((i2&7)*4)]
                          : make_float4(0.f, 0.f, 0.f, 0.f);
    }
    // B(k0=0) async into Bs[0]: wave w, it 0..3 -> rows 2w+it*8, 2w+it*8+1 (1KB contiguous)
    #pragma unroll
    for (int it = 0; it < 4; it++) {
        int brow = 2*wv + it*8;
        async_copy16(&WoT[(size_t)(brow + (lane>>5))*C_ + n0 + (lane&31)*4],
                     &Bs[0][brow*128]);
    }
    #pragma unroll
    for (int it = 0; it < 4; it++) {
        int i2 = tid + it*256;
        int ar = i2>>3, ak = (i2&7)*4;
        float4 v = xa[it];
        As[0][(ak+0)*132 + ar] = v.x;
        As[0][(ak+1)*132 + ar] = v.y;
        As[0][(ak+2)*132 + ar] = v.z;
        As[0][(ak+3)*132 + ar] = v.w;
    }
    __syncthreads();
    int cur = 0;
    for (int k0 = 0; k0 < C_; k0 += 32) {
        if (k0 + 32 < C_) {
            int nxt = cur ^ 1;
            // async B(k0+32) into nxt buffer: flies during compute below
            #pragma unroll
            for (int it = 0; it < 4; it++) {
                int brow = 2*wv + it*8;
                async_copy16(&WoT[(size_t)(k0 + 32 + brow + (lane>>5))*C_ + n0 + (lane&31)*4],
                             &Bs[nxt][brow*128]);
            }
            #pragma unroll
            for (int it = 0; it < 4; it++) {
                int i2 = tid + it*256;
                int m = m0 + (i2>>3);
                xa[it] = (m < M2) ? *(const float4*)&y[(size_t)m*C_ + k0 + 32 + ((i2&7)*4)]
                                  : make_float4(0.f, 0.f, 0.f, 0.f);
            }
        }
        #pragma unroll 2
        for (int kk = 0; kk < 32; kk++) {
            float a[8], bf[8];
            *(float4*)&a[0]  = *(const float4*)&As[cur][kk*132 + tm2*8];
            *(float4*)&a[4]  = *(const float4*)&As[cur][kk*132 + tm2*8 + 4];
            *(float4*)&bf[0] = *(const float4*)&Bs[cur][kk*128 + tn2*4];
            *(float4*)&bf[4] = *(const float4*)&Bs[cur][kk*128 + tn2*4 + 64];
            #pragma unroll
            for (int i = 0; i < 8; i++)
                #pragma unroll
                for (int j = 0; j < 8; j++)
                    acc[i][j] = fmaf(a[i], bf[j], acc[i][j]);
        }
        if (k0 + 32 < C_) {
            int nxt = cur ^ 1;
            #pragma unroll
            for (int it = 0; it < 4; it++) {
                int i2 = tid + it*256;
                int ar = i2>>3, ak = (i2&7)*4;
                float4 v = xa[it];
                As[nxt][(ak+0)*132 + ar] = v.x;
                As[nxt][(ak+1)*132 + ar] = v.y;
                As[nxt][(ak+2)*132 + ar] = v.z;
                As[nxt][(ak+3)*132 + ar] = v.w;
            }
            cur = nxt;
        }
        __syncthreads();
    }
    float4 bo0 = *(const float4*)&bo[n0 + tn2*4];
    float4 bo1 = *(const float4*)&bo[n0 + 64 + tn2*4];
    #pragma unroll
    for (int i = 0; i < 8; i++) {
        int m = m0 + tm2*8 + i;
        if (m < M2) {
            int b = m / KTOP, t = m - b*KTOP;
            int l = idx[b*KTOP + t];
            size_t base = ((size_t)b*L_ + l)*C_;
            float4 x0 = *(const float4*)&x[base + n0 + tn2*4];
            float4 x1 = *(const float4*)&x[base + n0 + 64 + tn2*4];
            float4 o0 = make_float4(acc[i][0]+bo0.x+x0.x, acc[i][1]+bo0.y+x0.y,
                                    acc[i][2]+bo0.z+x0.z, acc[i][3]+bo0.w+x0.w);
            float4 o1 = make_float4(acc[i][4]+bo1.x+x1.x, acc[i][5]+bo1.y+x1.y,
                                    acc[i][6]+bo1.z+x1.z, acc[i][7]+bo1.w+x1.w);
            *(float4*)&out0[base + n0 + tn2*4]      = o0;
            *(float4*)&out0[base + n0 + 64 + tn2*4] = o1;
        }
    }
}

extern "C" void kernel_launch(void* const* d_in, const int* in_sizes, int n_in,
                              void* d_out, int out_size, void* d_ws, size_t ws_size,
                              hipStream_t stream)
{
    const float* x      = (const float*)d_in[0];
    const float* alpha  = (const float*)d_in[1];
    const float* dyt_w  = (const float*)d_in[2];
    const float* dyt_b  = (const float*)d_in[3];
    const float* Wi     = (const float*)d_in[4];
    const float* bi     = (const float*)d_in[5];
    const float* conv_w = (const float*)d_in[6];
    const float* A      = (const float*)d_in[7];
    const float* Bp     = (const float*)d_in[8];
    const float* Cp     = (const float*)d_in[9];
    const float* Wo     = (const float*)d_in[10];
    const float* bo     = (const float*)d_in[11];

    float* ws  = (float*)d_ws;
    float* xp  = ws + XP_OFF;
    float* yb  = ws + Y_OFF;
    float* cn  = ws + CN_OFF;
    float* cf  = ws + CF_OFF;
    int*   idx = (int*)(ws + IDX_OFF);
    float* WiT = ws + WIT_OFF;
    float* WoT = ws + WOT_OFF;
    // Y-region sub-lease (all dead before y_kernel writes yb):
    unsigned long long* kw1 = (unsigned long long*)(ws + Y_OFF);   // 131072 u64
    unsigned long long* kw2 = kw1 + (size_t)B_*L_;                 // 131072 u64
    float* e = ws + Y_OFF + 524288;                                // M1 floats

    float* out0 = (float*)d_out;
    float* sim  = out0 + (size_t)M1*C_;

    prep_kernel<<<145, 256, 0, stream>>>(Wi, Wo, WiT, WoT, A, Bp, Cp, cf,
                                         x, bi, alpha, dyt_w, dyt_b, cn);
    gemm1_kernel<<<M1/128, 256, 0, stream>>>(x, WiT, bi, alpha, dyt_w, dyt_b, cn, xp, e);
    softmax_kernel<<<B_, 1024, 0, stream>>>(e, sim, kw1);
    sort1k_kernel<<<B_*L_/1024, 256, 0, stream>>>(kw1);
    merge_kernel<<<B_*L_/MT, 256, 0, stream>>>(kw1, kw2, 1024);
    merge_kernel<<<B_*L_/MT, 256, 0, stream>>>(kw2, kw1, 2048);
    merge_top_kernel<<<B_*2, 256, 0, stream>>>(kw1, idx);
    y_kernel<<<dim3((KTOP + TT - 1)/TT, B_), 256, 0, stream>>>(xp, idx, conv_w, cf, yb);
    copy_kernel<<<2048, 256, 0, stream>>>((const float4*)x, (float4*)out0);
    gemm2_kernel<<<dim3((M2 + 127)/128, 2), 256, 0, stream>>>(yb, WoT, bo, x, idx, out0);
}

// Round 10
// 450.693 us; speedup vs baseline: 1.5556x; 1.0187x over previous
//
#include <hip/hip_runtime.h>
#include <math.h>

#define B_ 16
#define L_ 8192
#define C_ 256
#define KTOP 2457            // max(1, int(8192*0.3))
#define JT 20                // recurrence taps; ||A||^20 ~ 1e-16 -> exact at fp32
#define M1 (B_*L_)           // 131072
#define M2 (B_*KTOP)         // 39312

// workspace layout in floats
#define XP_OFF  ((size_t)0)
#define Y_OFF   (XP_OFF + (size_t)M1*C_)        // yb: M2*C_ floats
#define CN_OFF  (Y_OFF  + (size_t)M2*C_)
#define CF_OFF  (CN_OFF + (size_t)B_*C_)
#define IDX_OFF (CF_OFF + (size_t)JT*C_)        // ints
#define WIT_OFF (IDX_OFF + (size_t)M2)
#define WOT_OFF (WIT_OFF + (size_t)C_*C_)
// Y region sub-lease (all die before y_kernel writes yb):
//   kw1 = Y_OFF (131072 u64 = 262144 f), kw2 = +262144 f, e = +524288 (M1 f)

// async global->LDS, 16B per lane, wave-uniform LDS base (m97 pattern)
__device__ __forceinline__ void async_copy16(const float* g, float* l) {
    __builtin_amdgcn_global_load_lds(
        (const __attribute__((address_space(1))) void*)g,
        (__attribute__((address_space(3))) void*)l, 16, 0, 0);
}

// ---------------- prep: transpose Wi/Wo + coef + center2, one launch ----------------
__global__ __launch_bounds__(256) void prep_kernel(
    const float* __restrict__ Wi, const float* __restrict__ Wo,
    float* __restrict__ WiT, float* __restrict__ WoT,
    const float* __restrict__ A, const float* __restrict__ Bp, const float* __restrict__ Cp,
    float* __restrict__ cf,
    const float* __restrict__ x, const float* __restrict__ bi, const float* __restrict__ alpha,
    const float* __restrict__ dw, const float* __restrict__ db, float* __restrict__ cn)
{
    __shared__ float shm[1089];
    const int bid = blockIdx.x, tid = threadIdx.x;
    if (bid < 128) {
        const int z = bid >> 6, rem = bid & 63;
        const int r0 = (rem >> 3) * 32, c0 = (rem & 7) * 32;
        const float* src = z ? Wo : Wi;
        float* dst = z ? WoT : WiT;
        float (*t)[33] = (float(*)[33])shm;
        int tx = tid & 31, ty = tid >> 5;
        #pragma unroll
        for (int r = 0; r < 4; r++)
            t[ty + r*8][tx] = src[(size_t)(r0 + ty + r*8)*C_ + c0 + tx];
        __syncthreads();
        #pragma unroll
        for (int r = 0; r < 4; r++)
            dst[(size_t)(c0 + ty + r*8)*C_ + r0 + tx] = t[tx][ty + r*8];
    } else if (bid == 128) {
        int c = tid;
        float* As = shm;
        float* v0 = shm + 256;
        As[c] = A[c];
        if (c < 16) v0[c] = 1.0f / (1.0f + expf(-Bp[c]));
        float sC[16];
        #pragma unroll
        for (int i = 0; i < 16; i++) sC[i] = 1.0f / (1.0f + expf(-Cp[c*16 + i]));
        __syncthreads();
        float v[16];
        #pragma unroll
        for (int i = 0; i < 16; i++) v[i] = v0[i];
        for (int j = 0; j < JT; j++) {
            float d = 0.f;
            #pragma unroll
            for (int i = 0; i < 16; i++) d += sC[i] * v[i];
            cf[j*C_ + c] = d;
            float nv[16];
            #pragma unroll
            for (int i = 0; i < 16; i++) {
                float s = 0.f;
                #pragma unroll
                for (int m = 0; m < 16; m++) s += As[i*16 + m] * v[m];
                nv[i] = s;
            }
            #pragma unroll
            for (int i = 0; i < 16; i++) v[i] = nv[i];
        }
    } else {
        int b = bid - 129, c = tid;
        float* xn = shm;
        float* red = shm + 256;
        float al = alpha[0];
        size_t base = ((size_t)b*L_ + L_/2)*C_;
        xn[c] = tanhf(al*x[base + c])*dw[c] + db[c];
        __syncthreads();
        float s = bi[c];
        #pragma unroll 8
        for (int k = 0; k < 256; k++) s = fmaf(xn[k], Wi[(size_t)c*C_ + k], s);
        float ss = s*s;
        #pragma unroll
        for (int off = 32; off; off >>= 1) ss += __shfl_xor(ss, off);
        if ((c & 63) == 0) red[c >> 6] = ss;
        __syncthreads();
        float tot = red[0] + red[1] + red[2] + red[3];
        float inv = 1.0f / fmaxf(sqrtf(tot), 1e-12f);
        cn[b*C_ + c] = s * inv;
    }
}

// ---------------- GEMM1 + fused e: xp = dyt(x)@WiT + bi ; e[m] = xp.cn/||xp|| ----------------
// BM=128, BN=256(full), BK=16, 16x8 micro-tile, DOUBLE-buffered (49.6KB total, same as r9).
// Per tile: async B(t+1)->Bs[nxt] + x(t+1)->regs issued BEFORE compute(t) (latency hides
// under 4096cy FMA); tanh+A-write after compute; ONE barrier per tile.
// No BN-split -> no duplicated A fetch/tanh (r8's failure mode). Canary: WRITE_SIZE ~131MB.
__global__ __launch_bounds__(256, 2) void gemm1_kernel(
    const float* __restrict__ x, const float* __restrict__ WiT,
    const float* __restrict__ bi, const float* __restrict__ alpha,
    const float* __restrict__ dw, const float* __restrict__ db,
    const float* __restrict__ cn, float* __restrict__ xp, float* __restrict__ e)
{
    __shared__ float As[2][16*132];   // [kk][m], pad 132 keeps 16B align
    __shared__ float Bs[2][16*256];   // [kk][n], 1KB rows
    const int tid = threadIdx.x;
    const int lane = tid & 63;
    const int wv = tid >> 6;       // 0..3
    const int tn2 = tid & 31;      // cols tn2*4..+3 and 128+tn2*4..+3
    const int tm2 = tid >> 5;      // rows tm2*16..+15
    const int m0 = blockIdx.x * 128;
    const int b  = m0 >> 13;
    const float al = alpha[0];
    const int ar = tid >> 2;             // A stage row 0..63 (+it*64)
    const int ak = (tid & 3) * 4;        // A stage k 0,4,8,12

    float acc[16][8];
    #pragma unroll
    for (int i = 0; i < 16; i++)
        #pragma unroll
        for (int j = 0; j < 8; j++) acc[i][j] = 0.f;

    // prologue: stage tile 0 into buffer 0
    #pragma unroll
    for (int it = 0; it < 4; it++)
        async_copy16(&WiT[(size_t)(wv + it*4)*C_ + lane*4], &Bs[0][(wv + it*4)*256]);
    {
        float4 w4 = *(const float4*)&dw[ak];
        float4 b4 = *(const float4*)&db[ak];
        #pragma unroll
        for (int it = 0; it < 2; it++) {
            int r = ar + it*64;
            float4 v = *(const float4*)&x[(size_t)(m0 + r)*C_ + ak];
            As[0][(ak+0)*132 + r] = tanhf(al*v.x)*w4.x + b4.x;
            As[0][(ak+1)*132 + r] = tanhf(al*v.y)*w4.y + b4.y;
            As[0][(ak+2)*132 + r] = tanhf(al*v.z)*w4.z + b4.z;
            As[0][(ak+3)*132 + r] = tanhf(al*v.w)*w4.w + b4.w;
        }
    }
    __syncthreads();
    int cur = 0;
    for (int t = 0; t < 16; t++) {
        const int k0 = t * 16;
        float4 xa0, xa1;
        if (t < 15) {
            int nxt = cur ^ 1;
            // async B(t+1) into nxt: flies during compute below
            #pragma unroll
            for (int it = 0; it < 4; it++)
                async_copy16(&WiT[(size_t)(k0 + 16 + wv + it*4)*C_ + lane*4],
                             &Bs[nxt][(wv + it*4)*256]);
            // x(t+1) into regs: latency hidden under compute
            xa0 = *(const float4*)&x[(size_t)(m0 + ar)*C_ + k0 + 16 + ak];
            xa1 = *(const float4*)&x[(size_t)(m0 + ar + 64)*C_ + k0 + 16 + ak];
        }
        #pragma unroll 2
        for (int kk = 0; kk < 16; kk++) {
            float a[16];
            *(float4*)&a[0]  = *(const float4*)&As[cur][kk*132 + tm2*16];
            *(float4*)&a[4]  = *(const float4*)&As[cur][kk*132 + tm2*16 + 4];
            *(float4*)&a[8]  = *(const float4*)&As[cur][kk*132 + tm2*16 + 8];
            *(float4*)&a[12] = *(const float4*)&As[cur][kk*132 + tm2*16 + 12];
            float4 b0 = *(const float4*)&Bs[cur][kk*256 + tn2*4];
            float4 b1 = *(const float4*)&Bs[cur][kk*256 + tn2*4 + 128];
            #pragma unroll
            for (int i = 0; i < 16; i++) {
                acc[i][0] = fmaf(a[i], b0.x, acc[i][0]);
                acc[i][1] = fmaf(a[i], b0.y, acc[i][1]);
                acc[i][2] = fmaf(a[i], b0.z, acc[i][2]);
                acc[i][3] = fmaf(a[i], b0.w, acc[i][3]);
                acc[i][4] = fmaf(a[i], b1.x, acc[i][4]);
                acc[i][5] = fmaf(a[i], b1.y, acc[i][5]);
                acc[i][6] = fmaf(a[i], b1.z, acc[i][6]);
                acc[i][7] = fmaf(a[i], b1.w, acc[i][7]);
            }
        }
        if (t < 15) {
            int nxt = cur ^ 1;
            float4 w4 = *(const float4*)&dw[k0 + 16 + ak];
            float4 b4 = *(const float4*)&db[k0 + 16 + ak];
            As[nxt][(ak+0)*132 + ar] = tanhf(al*xa0.x)*w4.x + b4.x;
            As[nxt][(ak+1)*132 + ar] = tanhf(al*xa0.y)*w4.y + b4.y;
            As[nxt][(ak+2)*132 + ar] = tanhf(al*xa0.z)*w4.z + b4.z;
            As[nxt][(ak+3)*132 + ar] = tanhf(al*xa0.w)*w4.w + b4.w;
            As[nxt][(ak+0)*132 + ar + 64] = tanhf(al*xa1.x)*w4.x + b4.x;
            As[nxt][(ak+1)*132 + ar + 64] = tanhf(al*xa1.y)*w4.y + b4.y;
            As[nxt][(ak+2)*132 + ar + 64] = tanhf(al*xa1.z)*w4.z + b4.z;
            As[nxt][(ak+3)*132 + ar + 64] = tanhf(al*xa1.w)*w4.w + b4.w;
            cur = nxt;
        }
        __syncthreads();
    }
    float4 bi0 = *(const float4*)&bi[tn2*4];
    float4 bi1 = *(const float4*)&bi[tn2*4 + 128];
    float4 c0  = *(const float4*)&cn[b*C_ + tn2*4];
    float4 c1  = *(const float4*)&cn[b*C_ + tn2*4 + 128];
    #pragma unroll
    for (int i = 0; i < 16; i++) {
        size_t row = m0 + tm2*16 + i;
        float4 o0 = make_float4(acc[i][0]+bi0.x, acc[i][1]+bi0.y, acc[i][2]+bi0.z, acc[i][3]+bi0.w);
        float4 o1 = make_float4(acc[i][4]+bi1.x, acc[i][5]+bi1.y, acc[i][6]+bi1.z, acc[i][7]+bi1.w);
        *(float4*)&xp[row*C_ + tn2*4]       = o0;
        *(float4*)&xp[row*C_ + tn2*4 + 128] = o1;
        float dt = o0.x*c0.x + o0.y*c0.y + o0.z*c0.z + o0.w*c0.w
                 + o1.x*c1.x + o1.y*c1.y + o1.z*c1.z + o1.w*c1.w;
        float ss = o0.x*o0.x + o0.y*o0.y + o0.z*o0.z + o0.w*o0.w
                 + o1.x*o1.x + o1.y*o1.y + o1.z*o1.z + o1.w*o1.w;
        #pragma unroll
        for (int off = 16; off; off >>= 1) {
            dt += __shfl_xor(dt, off);
            ss += __shfl_xor(ss, off);
        }
        if (tn2 == 0) e[row] = dt / fmaxf(sqrtf(ss), 1e-12f);
    }
}

// ---------------- softmax per batch; emit sim + u64 keys (sim desc, idx asc) ----------------
__global__ __launch_bounds__(1024) void softmax_kernel(
    const float* __restrict__ e, float* __restrict__ sim, unsigned long long* __restrict__ kw)
{
    __shared__ float scratch[32];
    const int b = blockIdx.x, tid = threadIdx.x;
    const int lane = tid & 63, wid = tid >> 6; // 16 waves
    const float* eb = e + (size_t)b*L_;
    float ev[8];
    #pragma unroll
    for (int s = 0; s < 8; s++) ev[s] = eb[tid + s*1024];
    float mx = ev[0];
    #pragma unroll
    for (int s = 1; s < 8; s++) mx = fmaxf(mx, ev[s]);
    #pragma unroll
    for (int off = 32; off; off >>= 1) mx = fmaxf(mx, __shfl_xor(mx, off));
    if (lane == 0) scratch[wid] = mx;
    __syncthreads();
    if (tid == 0) {
        float m2 = scratch[0];
        for (int i = 1; i < 16; i++) m2 = fmaxf(m2, scratch[i]);
        scratch[20] = m2;
    }
    __syncthreads();
    mx = scratch[20];
    float pv[8], sum = 0.f;
    #pragma unroll
    for (int s = 0; s < 8; s++) { pv[s] = expf(ev[s] - mx); sum += pv[s]; }
    #pragma unroll
    for (int off = 32; off; off >>= 1) sum += __shfl_xor(sum, off);
    __syncthreads();
    if (lane == 0) scratch[wid] = sum;
    __syncthreads();
    if (tid == 0) {
        float s2 = 0.f;
        for (int i = 0; i < 16; i++) s2 += scratch[i];
        scratch[21] = s2;
    }
    __syncthreads();
    float inv = 1.0f / scratch[21];
    #pragma unroll
    for (int s = 0; s < 8; s++) {
        int l = tid + s*1024;
        float sm = pv[s] * inv;
        sim[(size_t)b*L_ + l] = sm;
        kw[(size_t)b*L_ + l] =
            ((unsigned long long)__float_as_uint(sm) << 32) | (unsigned)(0xFFFFFFFFu - l);
    }
}

// ---------------- sort 1024-element chunks descending (bitonic in LDS) ----------------
__global__ __launch_bounds__(256) void sort1k_kernel(unsigned long long* __restrict__ keys)
{
    __shared__ unsigned long long k[1024];
    size_t base = (size_t)blockIdx.x * 1024;
    int tid = threadIdx.x;
    #pragma unroll
    for (int s = 0; s < 4; s++) k[tid + s*256] = keys[base + tid + s*256];
    __syncthreads();
    for (int ksz = 2; ksz <= 1024; ksz <<= 1) {
        for (int j = ksz >> 1; j > 0; j >>= 1) {
            #pragma unroll
            for (int s = 0; s < 2; s++) {
                int p = tid + s*256;
                int i = ((p & ~(j-1)) << 1) | (p & (j-1));
                int ix = i | j;
                unsigned long long a = k[i], c = k[ix];
                bool desc = ((i & ksz) == 0);
                if (desc ? (a < c) : (a > c)) { k[i] = c; k[ix] = a; }
            }
            __syncthreads();
        }
    }
    #pragma unroll
    for (int s = 0; s < 4; s++) keys[base + tid + s*256] = k[tid + s*256];
}

// ---------------- merge pass, tile-parallel: fixed 2048-output tiles, merge-path ----------------
#define MT 2048
__global__ __launch_bounds__(256) void merge_kernel(
    const unsigned long long* __restrict__ src, unsigned long long* __restrict__ dst, int run)
{
    const size_t tile = blockIdx.x;
    const size_t pairSpan = (size_t)2 * run;
    const size_t p = tile * MT / pairSpan;
    const int o = (int)(tile * MT % pairSpan);
    const unsigned long long* A  = src + p * pairSpan;
    const unsigned long long* Bv = A + run;
    unsigned long long* D = dst + p * pairSpan;

    int q0 = o + threadIdx.x * (MT/256);
    int lo = (q0 > run) ? (q0 - run) : 0;
    int hi = (q0 < run) ? q0 : run;
    while (lo < hi) {
        int mid = (lo + hi) >> 1;
        if (A[mid] >= Bv[q0 - 1 - mid]) lo = mid + 1; else hi = mid;
    }
    int a = lo, bq = q0 - lo;
    #pragma unroll
    for (int q = 0; q < MT/256; q++) {
        unsigned long long va = (a < run) ? A[a] : 0ULL;
        unsigned long long vb = (bq < run) ? Bv[bq] : 0ULL;
        bool takeA = (bq >= run) || ((a < run) && (va > vb));
        D[q0 + q] = takeA ? va : vb;
        if (takeA) a++; else bq++;
    }
}

// ---------------- final merge (runs of 4096) producing only top-KTOP indices ----------------
__global__ __launch_bounds__(256) void merge_top_kernel(
    const unsigned long long* __restrict__ src, int* __restrict__ idxo)
{
    const int tile = blockIdx.x;               // 0..31
    const int p = tile >> 1;
    const int o = (tile & 1) * MT;
    const int run = 4096;
    const unsigned long long* A  = src + (size_t)p * L_;
    const unsigned long long* Bv = A + run;

    int q0 = o + threadIdx.x * (MT/256);
    int lo = (q0 > run) ? (q0 - run) : 0;
    int hi = (q0 < run) ? q0 : run;
    while (lo < hi) {
        int mid = (lo + hi) >> 1;
        if (A[mid] >= Bv[q0 - 1 - mid]) lo = mid + 1; else hi = mid;
    }
    int a = lo, bq = q0 - lo;
    #pragma unroll
    for (int q = 0; q < MT/256; q++) {
        unsigned long long va = (a < run) ? A[a] : 0ULL;
        unsigned long long vb = (bq < run) ? Bv[bq] : 0ULL;
        bool takeA = (bq >= run) || ((a < run) && (va > vb));
        unsigned long long v = takeA ? va : vb;
        if (q0 + q < KTOP)
            idxo[p*KTOP + q0 + q] = (int)(0xFFFFFFFFu - (unsigned)(v & 0xFFFFFFFFu));
        if (takeA) a++; else bq++;
    }
}

// ---------------- y: tiled over 32 consecutive t with 51-row LDS window ----------------
#define TT 32
__global__ __launch_bounds__(256) void y_kernel(const float* __restrict__ xp,
    const int* __restrict__ idx, const float* __restrict__ conv_w,
    const float* __restrict__ cf, float* __restrict__ y)
{
    __shared__ float rows[(TT + JT - 1) * C_];   // 51 rows x 1KB = 51KB
    const int b = blockIdx.y;
    const int t0 = blockIdx.x * TT;
    const int tid = threadIdx.x;
    const int c4 = (tid & 63) * 4;
    const int tg = tid >> 6;
    const int* idxb = idx + b*KTOP;

    for (int s = tid; s < (TT + JT - 1) * 64; s += 256) {
        int r = s >> 6, cq = (s & 63) * 4;
        int gi = t0 - (JT - 1) + r;
        float4 v = make_float4(0.f, 0.f, 0.f, 0.f);
        if (gi >= 0 && gi < KTOP) {
            int l = idxb[gi];
            v = *(const float4*)&xp[((size_t)b*L_ + l)*C_ + cq];
        }
        *(float4*)&rows[r*C_ + cq] = v;
    }
    float4 cfr[JT];
    #pragma unroll
    for (int j = 0; j < JT; j++) cfr[j] = *(const float4*)&cf[j*C_ + c4];
    float4 cw = *(const float4*)&conv_w[c4];
    __syncthreads();

    #pragma unroll
    for (int u = 0; u < TT/4; u++) {
        int tl = tg + u*4;
        int t = t0 + tl;
        if (t < KTOP) {
            float4 acc = make_float4(0.f, 0.f, 0.f, 0.f);
            #pragma unroll
            for (int j = 0; j < JT; j++) {
                const float4 v = *(const float4*)&rows[(tl + JT - 1 - j)*C_ + c4];
                acc.x = fmaf(cfr[j].x, v.x, acc.x);
                acc.y = fmaf(cfr[j].y, v.y, acc.y);
                acc.z = fmaf(cfr[j].z, v.z, acc.z);
                acc.w = fmaf(cfr[j].w, v.w, acc.w);
            }
            acc.x *= cw.x; acc.y *= cw.y; acc.z *= cw.z; acc.w *= cw.w;
            *(float4*)&y[((size_t)b*KTOP + t)*C_ + c4] = acc;
        }
    }
}

// ---------------- residual copy ----------------
__global__ void copy_kernel(const float4* __restrict__ src, float4* __restrict__ dst)
{
    size_t n4 = (size_t)M1*C_/4;
    for (size_t i = (size_t)blockIdx.x*blockDim.x + threadIdx.x; i < n4;
         i += (size_t)gridDim.x*blockDim.x)
        dst[i] = src[i];
}

// ---------------- GEMM2 + scatter epilogue over 128x128 tiles ----------------
__global__ __launch_bounds__(256, 2) void gemm2_kernel(
    const float* __restrict__ y, const float* __restrict__ WoT,
    const float* __restrict__ bo, const float* __restrict__ x,
    const int* __restrict__ idx, float* __restrict__ out0)
{
    __shared__ float As[2][32*132];
    __shared__ float Bs[2][32*128];   // 512B rows; wave covers 1KB = 2 rows
    const int tid = threadIdx.x;
    const int lane = tid & 63;
    const int wv = tid >> 6;
    const int tm2 = tid >> 4;
    const int tn2 = tid & 15;
    const int m0 = blockIdx.x * 128;
    const int n0 = blockIdx.y * 128;

    float acc[8][8];
    #pragma unroll
    for (int i = 0; i < 8; i++)
        #pragma unroll
        for (int j = 0; j < 8; j++) acc[i][j] = 0.f;

    float4 xa[4];
    #pragma unroll
    for (int it = 0; it < 4; it++) {
        int i2 = tid + it*256;
        int m = m0 + (i2>>3);
        xa[it] = (m < M2) ? *(const float4*)&y[(size_t)m*C_ + ((i2&7)*4)]
                          : make_float4(0.f, 0.f, 0.f, 0.f);
    }
    #pragma unroll
    for (int it = 0; it < 4; it++) {
        int brow = 2*wv + it*8;
        async_copy16(&WoT[(size_t)(brow + (lane>>5))*C_ + n0 + (lane&31)*4],
                     &Bs[0][brow*128]);
    }
    #pragma unroll
    for (int it = 0; it < 4; it++) {
        int i2 = tid + it*256;
        int ar = i2>>3, ak = (i2&7)*4;
        float4 v = xa[it];
        As[0][(ak+0)*132 + ar] = v.x;
        As[0][(ak+1)*132 + ar] = v.y;
        As[0][(ak+2)*132 + ar] = v.z;
        As[0][(ak+3)*132 + ar] = v.w;
    }
    __syncthreads();
    int cur = 0;
    for (int k0 = 0; k0 < C_; k0 += 32) {
        if (k0 + 32 < C_) {
            int nxt = cur ^ 1;
            #pragma unroll
            for (int it = 0; it < 4; it++) {
                int brow = 2*wv + it*8;
                async_copy16(&WoT[(size_t)(k0 + 32 + brow + (lane>>5))*C_ + n0 + (lane&31)*4],
                             &Bs[nxt][brow*128]);
            }
            #pragma unroll
            for (int it = 0; it < 4; it++) {
                int i2 = tid + it*256;
                int m = m0 + (i2>>3);
                xa[it] = (m < M2) ? *(const float4*)&y[(size_t)m*C_ + k0 + 32 + ((i2&7)*4)]
                                  : make_float4(0.f, 0.f, 0.f, 0.f);
            }
        }
        #pragma unroll 2
        for (int kk = 0; kk < 32; kk++) {
            float a[8], bf[8];
            *(float4*)&a[0]  = *(const float4*)&As[cur][kk*132 + tm2*8];
            *(float4*)&a[4]  = *(const float4*)&As[cur][kk*132 + tm2*8 + 4];
            *(float4*)&bf[0] = *(const float4*)&Bs[cur][kk*128 + tn2*4];
            *(float4*)&bf[4] = *(const float4*)&Bs[cur][kk*128 + tn2*4 + 64];
            #pragma unroll
            for (int i = 0; i < 8; i++)
                #pragma unroll
                for (int j = 0; j < 8; j++)
                    acc[i][j] = fmaf(a[i], bf[j], acc[i][j]);
        }
        if (k0 + 32 < C_) {
            int nxt = cur ^ 1;
            #pragma unroll
            for (int it = 0; it < 4; it++) {
                int i2 = tid + it*256;
                int ar = i2>>3, ak = (i2&7)*4;
                float4 v = xa[it];
                As[nxt][(ak+0)*132 + ar] = v.x;
                As[nxt][(ak+1)*132 + ar] = v.y;
                As[nxt][(ak+2)*132 + ar] = v.z;
                As[nxt][(ak+3)*132 + ar] = v.w;
            }
            cur = nxt;
        }
        __syncthreads();
    }
    float4 bo0 = *(const float4*)&bo[n0 + tn2*4];
    float4 bo1 = *(const float4*)&bo[n0 + 64 + tn2*4];
    #pragma unroll
    for (int i = 0; i < 8; i++) {
        int m = m0 + tm2*8 + i;
        if (m < M2) {
            int b = m / KTOP, t = m - b*KTOP;
            int l = idx[b*KTOP + t];
            size_t base = ((size_t)b*L_ + l)*C_;
            float4 x0 = *(const float4*)&x[base + n0 + tn2*4];
            float4 x1 = *(const float4*)&x[base + n0 + 64 + tn2*4];
            float4 o0 = make_float4(acc[i][0]+bo0.x+x0.x, acc[i][1]+bo0.y+x0.y,
                                    acc[i][2]+bo0.z+x0.z, acc[i][3]+bo0.w+x0.w);
            float4 o1 = make_float4(acc[i][4]+bo1.x+x1.x, acc[i][5]+bo1.y+x1.y,
                                    acc[i][6]+bo1.z+x1.z, acc[i][7]+bo1.w+x1.w);
            *(float4*)&out0[base + n0 + tn2*4]      = o0;
            *(float4*)&out0[base + n0 + 64 + tn2*4] = o1;
        }
    }
}

extern "C" void kernel_launch(void* const* d_in, const int* in_sizes, int n_in,
                              void* d_out, int out_size, void* d_ws, size_t ws_size,
                              hipStream_t stream)
{
    const float* x      = (const float*)d_in[0];
    const float* alpha  = (const float*)d_in[1];
    const float* dyt_w  = (const float*)d_in[2];
    const float* dyt_b  = (const float*)d_in[3];
    const float* Wi     = (const float*)d_in[4];
    const float* bi     = (const float*)d_in[5];
    const float* conv_w = (const float*)d_in[6];
    const float* A      = (const float*)d_in[7];
    const float* Bp     = (const float*)d_in[8];
    const float* Cp     = (const float*)d_in[9];
    const float* Wo     = (const float*)d_in[10];
    const float* bo     = (const float*)d_in[11];

    float* ws  = (float*)d_ws;
    float* xp  = ws + XP_OFF;
    float* yb  = ws + Y_OFF;
    float* cn  = ws + CN_OFF;
    float* cf  = ws + CF_OFF;
    int*   idx = (int*)(ws + IDX_OFF);
    float* WiT = ws + WIT_OFF;
    float* WoT = ws + WOT_OFF;
    // Y-region sub-lease (all dead before y_kernel writes yb):
    unsigned long long* kw1 = (unsigned long long*)(ws + Y_OFF);   // 131072 u64
    unsigned long long* kw2 = kw1 + (size_t)B_*L_;                 // 131072 u64
    float* e = ws + Y_OFF + 524288;                                // M1 floats

    float* out0 = (float*)d_out;
    float* sim  = out0 + (size_t)M1*C_;

    prep_kernel<<<145, 256, 0, stream>>>(Wi, Wo, WiT, WoT, A, Bp, Cp, cf,
                                         x, bi, alpha, dyt_w, dyt_b, cn);
    gemm1_kernel<<<M1/128, 256, 0, stream>>>(x, WiT, bi, alpha, dyt_w, dyt_b, cn, xp, e);
    softmax_kernel<<<B_, 1024, 0, stream>>>(e, sim, kw1);
    sort1k_kernel<<<B_*L_/1024, 256, 0, stream>>>(kw1);
    merge_kernel<<<B_*L_/MT, 256, 0, stream>>>(kw1, kw2, 1024);
    merge_kernel<<<B_*L_/MT, 256, 0, stream>>>(kw2, kw1, 2048);
    merge_top_kernel<<<B_*2, 256, 0, stream>>>(kw1, idx);
    y_kernel<<<dim3((KTOP + TT - 1)/TT, B_), 256, 0, stream>>>(xp, idx, conv_w, cf, yb);
    copy_kernel<<<2048, 256, 0, stream>>>((const float4*)x, (float4*)out0);
    gemm2_kernel<<<dim3((M2 + 127)/128, 2), 256, 0, stream>>>(yb, WoT, bo, x, idx, out0);
}

// Round 11
// 439.847 us; speedup vs baseline: 1.5940x; 1.0247x over previous
//
#include <hip/hip_runtime.h>
#include <math.h>

#define B_ 16
#define L_ 8192
#define C_ 256
#define KTOP 2457            // max(1, int(8192*0.3))
#define JT 20                // recurrence taps; ||A||^20 ~ 1e-16 -> exact at fp32
#define M1 (B_*L_)           // 131072
#define M2 (B_*KTOP)         // 39312

// workspace layout in floats
#define XP_OFF  ((size_t)0)
#define Y_OFF   (XP_OFF + (size_t)M1*C_)        // yb: M2*C_ floats
#define CN_OFF  (Y_OFF  + (size_t)M2*C_)
#define CF_OFF  (CN_OFF + (size_t)B_*C_)
#define IDX_OFF (CF_OFF + (size_t)JT*C_)        // ints
#define WIT_OFF (IDX_OFF + (size_t)M2)
#define WOT_OFF (WIT_OFF + (size_t)C_*C_)
// Y region sub-lease (all die before y_kernel writes yb):
//   kw1 = Y_OFF (131072 u64 = 262144 f), kw2 = +262144 f, e = +524288 (M1 f)

// async global->LDS, 16B per lane, wave-uniform LDS base (m97 pattern)
__device__ __forceinline__ void async_copy16(const float* g, float* l) {
    __builtin_amdgcn_global_load_lds(
        (const __attribute__((address_space(1))) void*)g,
        (__attribute__((address_space(3))) void*)l, 16, 0, 0);
}

// ---------------- prep: transpose Wi/Wo + coef + center2, one launch ----------------
__global__ __launch_bounds__(256) void prep_kernel(
    const float* __restrict__ Wi, const float* __restrict__ Wo,
    float* __restrict__ WiT, float* __restrict__ WoT,
    const float* __restrict__ A, const float* __restrict__ Bp, const float* __restrict__ Cp,
    float* __restrict__ cf,
    const float* __restrict__ x, const float* __restrict__ bi, const float* __restrict__ alpha,
    const float* __restrict__ dw, const float* __restrict__ db, float* __restrict__ cn)
{
    __shared__ float shm[1089];
    const int bid = blockIdx.x, tid = threadIdx.x;
    if (bid < 128) {
        const int z = bid >> 6, rem = bid & 63;
        const int r0 = (rem >> 3) * 32, c0 = (rem & 7) * 32;
        const float* src = z ? Wo : Wi;
        float* dst = z ? WoT : WiT;
        float (*t)[33] = (float(*)[33])shm;
        int tx = tid & 31, ty = tid >> 5;
        #pragma unroll
        for (int r = 0; r < 4; r++)
            t[ty + r*8][tx] = src[(size_t)(r0 + ty + r*8)*C_ + c0 + tx];
        __syncthreads();
        #pragma unroll
        for (int r = 0; r < 4; r++)
            dst[(size_t)(c0 + ty + r*8)*C_ + r0 + tx] = t[tx][ty + r*8];
    } else if (bid == 128) {
        int c = tid;
        float* As = shm;
        float* v0 = shm + 256;
        As[c] = A[c];
        if (c < 16) v0[c] = 1.0f / (1.0f + expf(-Bp[c]));
        float sC[16];
        #pragma unroll
        for (int i = 0; i < 16; i++) sC[i] = 1.0f / (1.0f + expf(-Cp[c*16 + i]));
        __syncthreads();
        float v[16];
        #pragma unroll
        for (int i = 0; i < 16; i++) v[i] = v0[i];
        for (int j = 0; j < JT; j++) {
            float d = 0.f;
            #pragma unroll
            for (int i = 0; i < 16; i++) d += sC[i] * v[i];
            cf[j*C_ + c] = d;
            float nv[16];
            #pragma unroll
            for (int i = 0; i < 16; i++) {
                float s = 0.f;
                #pragma unroll
                for (int m = 0; m < 16; m++) s += As[i*16 + m] * v[m];
                nv[i] = s;
            }
            #pragma unroll
            for (int i = 0; i < 16; i++) v[i] = nv[i];
        }
    } else {
        int b = bid - 129, c = tid;
        float* xn = shm;
        float* red = shm + 256;
        float al = alpha[0];
        size_t base = ((size_t)b*L_ + L_/2)*C_;
        xn[c] = tanhf(al*x[base + c])*dw[c] + db[c];
        __syncthreads();
        float s = bi[c];
        #pragma unroll 8
        for (int k = 0; k < 256; k++) s = fmaf(xn[k], Wi[(size_t)c*C_ + k], s);
        float ss = s*s;
        #pragma unroll
        for (int off = 32; off; off >>= 1) ss += __shfl_xor(ss, off);
        if ((c & 63) == 0) red[c >> 6] = ss;
        __syncthreads();
        float tot = red[0] + red[1] + red[2] + red[3];
        float inv = 1.0f / fmaxf(sqrtf(tot), 1e-12f);
        cn[b*C_ + c] = s * inv;
    }
}

// ---------------- GEMM1 + fused e + fused residual: BM=128, BN=256, BK=16, dbuf ----------------
// (256,3): 3 blocks/CU (LDS 3x49.6=149KB fits; VGPR cap 170 >> 104 used - no spill).
// Per tile: async B(t+1)->Bs[nxt] + x(t+1)->regs BEFORE compute(t); tanh+A-write after;
// ONE barrier/tile. Epilogue also writes out0=x (rows L2-hot from K-loop).
// Canaries: WRITE ~265MB (fusion) - any more = spill; VGPR<=170.
__global__ __launch_bounds__(256, 3) void gemm1_kernel(
    const float* __restrict__ x, const float* __restrict__ WiT,
    const float* __restrict__ bi, const float* __restrict__ alpha,
    const float* __restrict__ dw, const float* __restrict__ db,
    const float* __restrict__ cn, float* __restrict__ xp, float* __restrict__ e,
    float* __restrict__ out0)
{
    __shared__ float As[2][16*132];   // [kk][m], pad 132 keeps 16B align
    __shared__ float Bs[2][16*256];   // [kk][n], 1KB rows
    const int tid = threadIdx.x;
    const int lane = tid & 63;
    const int wv = tid >> 6;       // 0..3
    const int tn2 = tid & 31;      // cols tn2*4..+3 and 128+tn2*4..+3
    const int tm2 = tid >> 5;      // rows tm2*16..+15
    const int m0 = blockIdx.x * 128;
    const int b  = m0 >> 13;
    const float al = alpha[0];
    const int ar = tid >> 2;             // A stage row 0..63 (+64)
    const int ak = (tid & 3) * 4;        // A stage k 0,4,8,12

    float acc[16][8];
    #pragma unroll
    for (int i = 0; i < 16; i++)
        #pragma unroll
        for (int j = 0; j < 8; j++) acc[i][j] = 0.f;

    // prologue: stage tile 0 into buffer 0
    #pragma unroll
    for (int it = 0; it < 4; it++)
        async_copy16(&WiT[(size_t)(wv + it*4)*C_ + lane*4], &Bs[0][(wv + it*4)*256]);
    {
        float4 w4 = *(const float4*)&dw[ak];
        float4 b4 = *(const float4*)&db[ak];
        #pragma unroll
        for (int it = 0; it < 2; it++) {
            int r = ar + it*64;
            float4 v = *(const float4*)&x[(size_t)(m0 + r)*C_ + ak];
            As[0][(ak+0)*132 + r] = tanhf(al*v.x)*w4.x + b4.x;
            As[0][(ak+1)*132 + r] = tanhf(al*v.y)*w4.y + b4.y;
            As[0][(ak+2)*132 + r] = tanhf(al*v.z)*w4.z + b4.z;
            As[0][(ak+3)*132 + r] = tanhf(al*v.w)*w4.w + b4.w;
        }
    }
    __syncthreads();
    int cur = 0;
    for (int t = 0; t < 16; t++) {
        const int k0 = t * 16;
        float4 xa0, xa1;
        if (t < 15) {
            int nxt = cur ^ 1;
            #pragma unroll
            for (int it = 0; it < 4; it++)
                async_copy16(&WiT[(size_t)(k0 + 16 + wv + it*4)*C_ + lane*4],
                             &Bs[nxt][(wv + it*4)*256]);
            xa0 = *(const float4*)&x[(size_t)(m0 + ar)*C_ + k0 + 16 + ak];
            xa1 = *(const float4*)&x[(size_t)(m0 + ar + 64)*C_ + k0 + 16 + ak];
        }
        #pragma unroll 2
        for (int kk = 0; kk < 16; kk++) {
            float a[16];
            *(float4*)&a[0]  = *(const float4*)&As[cur][kk*132 + tm2*16];
            *(float4*)&a[4]  = *(const float4*)&As[cur][kk*132 + tm2*16 + 4];
            *(float4*)&a[8]  = *(const float4*)&As[cur][kk*132 + tm2*16 + 8];
            *(float4*)&a[12] = *(const float4*)&As[cur][kk*132 + tm2*16 + 12];
            float4 b0 = *(const float4*)&Bs[cur][kk*256 + tn2*4];
            float4 b1 = *(const float4*)&Bs[cur][kk*256 + tn2*4 + 128];
            #pragma unroll
            for (int i = 0; i < 16; i++) {
                acc[i][0] = fmaf(a[i], b0.x, acc[i][0]);
                acc[i][1] = fmaf(a[i], b0.y, acc[i][1]);
                acc[i][2] = fmaf(a[i], b0.z, acc[i][2]);
                acc[i][3] = fmaf(a[i], b0.w, acc[i][3]);
                acc[i][4] = fmaf(a[i], b1.x, acc[i][4]);
                acc[i][5] = fmaf(a[i], b1.y, acc[i][5]);
                acc[i][6] = fmaf(a[i], b1.z, acc[i][6]);
                acc[i][7] = fmaf(a[i], b1.w, acc[i][7]);
            }
        }
        if (t < 15) {
            int nxt = cur ^ 1;
            float4 w4 = *(const float4*)&dw[k0 + 16 + ak];
            float4 b4 = *(const float4*)&db[k0 + 16 + ak];
            As[nxt][(ak+0)*132 + ar] = tanhf(al*xa0.x)*w4.x + b4.x;
            As[nxt][(ak+1)*132 + ar] = tanhf(al*xa0.y)*w4.y + b4.y;
            As[nxt][(ak+2)*132 + ar] = tanhf(al*xa0.z)*w4.z + b4.z;
            As[nxt][(ak+3)*132 + ar] = tanhf(al*xa0.w)*w4.w + b4.w;
            As[nxt][(ak+0)*132 + ar + 64] = tanhf(al*xa1.x)*w4.x + b4.x;
            As[nxt][(ak+1)*132 + ar + 64] = tanhf(al*xa1.y)*w4.y + b4.y;
            As[nxt][(ak+2)*132 + ar + 64] = tanhf(al*xa1.z)*w4.z + b4.z;
            As[nxt][(ak+3)*132 + ar + 64] = tanhf(al*xa1.w)*w4.w + b4.w;
            cur = nxt;
        }
        __syncthreads();
    }
    float4 bi0 = *(const float4*)&bi[tn2*4];
    float4 bi1 = *(const float4*)&bi[tn2*4 + 128];
    float4 c0  = *(const float4*)&cn[b*C_ + tn2*4];
    float4 c1  = *(const float4*)&cn[b*C_ + tn2*4 + 128];
    #pragma unroll
    for (int i = 0; i < 16; i++) {
        size_t row = m0 + tm2*16 + i;
        float4 o0 = make_float4(acc[i][0]+bi0.x, acc[i][1]+bi0.y, acc[i][2]+bi0.z, acc[i][3]+bi0.w);
        float4 o1 = make_float4(acc[i][4]+bi1.x, acc[i][5]+bi1.y, acc[i][6]+bi1.z, acc[i][7]+bi1.w);
        *(float4*)&xp[row*C_ + tn2*4]       = o0;
        *(float4*)&xp[row*C_ + tn2*4 + 128] = o1;
        // fused residual: out0 = x (topk rows overwritten later by gemm2); rows L2-hot
        *(float4*)&out0[row*C_ + tn2*4]       = *(const float4*)&x[row*C_ + tn2*4];
        *(float4*)&out0[row*C_ + tn2*4 + 128] = *(const float4*)&x[row*C_ + tn2*4 + 128];
        float dt = o0.x*c0.x + o0.y*c0.y + o0.z*c0.z + o0.w*c0.w
                 + o1.x*c1.x + o1.y*c1.y + o1.z*c1.z + o1.w*c1.w;
        float ss = o0.x*o0.x + o0.y*o0.y + o0.z*o0.z + o0.w*o0.w
                 + o1.x*o1.x + o1.y*o1.y + o1.z*o1.z + o1.w*o1.w;
        #pragma unroll
        for (int off = 16; off; off >>= 1) {
            dt += __shfl_xor(dt, off);
            ss += __shfl_xor(ss, off);
        }
        if (tn2 == 0) e[row] = dt / fmaxf(sqrtf(ss), 1e-12f);
    }
}

// ---------------- softmax per batch; emit sim + u64 keys (sim desc, idx asc) ----------------
__global__ __launch_bounds__(1024) void softmax_kernel(
    const float* __restrict__ e, float* __restrict__ sim, unsigned long long* __restrict__ kw)
{
    __shared__ float scratch[32];
    const int b = blockIdx.x, tid = threadIdx.x;
    const int lane = tid & 63, wid = tid >> 6; // 16 waves
    const float* eb = e + (size_t)b*L_;
    float ev[8];
    #pragma unroll
    for (int s = 0; s < 8; s++) ev[s] = eb[tid + s*1024];
    float mx = ev[0];
    #pragma unroll
    for (int s = 1; s < 8; s++) mx = fmaxf(mx, ev[s]);
    #pragma unroll
    for (int off = 32; off; off >>= 1) mx = fmaxf(mx, __shfl_xor(mx, off));
    if (lane == 0) scratch[wid] = mx;
    __syncthreads();
    if (tid == 0) {
        float m2 = scratch[0];
        for (int i = 1; i < 16; i++) m2 = fmaxf(m2, scratch[i]);
        scratch[20] = m2;
    }
    __syncthreads();
    mx = scratch[20];
    float pv[8], sum = 0.f;
    #pragma unroll
    for (int s = 0; s < 8; s++) { pv[s] = expf(ev[s] - mx); sum += pv[s]; }
    #pragma unroll
    for (int off = 32; off; off >>= 1) sum += __shfl_xor(sum, off);
    __syncthreads();
    if (lane == 0) scratch[wid] = sum;
    __syncthreads();
    if (tid == 0) {
        float s2 = 0.f;
        for (int i = 0; i < 16; i++) s2 += scratch[i];
        scratch[21] = s2;
    }
    __syncthreads();
    float inv = 1.0f / scratch[21];
    #pragma unroll
    for (int s = 0; s < 8; s++) {
        int l = tid + s*1024;
        float sm = pv[s] * inv;
        sim[(size_t)b*L_ + l] = sm;
        kw[(size_t)b*L_ + l] =
            ((unsigned long long)__float_as_uint(sm) << 32) | (unsigned)(0xFFFFFFFFu - l);
    }
}

// ---------------- sort 1024-element chunks descending (bitonic in LDS) ----------------
__global__ __launch_bounds__(256) void sort1k_kernel(unsigned long long* __restrict__ keys)
{
    __shared__ unsigned long long k[1024];
    size_t base = (size_t)blockIdx.x * 1024;
    int tid = threadIdx.x;
    #pragma unroll
    for (int s = 0; s < 4; s++) k[tid + s*256] = keys[base + tid + s*256];
    __syncthreads();
    for (int ksz = 2; ksz <= 1024; ksz <<= 1) {
        for (int j = ksz >> 1; j > 0; j >>= 1) {
            #pragma unroll
            for (int s = 0; s < 2; s++) {
                int p = tid + s*256;
                int i = ((p & ~(j-1)) << 1) | (p & (j-1));
                int ix = i | j;
                unsigned long long a = k[i], c = k[ix];
                bool desc = ((i & ksz) == 0);
                if (desc ? (a < c) : (a > c)) { k[i] = c; k[ix] = a; }
            }
            __syncthreads();
        }
    }
    #pragma unroll
    for (int s = 0; s < 4; s++) keys[base + tid + s*256] = k[tid + s*256];
}

// ---------------- merge pass, tile-parallel: fixed 2048-output tiles, merge-path ----------------
#define MT 2048
__global__ __launch_bounds__(256) void merge_kernel(
    const unsigned long long* __restrict__ src, unsigned long long* __restrict__ dst, int run)
{
    const size_t tile = blockIdx.x;
    const size_t pairSpan = (size_t)2 * run;
    const size_t p = tile * MT / pairSpan;
    const int o = (int)(tile * MT % pairSpan);
    const unsigned long long* A  = src + p * pairSpan;
    const unsigned long long* Bv = A + run;
    unsigned long long* D = dst + p * pairSpan;

    int q0 = o + threadIdx.x * (MT/256);
    int lo = (q0 > run) ? (q0 - run) : 0;
    int hi = (q0 < run) ? q0 : run;
    while (lo < hi) {
        int mid = (lo + hi) >> 1;
        if (A[mid] >= Bv[q0 - 1 - mid]) lo = mid + 1; else hi = mid;
    }
    int a = lo, bq = q0 - lo;
    #pragma unroll
    for (int q = 0; q < MT/256; q++) {
        unsigned long long va = (a < run) ? A[a] : 0ULL;
        unsigned long long vb = (bq < run) ? Bv[bq] : 0ULL;
        bool takeA = (bq >= run) || ((a < run) && (va > vb));
        D[q0 + q] = takeA ? va : vb;
        if (takeA) a++; else bq++;
    }
}

// ---------------- final merge (runs of 4096) producing only top-KTOP indices ----------------
__global__ __launch_bounds__(256) void merge_top_kernel(
    const unsigned long long* __restrict__ src, int* __restrict__ idxo)
{
    const int tile = blockIdx.x;               // 0..31
    const int p = tile >> 1;
    const int o = (tile & 1) * MT;
    const int run = 4096;
    const unsigned long long* A  = src + (size_t)p * L_;
    const unsigned long long* Bv = A + run;

    int q0 = o + threadIdx.x * (MT/256);
    int lo = (q0 > run) ? (q0 - run) : 0;
    int hi = (q0 < run) ? q0 : run;
    while (lo < hi) {
        int mid = (lo + hi) >> 1;
        if (A[mid] >= Bv[q0 - 1 - mid]) lo = mid + 1; else hi = mid;
    }
    int a = lo, bq = q0 - lo;
    #pragma unroll
    for (int q = 0; q < MT/256; q++) {
        unsigned long long va = (a < run) ? A[a] : 0ULL;
        unsigned long long vb = (bq < run) ? Bv[bq] : 0ULL;
        bool takeA = (bq >= run) || ((a < run) && (va > vb));
        unsigned long long v = takeA ? va : vb;
        if (q0 + q < KTOP)
            idxo[p*KTOP + q0 + q] = (int)(0xFFFFFFFFu - (unsigned)(v & 0xFFFFFFFFu));
        if (takeA) a++; else bq++;
    }
}

// ---------------- y: tiled over 32 consecutive t with 51-row LDS window ----------------
#define TT 32
__global__ __launch_bounds__(256) void y_kernel(const float* __restrict__ xp,
    const int* __restrict__ idx, const float* __restrict__ conv_w,
    const float* __restrict__ cf, float* __restrict__ y)
{
    __shared__ float rows[(TT + JT - 1) * C_];   // 51 rows x 1KB = 51KB
    const int b = blockIdx.y;
    const int t0 = blockIdx.x * TT;
    const int tid = threadIdx.x;
    const int c4 = (tid & 63) * 4;
    const int tg = tid >> 6;
    const int* idxb = idx + b*KTOP;

    for (int s = tid; s < (TT + JT - 1) * 64; s += 256) {
        int r = s >> 6, cq = (s & 63) * 4;
        int gi = t0 - (JT - 1) + r;
        float4 v = make_float4(0.f, 0.f, 0.f, 0.f);
        if (gi >= 0 && gi < KTOP) {
            int l = idxb[gi];
            v = *(const float4*)&xp[((size_t)b*L_ + l)*C_ + cq];
        }
        *(float4*)&rows[r*C_ + cq] = v;
    }
    float4 cfr[JT];
    #pragma unroll
    for (int j = 0; j < JT; j++) cfr[j] = *(const float4*)&cf[j*C_ + c4];
    float4 cw = *(const float4*)&conv_w[c4];
    __syncthreads();

    #pragma unroll
    for (int u = 0; u < TT/4; u++) {
        int tl = tg + u*4;
        int t = t0 + tl;
        if (t < KTOP) {
            float4 acc = make_float4(0.f, 0.f, 0.f, 0.f);
            #pragma unroll
            for (int j = 0; j < JT; j++) {
                const float4 v = *(const float4*)&rows[(tl + JT - 1 - j)*C_ + c4];
                acc.x = fmaf(cfr[j].x, v.x, acc.x);
                acc.y = fmaf(cfr[j].y, v.y, acc.y);
                acc.z = fmaf(cfr[j].z, v.z, acc.z);
                acc.w = fmaf(cfr[j].w, v.w, acc.w);
            }
            acc.x *= cw.x; acc.y *= cw.y; acc.z *= cw.z; acc.w *= cw.w;
            *(float4*)&y[((size_t)b*KTOP + t)*C_ + c4] = acc;
        }
    }
}

// ---------------- GEMM2 + scatter epilogue over 128x128 tiles ----------------
__global__ __launch_bounds__(256, 2) void gemm2_kernel(
    const float* __restrict__ y, const float* __restrict__ WoT,
    const float* __restrict__ bo, const float* __restrict__ x,
    const int* __restrict__ idx, float* __restrict__ out0)
{
    __shared__ float As[2][32*132];
    __shared__ float Bs[2][32*128];   // 512B rows; wave covers 1KB = 2 rows
    const int tid = threadIdx.x;
    const int lane = tid & 63;
    const int wv = tid >> 6;
    const int tm2 = tid >> 4;
    const int tn2 = tid & 15;
    const int m0 = blockIdx.x * 128;
    const int n0 = blockIdx.y * 128;

    float acc[8][8];
    #pragma unroll
    for (int i = 0; i < 8; i++)
        #pragma unroll
        for (int j = 0; j < 8; j++) acc[i][j] = 0.f;

    float4 xa[4];
    #pragma unroll
    for (int it = 0; it < 4; it++) {
        int i2 = tid + it*256;
        int m = m0 + (i2>>3);
        xa[it] = (m < M2) ? *(const float4*)&y[(size_t)m*C_ + ((i2&7)*4)]
                          : make_float4(0.f, 0.f, 0.f, 0.f);
    }
    #pragma unroll
    for (int it = 0; it < 4; it++) {
        int brow = 2*wv + it*8;
        async_copy16(&WoT[(size_t)(brow + (lane>>5))*C_ + n0 + (lane&31)*4],
                     &Bs[0][brow*128]);
    }
    #pragma unroll
    for (int it = 0; it < 4; it++) {
        int i2 = tid + it*256;
        int ar = i2>>3, ak = (i2&7)*4;
        float4 v = xa[it];
        As[0][(ak+0)*132 + ar] = v.x;
        As[0][(ak+1)*132 + ar] = v.y;
        As[0][(ak+2)*132 + ar] = v.z;
        As[0][(ak+3)*132 + ar] = v.w;
    }
    __syncthreads();
    int cur = 0;
    for (int k0 = 0; k0 < C_; k0 += 32) {
        if (k0 + 32 < C_) {
            int nxt = cur ^ 1;
            #pragma unroll
            for (int it = 0; it < 4; it++) {
                int brow = 2*wv + it*8;
                async_copy16(&WoT[(size_t)(k0 + 32 + brow + (lane>>5))*C_ + n0 + (lane&31)*4],
                             &Bs[nxt][brow*128]);
            }
            #pragma unroll
            for (int it = 0; it < 4; it++) {
                int i2 = tid + it*256;
                int m = m0 + (i2>>3);
                xa[it] = (m < M2) ? *(const float4*)&y[(size_t)m*C_ + k0 + 32 + ((i2&7)*4)]
                                  : make_float4(0.f, 0.f, 0.f, 0.f);
            }
        }
        #pragma unroll 2
        for (int kk = 0; kk < 32; kk++) {
            float a[8], bf[8];
            *(float4*)&a[0]  = *(const float4*)&As[cur][kk*132 + tm2*8];
            *(float4*)&a[4]  = *(const float4*)&As[cur][kk*132 + tm2*8 + 4];
            *(float4*)&bf[0] = *(const float4*)&Bs[cur][kk*128 + tn2*4];
            *(float4*)&bf[4] = *(const float4*)&Bs[cur][kk*128 + tn2*4 + 64];
            #pragma unroll
            for (int i = 0; i < 8; i++)
                #pragma unroll
                for (int j = 0; j < 8; j++)
                    acc[i][j] = fmaf(a[i], bf[j], acc[i][j]);
        }
        if (k0 + 32 < C_) {
            int nxt = cur ^ 1;
            #pragma unroll
            for (int it = 0; it < 4; it++) {
                int i2 = tid + it*256;
                int ar = i2>>3, ak = (i2&7)*4;
                float4 v = xa[it];
                As[nxt][(ak+0)*132 + ar] = v.x;
                As[nxt][(ak+1)*132 + ar] = v.y;
                As[nxt][(ak+2)*132 + ar] = v.z;
                As[nxt][(ak+3)*132 + ar] = v.w;
            }
            cur = nxt;
        }
        __syncthreads();
    }
    float4 bo0 = *(const float4*)&bo[n0 + tn2*4];
    float4 bo1 = *(const float4*)&bo[n0 + 64 + tn2*4];
    #pragma unroll
    for (int i = 0; i < 8; i++) {
        int m = m0 + tm2*8 + i;
        if (m < M2) {
            int b = m / KTOP, t = m - b*KTOP;
            int l = idx[b*KTOP + t];
            size_t base = ((size_t)b*L_ + l)*C_;
            float4 x0 = *(const float4*)&x[base + n0 + tn2*4];
            float4 x1 = *(const float4*)&x[base + n0 + 64 + tn2*4];
            float4 o0 = make_float4(acc[i][0]+bo0.x+x0.x, acc[i][1]+bo0.y+x0.y,
                                    acc[i][2]+bo0.z+x0.z, acc[i][3]+bo0.w+x0.w);
            float4 o1 = make_float4(acc[i][4]+bo1.x+x1.x, acc[i][5]+bo1.y+x1.y,
                                    acc[i][6]+bo1.z+x1.z, acc[i][7]+bo1.w+x1.w);
            *(float4*)&out0[base + n0 + tn2*4]      = o0;
            *(float4*)&out0[base + n0 + 64 + tn2*4] = o1;
        }
    }
}

extern "C" void kernel_launch(void* const* d_in, const int* in_sizes, int n_in,
                              void* d_out, int out_size, void* d_ws, size_t ws_size,
                              hipStream_t stream)
{
    const float* x      = (const float*)d_in[0];
    const float* alpha  = (const float*)d_in[1];
    const float* dyt_w  = (const float*)d_in[2];
    const float* dyt_b  = (const float*)d_in[3];
    const float* Wi     = (const float*)d_in[4];
    const float* bi     = (const float*)d_in[5];
    const float* conv_w = (const float*)d_in[6];
    const float* A      = (const float*)d_in[7];
    const float* Bp     = (const float*)d_in[8];
    const float* Cp     = (const float*)d_in[9];
    const float* Wo     = (const float*)d_in[10];
    const float* bo     = (const float*)d_in[11];

    float* ws  = (float*)d_ws;
    float* xp  = ws + XP_OFF;
    float* yb  = ws + Y_OFF;
    float* cn  = ws + CN_OFF;
    float* cf  = ws + CF_OFF;
    int*   idx = (int*)(ws + IDX_OFF);
    float* WiT = ws + WIT_OFF;
    float* WoT = ws + WOT_OFF;
    // Y-region sub-lease (all dead before y_kernel writes yb):
    unsigned long long* kw1 = (unsigned long long*)(ws + Y_OFF);   // 131072 u64
    unsigned long long* kw2 = kw1 + (size_t)B_*L_;                 // 131072 u64
    float* e = ws + Y_OFF + 524288;                                // M1 floats

    float* out0 = (float*)d_out;
    float* sim  = out0 + (size_t)M1*C_;

    prep_kernel<<<145, 256, 0, stream>>>(Wi, Wo, WiT, WoT, A, Bp, Cp, cf,
                                         x, bi, alpha, dyt_w, dyt_b, cn);
    gemm1_kernel<<<M1/128, 256, 0, stream>>>(x, WiT, bi, alpha, dyt_w, dyt_b, cn, xp, e, out0);
    softmax_kernel<<<B_, 1024, 0, stream>>>(e, sim, kw1);
    sort1k_kernel<<<B_*L_/1024, 256, 0, stream>>>(kw1);
    merge_kernel<<<B_*L_/MT, 256, 0, stream>>>(kw1, kw2, 1024);
    merge_kernel<<<B_*L_/MT, 256, 0, stream>>>(kw2, kw1, 2048);
    merge_top_kernel<<<B_*2, 256, 0, stream>>>(kw1, idx);
    y_kernel<<<dim3((KTOP + TT - 1)/TT, B_), 256, 0, stream>>>(xp, idx, conv_w, cf, yb);
    gemm2_kernel<<<dim3((M2 + 127)/128, 2), 256, 0, stream>>>(yb, WoT, bo, x, idx, out0);
}

// Round 12
// 421.446 us; speedup vs baseline: 1.6636x; 1.0437x over previous
//
#include <hip/hip_runtime.h>
#include <math.h>

#define B_ 16
#define L_ 8192
#define C_ 256
#define KTOP 2457            // max(1, int(8192*0.3))
#define JT 20                // recurrence taps; ||A||^20 ~ 1e-16 -> exact at fp32
#define M1 (B_*L_)           // 131072
#define M2 (B_*KTOP)         // 39312

// workspace layout in floats
#define XP_OFF  ((size_t)0)
#define Y_OFF   (XP_OFF + (size_t)M1*C_)        // yb: M2*C_ floats
#define CN_OFF  (Y_OFF  + (size_t)M2*C_)
#define CF_OFF  (CN_OFF + (size_t)B_*C_)
#define IDX_OFF (CF_OFF + (size_t)JT*C_)        // ints
#define WIT_OFF (IDX_OFF + (size_t)M2)
#define WOT_OFF (WIT_OFF + (size_t)C_*C_)
// Y region sub-lease (all die before y_kernel writes yb):
//   kw1 = Y_OFF (131072 u64 = 262144 f), kw2 = +262144 f, e = +524288 (M1 f)

// async global->LDS, 16B per lane, wave-uniform LDS base (m97 pattern)
__device__ __forceinline__ void async_copy16(const float* g, float* l) {
    __builtin_amdgcn_global_load_lds(
        (const __attribute__((address_space(1))) void*)g,
        (__attribute__((address_space(3))) void*)l, 16, 0, 0);
}

// ---------------- prep: transpose Wi/Wo + coef + center2, one launch ----------------
__global__ __launch_bounds__(256) void prep_kernel(
    const float* __restrict__ Wi, const float* __restrict__ Wo,
    float* __restrict__ WiT, float* __restrict__ WoT,
    const float* __restrict__ A, const float* __restrict__ Bp, const float* __restrict__ Cp,
    float* __restrict__ cf,
    const float* __restrict__ x, const float* __restrict__ bi, const float* __restrict__ alpha,
    const float* __restrict__ dw, const float* __restrict__ db, float* __restrict__ cn)
{
    __shared__ float shm[1089];
    const int bid = blockIdx.x, tid = threadIdx.x;
    if (bid < 128) {
        const int z = bid >> 6, rem = bid & 63;
        const int r0 = (rem >> 3) * 32, c0 = (rem & 7) * 32;
        const float* src = z ? Wo : Wi;
        float* dst = z ? WoT : WiT;
        float (*t)[33] = (float(*)[33])shm;
        int tx = tid & 31, ty = tid >> 5;
        #pragma unroll
        for (int r = 0; r < 4; r++)
            t[ty + r*8][tx] = src[(size_t)(r0 + ty + r*8)*C_ + c0 + tx];
        __syncthreads();
        #pragma unroll
        for (int r = 0; r < 4; r++)
            dst[(size_t)(c0 + ty + r*8)*C_ + r0 + tx] = t[tx][ty + r*8];
    } else if (bid == 128) {
        int c = tid;
        float* As = shm;
        float* v0 = shm + 256;
        As[c] = A[c];
        if (c < 16) v0[c] = 1.0f / (1.0f + expf(-Bp[c]));
        float sC[16];
        #pragma unroll
        for (int i = 0; i < 16; i++) sC[i] = 1.0f / (1.0f + expf(-Cp[c*16 + i]));
        __syncthreads();
        float v[16];
        #pragma unroll
        for (int i = 0; i < 16; i++) v[i] = v0[i];
        for (int j = 0; j < JT; j++) {
            float d = 0.f;
            #pragma unroll
            for (int i = 0; i < 16; i++) d += sC[i] * v[i];
            cf[j*C_ + c] = d;
            float nv[16];
            #pragma unroll
            for (int i = 0; i < 16; i++) {
                float s = 0.f;
                #pragma unroll
                for (int m = 0; m < 16; m++) s += As[i*16 + m] * v[m];
                nv[i] = s;
            }
            #pragma unroll
            for (int i = 0; i < 16; i++) v[i] = nv[i];
        }
    } else {
        int b = bid - 129, c = tid;
        float* xn = shm;
        float* red = shm + 256;
        float al = alpha[0];
        size_t base = ((size_t)b*L_ + L_/2)*C_;
        xn[c] = tanhf(al*x[base + c])*dw[c] + db[c];
        __syncthreads();
        float s = bi[c];
        #pragma unroll 8
        for (int k = 0; k < 256; k++) s = fmaf(xn[k], Wi[(size_t)c*C_ + k], s);
        float ss = s*s;
        #pragma unroll
        for (int off = 32; off; off >>= 1) ss += __shfl_xor(ss, off);
        if ((c & 63) == 0) red[c >> 6] = ss;
        __syncthreads();
        float tot = red[0] + red[1] + red[2] + red[3];
        float inv = 1.0f / fmaxf(sqrtf(tot), 1e-12f);
        cn[b*C_ + c] = s * inv;
    }
}

// ---------------- GEMM1 + fused e + fused residual: BM=128, BN=256, BK=16, dbuf ----------------
// (256,2): r11 showed (256,3) forces VGPR 104->84 and LOSES ILP (VALUBusy 67->61, +22us).
// Per tile: async B(t+1)->Bs[nxt] + x(t+1)->regs BEFORE compute(t); tanh+A-write after;
// ONE barrier/tile. Epilogue writes xp, out0=x (L2-hot), partial-e.
// Canaries: WRITE ~265MB; VGPR ~104.
__global__ __launch_bounds__(256, 2) void gemm1_kernel(
    const float* __restrict__ x, const float* __restrict__ WiT,
    const float* __restrict__ bi, const float* __restrict__ alpha,
    const float* __restrict__ dw, const float* __restrict__ db,
    const float* __restrict__ cn, float* __restrict__ xp, float* __restrict__ e,
    float* __restrict__ out0)
{
    __shared__ float As[2][16*132];   // [kk][m], pad 132 keeps 16B align
    __shared__ float Bs[2][16*256];   // [kk][n], 1KB rows
    const int tid = threadIdx.x;
    const int lane = tid & 63;
    const int wv = tid >> 6;       // 0..3
    const int tn2 = tid & 31;      // cols tn2*4..+3 and 128+tn2*4..+3
    const int tm2 = tid >> 5;      // rows tm2*16..+15
    const int m0 = blockIdx.x * 128;
    const int b  = m0 >> 13;
    const float al = alpha[0];
    const int ar = tid >> 2;             // A stage row 0..63 (+64)
    const int ak = (tid & 3) * 4;        // A stage k 0,4,8,12

    float acc[16][8];
    #pragma unroll
    for (int i = 0; i < 16; i++)
        #pragma unroll
        for (int j = 0; j < 8; j++) acc[i][j] = 0.f;

    // prologue: stage tile 0 into buffer 0
    #pragma unroll
    for (int it = 0; it < 4; it++)
        async_copy16(&WiT[(size_t)(wv + it*4)*C_ + lane*4], &Bs[0][(wv + it*4)*256]);
    {
        float4 w4 = *(const float4*)&dw[ak];
        float4 b4 = *(const float4*)&db[ak];
        #pragma unroll
        for (int it = 0; it < 2; it++) {
            int r = ar + it*64;
            float4 v = *(const float4*)&x[(size_t)(m0 + r)*C_ + ak];
            As[0][(ak+0)*132 + r] = tanhf(al*v.x)*w4.x + b4.x;
            As[0][(ak+1)*132 + r] = tanhf(al*v.y)*w4.y + b4.y;
            As[0][(ak+2)*132 + r] = tanhf(al*v.z)*w4.z + b4.z;
            As[0][(ak+3)*132 + r] = tanhf(al*v.w)*w4.w + b4.w;
        }
    }
    __syncthreads();
    int cur = 0;
    for (int t = 0; t < 16; t++) {
        const int k0 = t * 16;
        float4 xa0, xa1;
        if (t < 15) {
            int nxt = cur ^ 1;
            #pragma unroll
            for (int it = 0; it < 4; it++)
                async_copy16(&WiT[(size_t)(k0 + 16 + wv + it*4)*C_ + lane*4],
                             &Bs[nxt][(wv + it*4)*256]);
            xa0 = *(const float4*)&x[(size_t)(m0 + ar)*C_ + k0 + 16 + ak];
            xa1 = *(const float4*)&x[(size_t)(m0 + ar + 64)*C_ + k0 + 16 + ak];
        }
        #pragma unroll 2
        for (int kk = 0; kk < 16; kk++) {
            float a[16];
            *(float4*)&a[0]  = *(const float4*)&As[cur][kk*132 + tm2*16];
            *(float4*)&a[4]  = *(const float4*)&As[cur][kk*132 + tm2*16 + 4];
            *(float4*)&a[8]  = *(const float4*)&As[cur][kk*132 + tm2*16 + 8];
            *(float4*)&a[12] = *(const float4*)&As[cur][kk*132 + tm2*16 + 12];
            float4 b0 = *(const float4*)&Bs[cur][kk*256 + tn2*4];
            float4 b1 = *(const float4*)&Bs[cur][kk*256 + tn2*4 + 128];
            #pragma unroll
            for (int i = 0; i < 16; i++) {
                acc[i][0] = fmaf(a[i], b0.x, acc[i][0]);
                acc[i][1] = fmaf(a[i], b0.y, acc[i][1]);
                acc[i][2] = fmaf(a[i], b0.z, acc[i][2]);
                acc[i][3] = fmaf(a[i], b0.w, acc[i][3]);
                acc[i][4] = fmaf(a[i], b1.x, acc[i][4]);
                acc[i][5] = fmaf(a[i], b1.y, acc[i][5]);
                acc[i][6] = fmaf(a[i], b1.z, acc[i][6]);
                acc[i][7] = fmaf(a[i], b1.w, acc[i][7]);
            }
        }
        if (t < 15) {
            int nxt = cur ^ 1;
            float4 w4 = *(const float4*)&dw[k0 + 16 + ak];
            float4 b4 = *(const float4*)&db[k0 + 16 + ak];
            As[nxt][(ak+0)*132 + ar] = tanhf(al*xa0.x)*w4.x + b4.x;
            As[nxt][(ak+1)*132 + ar] = tanhf(al*xa0.y)*w4.y + b4.y;
            As[nxt][(ak+2)*132 + ar] = tanhf(al*xa0.z)*w4.z + b4.z;
            As[nxt][(ak+3)*132 + ar] = tanhf(al*xa0.w)*w4.w + b4.w;
            As[nxt][(ak+0)*132 + ar + 64] = tanhf(al*xa1.x)*w4.x + b4.x;
            As[nxt][(ak+1)*132 + ar + 64] = tanhf(al*xa1.y)*w4.y + b4.y;
            As[nxt][(ak+2)*132 + ar + 64] = tanhf(al*xa1.z)*w4.z + b4.z;
            As[nxt][(ak+3)*132 + ar + 64] = tanhf(al*xa1.w)*w4.w + b4.w;
            cur = nxt;
        }
        __syncthreads();
    }
    float4 bi0 = *(const float4*)&bi[tn2*4];
    float4 bi1 = *(const float4*)&bi[tn2*4 + 128];
    float4 c0  = *(const float4*)&cn[b*C_ + tn2*4];
    float4 c1  = *(const float4*)&cn[b*C_ + tn2*4 + 128];
    #pragma unroll
    for (int i = 0; i < 16; i++) {
        size_t row = m0 + tm2*16 + i;
        float4 o0 = make_float4(acc[i][0]+bi0.x, acc[i][1]+bi0.y, acc[i][2]+bi0.z, acc[i][3]+bi0.w);
        float4 o1 = make_float4(acc[i][4]+bi1.x, acc[i][5]+bi1.y, acc[i][6]+bi1.z, acc[i][7]+bi1.w);
        *(float4*)&xp[row*C_ + tn2*4]       = o0;
        *(float4*)&xp[row*C_ + tn2*4 + 128] = o1;
        // fused residual: out0 = x (topk rows overwritten later by gemm2); rows L2-hot
        *(float4*)&out0[row*C_ + tn2*4]       = *(const float4*)&x[row*C_ + tn2*4];
        *(float4*)&out0[row*C_ + tn2*4 + 128] = *(const float4*)&x[row*C_ + tn2*4 + 128];
        float dt = o0.x*c0.x + o0.y*c0.y + o0.z*c0.z + o0.w*c0.w
                 + o1.x*c1.x + o1.y*c1.y + o1.z*c1.z + o1.w*c1.w;
        float ss = o0.x*o0.x + o0.y*o0.y + o0.z*o0.z + o0.w*o0.w
                 + o1.x*o1.x + o1.y*o1.y + o1.z*o1.z + o1.w*o1.w;
        #pragma unroll
        for (int off = 16; off; off >>= 1) {
            dt += __shfl_xor(dt, off);
            ss += __shfl_xor(ss, off);
        }
        if (tn2 == 0) e[row] = dt / fmaxf(sqrtf(ss), 1e-12f);
    }
}

// ---------------- softmax per batch; emit sim + u64 keys (sim desc, idx asc) ----------------
__global__ __launch_bounds__(1024) void softmax_kernel(
    const float* __restrict__ e, float* __restrict__ sim, unsigned long long* __restrict__ kw)
{
    __shared__ float scratch[32];
    const int b = blockIdx.x, tid = threadIdx.x;
    const int lane = tid & 63, wid = tid >> 6; // 16 waves
    const float* eb = e + (size_t)b*L_;
    float ev[8];
    #pragma unroll
    for (int s = 0; s < 8; s++) ev[s] = eb[tid + s*1024];
    float mx = ev[0];
    #pragma unroll
    for (int s = 1; s < 8; s++) mx = fmaxf(mx, ev[s]);
    #pragma unroll
    for (int off = 32; off; off >>= 1) mx = fmaxf(mx, __shfl_xor(mx, off));
    if (lane == 0) scratch[wid] = mx;
    __syncthreads();
    if (tid == 0) {
        float m2 = scratch[0];
        for (int i = 1; i < 16; i++) m2 = fmaxf(m2, scratch[i]);
        scratch[20] = m2;
    }
    __syncthreads();
    mx = scratch[20];
    float pv[8], sum = 0.f;
    #pragma unroll
    for (int s = 0; s < 8; s++) { pv[s] = expf(ev[s] - mx); sum += pv[s]; }
    #pragma unroll
    for (int off = 32; off; off >>= 1) sum += __shfl_xor(sum, off);
    __syncthreads();
    if (lane == 0) scratch[wid] = sum;
    __syncthreads();
    if (tid == 0) {
        float s2 = 0.f;
        for (int i = 0; i < 16; i++) s2 += scratch[i];
        scratch[21] = s2;
    }
    __syncthreads();
    float inv = 1.0f / scratch[21];
    #pragma unroll
    for (int s = 0; s < 8; s++) {
        int l = tid + s*1024;
        float sm = pv[s] * inv;
        sim[(size_t)b*L_ + l] = sm;
        kw[(size_t)b*L_ + l] =
            ((unsigned long long)__float_as_uint(sm) << 32) | (unsigned)(0xFFFFFFFFu - l);
    }
}

// ---------------- sort 1024-element chunks descending (bitonic in LDS) ----------------
__global__ __launch_bounds__(256) void sort1k_kernel(unsigned long long* __restrict__ keys)
{
    __shared__ unsigned long long k[1024];
    size_t base = (size_t)blockIdx.x * 1024;
    int tid = threadIdx.x;
    #pragma unroll
    for (int s = 0; s < 4; s++) k[tid + s*256] = keys[base + tid + s*256];
    __syncthreads();
    for (int ksz = 2; ksz <= 1024; ksz <<= 1) {
        for (int j = ksz >> 1; j > 0; j >>= 1) {
            #pragma unroll
            for (int s = 0; s < 2; s++) {
                int p = tid + s*256;
                int i = ((p & ~(j-1)) << 1) | (p & (j-1));
                int ix = i | j;
                unsigned long long a = k[i], c = k[ix];
                bool desc = ((i & ksz) == 0);
                if (desc ? (a < c) : (a > c)) { k[i] = c; k[ix] = a; }
            }
            __syncthreads();
        }
    }
    #pragma unroll
    for (int s = 0; s < 4; s++) keys[base + tid + s*256] = k[tid + s*256];
}

// ---------------- merge pass, tile-parallel: fixed 2048-output tiles, merge-path ----------------
#define MT 2048
__global__ __launch_bounds__(256) void merge_kernel(
    const unsigned long long* __restrict__ src, unsigned long long* __restrict__ dst, int run)
{
    const size_t tile = blockIdx.x;
    const size_t pairSpan = (size_t)2 * run;
    const size_t p = tile * MT / pairSpan;
    const int o = (int)(tile * MT % pairSpan);
    const unsigned long long* A  = src + p * pairSpan;
    const unsigned long long* Bv = A + run;
    unsigned long long* D = dst + p * pairSpan;

    int q0 = o + threadIdx.x * (MT/256);
    int lo = (q0 > run) ? (q0 - run) : 0;
    int hi = (q0 < run) ? q0 : run;
    while (lo < hi) {
        int mid = (lo + hi) >> 1;
        if (A[mid] >= Bv[q0 - 1 - mid]) lo = mid + 1; else hi = mid;
    }
    int a = lo, bq = q0 - lo;
    #pragma unroll
    for (int q = 0; q < MT/256; q++) {
        unsigned long long va = (a < run) ? A[a] : 0ULL;
        unsigned long long vb = (bq < run) ? Bv[bq] : 0ULL;
        bool takeA = (bq >= run) || ((a < run) && (va > vb));
        D[q0 + q] = takeA ? va : vb;
        if (takeA) a++; else bq++;
    }
}

// ---------------- final merge (runs of 4096) producing only top-KTOP indices ----------------
__global__ __launch_bounds__(256) void merge_top_kernel(
    const unsigned long long* __restrict__ src, int* __restrict__ idxo)
{
    const int tile = blockIdx.x;               // 0..31
    const int p = tile >> 1;
    const int o = (tile & 1) * MT;
    const int run = 4096;
    const unsigned long long* A  = src + (size_t)p * L_;
    const unsigned long long* Bv = A + run;

    int q0 = o + threadIdx.x * (MT/256);
    int lo = (q0 > run) ? (q0 - run) : 0;
    int hi = (q0 < run) ? q0 : run;
    while (lo < hi) {
        int mid = (lo + hi) >> 1;
        if (A[mid] >= Bv[q0 - 1 - mid]) lo = mid + 1; else hi = mid;
    }
    int a = lo, bq = q0 - lo;
    #pragma unroll
    for (int q = 0; q < MT/256; q++) {
        unsigned long long va = (a < run) ? A[a] : 0ULL;
        unsigned long long vb = (bq < run) ? Bv[bq] : 0ULL;
        bool takeA = (bq >= run) || ((a < run) && (va > vb));
        unsigned long long v = takeA ? va : vb;
        if (q0 + q < KTOP)
            idxo[p*KTOP + q0 + q] = (int)(0xFFFFFFFFu - (unsigned)(v & 0xFFFFFFFFu));
        if (takeA) a++; else bq++;
    }
}

// ---------------- y: tiled over 32 consecutive t with 51-row LDS window ----------------
#define TT 32
__global__ __launch_bounds__(256) void y_kernel(const float* __restrict__ xp,
    const int* __restrict__ idx, const float* __restrict__ conv_w,
    const float* __restrict__ cf, float* __restrict__ y)
{
    __shared__ float rows[(TT + JT - 1) * C_];   // 51 rows x 1KB = 51KB
    const int b = blockIdx.y;
    const int t0 = blockIdx.x * TT;
    const int tid = threadIdx.x;
    const int c4 = (tid & 63) * 4;
    const int tg = tid >> 6;
    const int* idxb = idx + b*KTOP;

    for (int s = tid; s < (TT + JT - 1) * 64; s += 256) {
        int r = s >> 6, cq = (s & 63) * 4;
        int gi = t0 - (JT - 1) + r;
        float4 v = make_float4(0.f, 0.f, 0.f, 0.f);
        if (gi >= 0 && gi < KTOP) {
            int l = idxb[gi];
            v = *(const float4*)&xp[((size_t)b*L_ + l)*C_ + cq];
        }
        *(float4*)&rows[r*C_ + cq] = v;
    }
    float4 cfr[JT];
    #pragma unroll
    for (int j = 0; j < JT; j++) cfr[j] = *(const float4*)&cf[j*C_ + c4];
    float4 cw = *(const float4*)&conv_w[c4];
    __syncthreads();

    #pragma unroll
    for (int u = 0; u < TT/4; u++) {
        int tl = tg + u*4;
        int t = t0 + tl;
        if (t < KTOP) {
            float4 acc = make_float4(0.f, 0.f, 0.f, 0.f);
            #pragma unroll
            for (int j = 0; j < JT; j++) {
                const float4 v = *(const float4*)&rows[(tl + JT - 1 - j)*C_ + c4];
                acc.x = fmaf(cfr[j].x, v.x, acc.x);
                acc.y = fmaf(cfr[j].y, v.y, acc.y);
                acc.z = fmaf(cfr[j].z, v.z, acc.z);
                acc.w = fmaf(cfr[j].w, v.w, acc.w);
            }
            acc.x *= cw.x; acc.y *= cw.y; acc.z *= cw.z; acc.w *= cw.w;
            *(float4*)&y[((size_t)b*KTOP + t)*C_ + c4] = acc;
        }
    }
}

// ---------------- GEMM2 + scatter epilogue: BM=128, BN=128, BK=16, dbuf, (256,3) ----------------
// LDS 2x(16*132+16*128)*4 = 33.3KB -> 3 blocks/CU at (256,3); 616 blocks fit ~one block-wave.
// acc 64 + 2 float4 prefetch + addr ~ 100 VGPR << 170 cap (no spill; canary=VGPR/WRITE).
__global__ __launch_bounds__(256, 3) void gemm2_kernel(
    const float* __restrict__ y, const float* __restrict__ WoT,
    const float* __restrict__ bo, const float* __restrict__ x,
    const int* __restrict__ idx, float* __restrict__ out0)
{
    __shared__ float As[2][16*132];
    __shared__ float Bs[2][16*128];   // 512B rows; wave covers 1KB = 2 rows
    const int tid = threadIdx.x;
    const int lane = tid & 63;
    const int wv = tid >> 6;
    const int tm2 = tid >> 4;          // rows tm2*8
    const int tn2 = tid & 15;          // cols tn2*4, +64
    const int m0 = blockIdx.x * 128;
    const int n0 = blockIdx.y * 128;
    const int ar = tid >> 2;           // 0..63 (+64)
    const int ak = (tid & 3) * 4;      // 0,4,8,12

    float acc[8][8];
    #pragma unroll
    for (int i = 0; i < 8; i++)
        #pragma unroll
        for (int j = 0; j < 8; j++) acc[i][j] = 0.f;

    // prologue: tile 0
    #pragma unroll
    for (int it = 0; it < 2; it++) {
        int brow = 2*wv + it*8;
        async_copy16(&WoT[(size_t)(brow + (lane>>5))*C_ + n0 + (lane&31)*4],
                     &Bs[0][brow*128]);
    }
    #pragma unroll
    for (int it = 0; it < 2; it++) {
        int r = ar + it*64;
        int m = m0 + r;
        float4 v = (m < M2) ? *(const float4*)&y[(size_t)m*C_ + ak]
                            : make_float4(0.f, 0.f, 0.f, 0.f);
        As[0][(ak+0)*132 + r] = v.x;
        As[0][(ak+1)*132 + r] = v.y;
        As[0][(ak+2)*132 + r] = v.z;
        As[0][(ak+3)*132 + r] = v.w;
    }
    __syncthreads();
    int cur = 0;
    for (int t = 0; t < 16; t++) {
        const int k0 = t * 16;
        float4 ya0, ya1;
        if (t < 15) {
            int nxt = cur ^ 1;
            #pragma unroll
            for (int it = 0; it < 2; it++) {
                int brow = 2*wv + it*8;
                async_copy16(&WoT[(size_t)(k0 + 16 + brow + (lane>>5))*C_ + n0 + (lane&31)*4],
                             &Bs[nxt][brow*128]);
            }
            int mA = m0 + ar, mB = m0 + ar + 64;
            ya0 = (mA < M2) ? *(const float4*)&y[(size_t)mA*C_ + k0 + 16 + ak]
                            : make_float4(0.f, 0.f, 0.f, 0.f);
            ya1 = (mB < M2) ? *(const float4*)&y[(size_t)mB*C_ + k0 + 16 + ak]
                            : make_float4(0.f, 0.f, 0.f, 0.f);
        }
        #pragma unroll 2
        for (int kk = 0; kk < 16; kk++) {
            float a[8], bf[8];
            *(float4*)&a[0]  = *(const float4*)&As[cur][kk*132 + tm2*8];
            *(float4*)&a[4]  = *(const float4*)&As[cur][kk*132 + tm2*8 + 4];
            *(float4*)&bf[0] = *(const float4*)&Bs[cur][kk*128 + tn2*4];
            *(float4*)&bf[4] = *(const float4*)&Bs[cur][kk*128 + tn2*4 + 64];
            #pragma unroll
            for (int i = 0; i < 8; i++)
                #pragma unroll
                for (int j = 0; j < 8; j++)
                    acc[i][j] = fmaf(a[i], bf[j], acc[i][j]);
        }
        if (t < 15) {
            int nxt = cur ^ 1;
            As[nxt][(ak+0)*132 + ar] = ya0.x;
            As[nxt][(ak+1)*132 + ar] = ya0.y;
            As[nxt][(ak+2)*132 + ar] = ya0.z;
            As[nxt][(ak+3)*132 + ar] = ya0.w;
            As[nxt][(ak+0)*132 + ar + 64] = ya1.x;
            As[nxt][(ak+1)*132 + ar + 64] = ya1.y;
            As[nxt][(ak+2)*132 + ar + 64] = ya1.z;
            As[nxt][(ak+3)*132 + ar + 64] = ya1.w;
            cur = nxt;
        }
        __syncthreads();
    }
    float4 bo0 = *(const float4*)&bo[n0 + tn2*4];
    float4 bo1 = *(const float4*)&bo[n0 + 64 + tn2*4];
    #pragma unroll
    for (int i = 0; i < 8; i++) {
        int m = m0 + tm2*8 + i;
        if (m < M2) {
            int b = m / KTOP, t = m - b*KTOP;
            int l = idx[b*KTOP + t];
            size_t base = ((size_t)b*L_ + l)*C_;
            float4 x0 = *(const float4*)&x[base + n0 + tn2*4];
            float4 x1 = *(const float4*)&x[base + n0 + 64 + tn2*4];
            float4 o0 = make_float4(acc[i][0]+bo0.x+x0.x, acc[i][1]+bo0.y+x0.y,
                                    acc[i][2]+bo0.z+x0.z, acc[i][3]+bo0.w+x0.w);
            float4 o1 = make_float4(acc[i][4]+bo1.x+x1.x, acc[i][5]+bo1.y+x1.y,
                                    acc[i][6]+bo1.z+x1.z, acc[i][7]+bo1.w+x1.w);
            *(float4*)&out0[base + n0 + tn2*4]      = o0;
            *(float4*)&out0[base + n0 + 64 + tn2*4] = o1;
        }
    }
}

extern "C" void kernel_launch(void* const* d_in, const int* in_sizes, int n_in,
                              void* d_out, int out_size, void* d_ws, size_t ws_size,
                              hipStream_t stream)
{
    const float* x      = (const float*)d_in[0];
    const float* alpha  = (const float*)d_in[1];
    const float* dyt_w  = (const float*)d_in[2];
    const float* dyt_b  = (const float*)d_in[3];
    const float* Wi     = (const float*)d_in[4];
    const float* bi     = (const float*)d_in[5];
    const float* conv_w = (const float*)d_in[6];
    const float* A      = (const float*)d_in[7];
    const float* Bp     = (const float*)d_in[8];
    const float* Cp     = (const float*)d_in[9];
    const float* Wo     = (const float*)d_in[10];
    const float* bo     = (const float*)d_in[11];

    float* ws  = (float*)d_ws;
    float* xp  = ws + XP_OFF;
    float* yb  = ws + Y_OFF;
    float* cn  = ws + CN_OFF;
    float* cf  = ws + CF_OFF;
    int*   idx = (int*)(ws + IDX_OFF);
    float* WiT = ws + WIT_OFF;
    float* WoT = ws + WOT_OFF;
    // Y-region sub-lease (all dead before y_kernel writes yb):
    unsigned long long* kw1 = (unsigned long long*)(ws + Y_OFF);   // 131072 u64
    unsigned long long* kw2 = kw1 + (size_t)B_*L_;                 // 131072 u64
    float* e = ws + Y_OFF + 524288;                                // M1 floats

    float* out0 = (float*)d_out;
    float* sim  = out0 + (size_t)M1*C_;

    prep_kernel<<<145, 256, 0, stream>>>(Wi, Wo, WiT, WoT, A, Bp, Cp, cf,
                                         x, bi, alpha, dyt_w, dyt_b, cn);
    gemm1_kernel<<<M1/128, 256, 0, stream>>>(x, WiT, bi, alpha, dyt_w, dyt_b, cn, xp, e, out0);
    softmax_kernel<<<B_, 1024, 0, stream>>>(e, sim, kw1);
    sort1k_kernel<<<B_*L_/1024, 256, 0, stream>>>(kw1);
    merge_kernel<<<B_*L_/MT, 256, 0, stream>>>(kw1, kw2, 1024);
    merge_kernel<<<B_*L_/MT, 256, 0, stream>>>(kw2, kw1, 2048);
    merge_top_kernel<<<B_*2, 256, 0, stream>>>(kw1, idx);
    y_kernel<<<dim3((KTOP + TT - 1)/TT, B_), 256, 0, stream>>>(xp, idx, conv_w, cf, yb);
    gemm2_kernel<<<dim3((M2 + 127)/128, 2), 256, 0, stream>>>(yb, WoT, bo, x, idx, out0);
}

// Round 13
// 419.510 us; speedup vs baseline: 1.6713x; 1.0046x over previous
//
#include <hip/hip_runtime.h>
#include <math.h>

#define B_ 16
#define L_ 8192
#define C_ 256
#define KTOP 2457            // max(1, int(8192*0.3))
#define JT 20                // recurrence taps; ||A||^20 ~ 1e-16 -> exact at fp32
#define M1 (B_*L_)           // 131072
#define M2 (B_*KTOP)         // 39312

// workspace layout in floats
#define XP_OFF  ((size_t)0)
#define Y_OFF   (XP_OFF + (size_t)M1*C_)        // yb: M2*C_ floats
#define CN_OFF  (Y_OFF  + (size_t)M2*C_)
#define CF_OFF  (CN_OFF + (size_t)B_*C_)
#define IDX_OFF (CF_OFF + (size_t)JT*C_)        // ints
#define WIT_OFF (IDX_OFF + (size_t)M2)
#define WOT_OFF (WIT_OFF + (size_t)C_*C_)
// Y region sub-lease (all die before y_kernel writes yb):
//   kw1 = Y_OFF (131072 u64 = 262144 f), kw2 = +262144 f, e = +524288 (M1 f)

// async global->LDS, 16B per lane, wave-uniform LDS base (m97 pattern)
__device__ __forceinline__ void async_copy16(const float* g, float* l) {
    __builtin_amdgcn_global_load_lds(
        (const __attribute__((address_space(1))) void*)g,
        (__attribute__((address_space(3))) void*)l, 16, 0, 0);
}

// ---------------- prep: transpose Wi/Wo + coef + center2, one launch ----------------
__global__ __launch_bounds__(256) void prep_kernel(
    const float* __restrict__ Wi, const float* __restrict__ Wo,
    float* __restrict__ WiT, float* __restrict__ WoT,
    const float* __restrict__ A, const float* __restrict__ Bp, const float* __restrict__ Cp,
    float* __restrict__ cf,
    const float* __restrict__ x, const float* __restrict__ bi, const float* __restrict__ alpha,
    const float* __restrict__ dw, const float* __restrict__ db, float* __restrict__ cn)
{
    __shared__ float shm[1089];
    const int bid = blockIdx.x, tid = threadIdx.x;
    if (bid < 128) {
        const int z = bid >> 6, rem = bid & 63;
        const int r0 = (rem >> 3) * 32, c0 = (rem & 7) * 32;
        const float* src = z ? Wo : Wi;
        float* dst = z ? WoT : WiT;
        float (*t)[33] = (float(*)[33])shm;
        int tx = tid & 31, ty = tid >> 5;
        #pragma unroll
        for (int r = 0; r < 4; r++)
            t[ty + r*8][tx] = src[(size_t)(r0 + ty + r*8)*C_ + c0 + tx];
        __syncthreads();
        #pragma unroll
        for (int r = 0; r < 4; r++)
            dst[(size_t)(c0 + ty + r*8)*C_ + r0 + tx] = t[tx][ty + r*8];
    } else if (bid == 128) {
        int c = tid;
        float* As = shm;
        float* v0 = shm + 256;
        As[c] = A[c];
        if (c < 16) v0[c] = 1.0f / (1.0f + expf(-Bp[c]));
        float sC[16];
        #pragma unroll
        for (int i = 0; i < 16; i++) sC[i] = 1.0f / (1.0f + expf(-Cp[c*16 + i]));
        __syncthreads();
        float v[16];
        #pragma unroll
        for (int i = 0; i < 16; i++) v[i] = v0[i];
        for (int j = 0; j < JT; j++) {
            float d = 0.f;
            #pragma unroll
            for (int i = 0; i < 16; i++) d += sC[i] * v[i];
            cf[j*C_ + c] = d;
            float nv[16];
            #pragma unroll
            for (int i = 0; i < 16; i++) {
                float s = 0.f;
                #pragma unroll
                for (int m = 0; m < 16; m++) s += As[i*16 + m] * v[m];
                nv[i] = s;
            }
            #pragma unroll
            for (int i = 0; i < 16; i++) v[i] = nv[i];
        }
    } else {
        int b = bid - 129, c = tid;
        float* xn = shm;
        float* red = shm + 256;
        float al = alpha[0];
        size_t base = ((size_t)b*L_ + L_/2)*C_;
        xn[c] = tanhf(al*x[base + c])*dw[c] + db[c];
        __syncthreads();
        float s = bi[c];
        #pragma unroll 8
        for (int k = 0; k < 256; k++) s = fmaf(xn[k], Wi[(size_t)c*C_ + k], s);
        float ss = s*s;
        #pragma unroll
        for (int off = 32; off; off >>= 1) ss += __shfl_xor(ss, off);
        if ((c & 63) == 0) red[c >> 6] = ss;
        __syncthreads();
        float tot = red[0] + red[1] + red[2] + red[3];
        float inv = 1.0f / fmaxf(sqrtf(tot), 1e-12f);
        cn[b*C_ + c] = s * inv;
    }
}

// ---------------- GEMM1 + fused e + fused residual: BM=128, BN=256, BK=16, dbuf ----------------
// (256,2): VGPR ~104-120 (no squeeze). Per tile: x(t+1)->regs FIRST, then async B(t+1)->Bs[nxt],
// then compute(t); tanh+A-write after; ONE barrier/tile. kk unroll 4: ds_read offsets become
// compile-time immediates (16-bit offset field covers 4 kk at stride 528B).
// Canaries: WRITE ~263MB; VGPR <= 128; conflicts ~1e6.
__global__ __launch_bounds__(256, 2) void gemm1_kernel(
    const float* __restrict__ x, const float* __restrict__ WiT,
    const float* __restrict__ bi, const float* __restrict__ alpha,
    const float* __restrict__ dw, const float* __restrict__ db,
    const float* __restrict__ cn, float* __restrict__ xp, float* __restrict__ e,
    float* __restrict__ out0)
{
    __shared__ float As[2][16*132];   // [kk][m], pad 132 keeps 16B align
    __shared__ float Bs[2][16*256];   // [kk][n], 1KB rows
    const int tid = threadIdx.x;
    const int lane = tid & 63;
    const int wv = tid >> 6;       // 0..3
    const int tn2 = tid & 31;      // cols tn2*4..+3 and 128+tn2*4..+3
    const int tm2 = tid >> 5;      // rows tm2*16..+15
    const int m0 = blockIdx.x * 128;
    const int b  = m0 >> 13;
    const float al = alpha[0];
    const int ar = tid >> 2;             // A stage row 0..63 (+64)
    const int ak = (tid & 3) * 4;        // A stage k 0,4,8,12

    float acc[16][8];
    #pragma unroll
    for (int i = 0; i < 16; i++)
        #pragma unroll
        for (int j = 0; j < 8; j++) acc[i][j] = 0.f;

    // prologue: stage tile 0 into buffer 0
    #pragma unroll
    for (int it = 0; it < 4; it++)
        async_copy16(&WiT[(size_t)(wv + it*4)*C_ + lane*4], &Bs[0][(wv + it*4)*256]);
    {
        float4 w4 = *(const float4*)&dw[ak];
        float4 b4 = *(const float4*)&db[ak];
        #pragma unroll
        for (int it = 0; it < 2; it++) {
            int r = ar + it*64;
            float4 v = *(const float4*)&x[(size_t)(m0 + r)*C_ + ak];
            As[0][(ak+0)*132 + r] = tanhf(al*v.x)*w4.x + b4.x;
            As[0][(ak+1)*132 + r] = tanhf(al*v.y)*w4.y + b4.y;
            As[0][(ak+2)*132 + r] = tanhf(al*v.z)*w4.z + b4.z;
            As[0][(ak+3)*132 + r] = tanhf(al*v.w)*w4.w + b4.w;
        }
    }
    __syncthreads();
    int cur = 0;
    for (int t = 0; t < 16; t++) {
        const int k0 = t * 16;
        float4 xa0, xa1;
        if (t < 15) {
            int nxt = cur ^ 1;
            // x(t+1) into regs first (maximal latency lead), then async B(t+1)
            xa0 = *(const float4*)&x[(size_t)(m0 + ar)*C_ + k0 + 16 + ak];
            xa1 = *(const float4*)&x[(size_t)(m0 + ar + 64)*C_ + k0 + 16 + ak];
            #pragma unroll
            for (int it = 0; it < 4; it++)
                async_copy16(&WiT[(size_t)(k0 + 16 + wv + it*4)*C_ + lane*4],
                             &Bs[nxt][(wv + it*4)*256]);
        }
        #pragma unroll 4
        for (int kk = 0; kk < 16; kk++) {
            float a[16];
            *(float4*)&a[0]  = *(const float4*)&As[cur][kk*132 + tm2*16];
            *(float4*)&a[4]  = *(const float4*)&As[cur][kk*132 + tm2*16 + 4];
            *(float4*)&a[8]  = *(const float4*)&As[cur][kk*132 + tm2*16 + 8];
            *(float4*)&a[12] = *(const float4*)&As[cur][kk*132 + tm2*16 + 12];
            float4 b0 = *(const float4*)&Bs[cur][kk*256 + tn2*4];
            float4 b1 = *(const float4*)&Bs[cur][kk*256 + tn2*4 + 128];
            #pragma unroll
            for (int i = 0; i < 16; i++) {
                acc[i][0] = fmaf(a[i], b0.x, acc[i][0]);
                acc[i][1] = fmaf(a[i], b0.y, acc[i][1]);
                acc[i][2] = fmaf(a[i], b0.z, acc[i][2]);
                acc[i][3] = fmaf(a[i], b0.w, acc[i][3]);
                acc[i][4] = fmaf(a[i], b1.x, acc[i][4]);
                acc[i][5] = fmaf(a[i], b1.y, acc[i][5]);
                acc[i][6] = fmaf(a[i], b1.z, acc[i][6]);
                acc[i][7] = fmaf(a[i], b1.w, acc[i][7]);
            }
        }
        if (t < 15) {
            int nxt = cur ^ 1;
            float4 w4 = *(const float4*)&dw[k0 + 16 + ak];
            float4 b4 = *(const float4*)&db[k0 + 16 + ak];
            As[nxt][(ak+0)*132 + ar] = tanhf(al*xa0.x)*w4.x + b4.x;
            As[nxt][(ak+1)*132 + ar] = tanhf(al*xa0.y)*w4.y + b4.y;
            As[nxt][(ak+2)*132 + ar] = tanhf(al*xa0.z)*w4.z + b4.z;
            As[nxt][(ak+3)*132 + ar] = tanhf(al*xa0.w)*w4.w + b4.w;
            As[nxt][(ak+0)*132 + ar + 64] = tanhf(al*xa1.x)*w4.x + b4.x;
            As[nxt][(ak+1)*132 + ar + 64] = tanhf(al*xa1.y)*w4.y + b4.y;
            As[nxt][(ak+2)*132 + ar + 64] = tanhf(al*xa1.z)*w4.z + b4.z;
            As[nxt][(ak+3)*132 + ar + 64] = tanhf(al*xa1.w)*w4.w + b4.w;
            cur = nxt;
        }
        __syncthreads();
    }
    float4 bi0 = *(const float4*)&bi[tn2*4];
    float4 bi1 = *(const float4*)&bi[tn2*4 + 128];
    float4 c0  = *(const float4*)&cn[b*C_ + tn2*4];
    float4 c1  = *(const float4*)&cn[b*C_ + tn2*4 + 128];
    #pragma unroll
    for (int i = 0; i < 16; i++) {
        size_t row = m0 + tm2*16 + i;
        float4 o0 = make_float4(acc[i][0]+bi0.x, acc[i][1]+bi0.y, acc[i][2]+bi0.z, acc[i][3]+bi0.w);
        float4 o1 = make_float4(acc[i][4]+bi1.x, acc[i][5]+bi1.y, acc[i][6]+bi1.z, acc[i][7]+bi1.w);
        *(float4*)&xp[row*C_ + tn2*4]       = o0;
        *(float4*)&xp[row*C_ + tn2*4 + 128] = o1;
        // fused residual: out0 = x (topk rows overwritten later by gemm2); rows L2-hot
        *(float4*)&out0[row*C_ + tn2*4]       = *(const float4*)&x[row*C_ + tn2*4];
        *(float4*)&out0[row*C_ + tn2*4 + 128] = *(const float4*)&x[row*C_ + tn2*4 + 128];
        float dt = o0.x*c0.x + o0.y*c0.y + o0.z*c0.z + o0.w*c0.w
                 + o1.x*c1.x + o1.y*c1.y + o1.z*c1.z + o1.w*c1.w;
        float ss = o0.x*o0.x + o0.y*o0.y + o0.z*o0.z + o0.w*o0.w
                 + o1.x*o1.x + o1.y*o1.y + o1.z*o1.z + o1.w*o1.w;
        #pragma unroll
        for (int off = 16; off; off >>= 1) {
            dt += __shfl_xor(dt, off);
            ss += __shfl_xor(ss, off);
        }
        if (tn2 == 0) e[row] = dt / fmaxf(sqrtf(ss), 1e-12f);
    }
}

// ---------------- softmax per batch; emit sim + u64 keys (sim desc, idx asc) ----------------
__global__ __launch_bounds__(1024) void softmax_kernel(
    const float* __restrict__ e, float* __restrict__ sim, unsigned long long* __restrict__ kw)
{
    __shared__ float scratch[32];
    const int b = blockIdx.x, tid = threadIdx.x;
    const int lane = tid & 63, wid = tid >> 6; // 16 waves
    const float* eb = e + (size_t)b*L_;
    float ev[8];
    #pragma unroll
    for (int s = 0; s < 8; s++) ev[s] = eb[tid + s*1024];
    float mx = ev[0];
    #pragma unroll
    for (int s = 1; s < 8; s++) mx = fmaxf(mx, ev[s]);
    #pragma unroll
    for (int off = 32; off; off >>= 1) mx = fmaxf(mx, __shfl_xor(mx, off));
    if (lane == 0) scratch[wid] = mx;
    __syncthreads();
    if (tid == 0) {
        float m2 = scratch[0];
        for (int i = 1; i < 16; i++) m2 = fmaxf(m2, scratch[i]);
        scratch[20] = m2;
    }
    __syncthreads();
    mx = scratch[20];
    float pv[8], sum = 0.f;
    #pragma unroll
    for (int s = 0; s < 8; s++) { pv[s] = expf(ev[s] - mx); sum += pv[s]; }
    #pragma unroll
    for (int off = 32; off; off >>= 1) sum += __shfl_xor(sum, off);
    __syncthreads();
    if (lane == 0) scratch[wid] = sum;
    __syncthreads();
    if (tid == 0) {
        float s2 = 0.f;
        for (int i = 0; i < 16; i++) s2 += scratch[i];
        scratch[21] = s2;
    }
    __syncthreads();
    float inv = 1.0f / scratch[21];
    #pragma unroll
    for (int s = 0; s < 8; s++) {
        int l = tid + s*1024;
        float sm = pv[s] * inv;
        sim[(size_t)b*L_ + l] = sm;
        kw[(size_t)b*L_ + l] =
            ((unsigned long long)__float_as_uint(sm) << 32) | (unsigned)(0xFFFFFFFFu - l);
    }
}

// ---------------- sort 1024-element chunks descending (bitonic in LDS) ----------------
__global__ __launch_bounds__(256) void sort1k_kernel(unsigned long long* __restrict__ keys)
{
    __shared__ unsigned long long k[1024];
    size_t base = (size_t)blockIdx.x * 1024;
    int tid = threadIdx.x;
    #pragma unroll
    for (int s = 0; s < 4; s++) k[tid + s*256] = keys[base + tid + s*256];
    __syncthreads();
    for (int ksz = 2; ksz <= 1024; ksz <<= 1) {
        for (int j = ksz >> 1; j > 0; j >>= 1) {
            #pragma unroll
            for (int s = 0; s < 2; s++) {
                int p = tid + s*256;
                int i = ((p & ~(j-1)) << 1) | (p & (j-1));
                int ix = i | j;
                unsigned long long a = k[i], c = k[ix];
                bool desc = ((i & ksz) == 0);
                if (desc ? (a < c) : (a > c)) { k[i] = c; k[ix] = a; }
            }
            __syncthreads();
        }
    }
    #pragma unroll
    for (int s = 0; s < 4; s++) keys[base + tid + s*256] = k[tid + s*256];
}

// ---------------- merge pass, tile-parallel: fixed 2048-output tiles, merge-path ----------------
#define MT 2048
__global__ __launch_bounds__(256) void merge_kernel(
    const unsigned long long* __restrict__ src, unsigned long long* __restrict__ dst, int run)
{
    const size_t tile = blockIdx.x;
    const size_t pairSpan = (size_t)2 * run;
    const size_t p = tile * MT / pairSpan;
    const int o = (int)(tile * MT % pairSpan);
    const unsigned long long* A  = src + p * pairSpan;
    const unsigned long long* Bv = A + run;
    unsigned long long* D = dst + p * pairSpan;

    int q0 = o + threadIdx.x * (MT/256);
    int lo = (q0 > run) ? (q0 - run) : 0;
    int hi = (q0 < run) ? q0 : run;
    while (lo < hi) {
        int mid = (lo + hi) >> 1;
        if (A[mid] >= Bv[q0 - 1 - mid]) lo = mid + 1; else hi = mid;
    }
    int a = lo, bq = q0 - lo;
    #pragma unroll
    for (int q = 0; q < MT/256; q++) {
        unsigned long long va = (a < run) ? A[a] : 0ULL;
        unsigned long long vb = (bq < run) ? Bv[bq] : 0ULL;
        bool takeA = (bq >= run) || ((a < run) && (va > vb));
        D[q0 + q] = takeA ? va : vb;
        if (takeA) a++; else bq++;
    }
}

// ---------------- final merge (runs of 4096) producing only top-KTOP indices ----------------
__global__ __launch_bounds__(256) void merge_top_kernel(
    const unsigned long long* __restrict__ src, int* __restrict__ idxo)
{
    const int tile = blockIdx.x;               // 0..31
    const int p = tile >> 1;
    const int o = (tile & 1) * MT;
    const int run = 4096;
    const unsigned long long* A  = src + (size_t)p * L_;
    const unsigned long long* Bv = A + run;

    int q0 = o + threadIdx.x * (MT/256);
    int lo = (q0 > run) ? (q0 - run) : 0;
    int hi = (q0 < run) ? q0 : run;
    while (lo < hi) {
        int mid = (lo + hi) >> 1;
        if (A[mid] >= Bv[q0 - 1 - mid]) lo = mid + 1; else hi = mid;
    }
    int a = lo, bq = q0 - lo;
    #pragma unroll
    for (int q = 0; q < MT/256; q++) {
        unsigned long long va = (a < run) ? A[a] : 0ULL;
        unsigned long long vb = (bq < run) ? Bv[bq] : 0ULL;
        bool takeA = (bq >= run) || ((a < run) && (va > vb));
        unsigned long long v = takeA ? va : vb;
        if (q0 + q < KTOP)
            idxo[p*KTOP + q0 + q] = (int)(0xFFFFFFFFu - (unsigned)(v & 0xFFFFFFFFu));
        if (takeA) a++; else bq++;
    }
}

// ---------------- y: tiled over 32 consecutive t with 51-row LDS window ----------------
#define TT 32
__global__ __launch_bounds__(256) void y_kernel(const float* __restrict__ xp,
    const int* __restrict__ idx, const float* __restrict__ conv_w,
    const float* __restrict__ cf, float* __restrict__ y)
{
    __shared__ float rows[(TT + JT - 1) * C_];   // 51 rows x 1KB = 51KB
    const int b = blockIdx.y;
    const int t0 = blockIdx.x * TT;
    const int tid = threadIdx.x;
    const int c4 = (tid & 63) * 4;
    const int tg = tid >> 6;
    const int* idxb = idx + b*KTOP;

    for (int s = tid; s < (TT + JT - 1) * 64; s += 256) {
        int r = s >> 6, cq = (s & 63) * 4;
        int gi = t0 - (JT - 1) + r;
        float4 v = make_float4(0.f, 0.f, 0.f, 0.f);
        if (gi >= 0 && gi < KTOP) {
            int l = idxb[gi];
            v = *(const float4*)&xp[((size_t)b*L_ + l)*C_ + cq];
        }
        *(float4*)&rows[r*C_ + cq] = v;
    }
    float4 cfr[JT];
    #pragma unroll
    for (int j = 0; j < JT; j++) cfr[j] = *(const float4*)&cf[j*C_ + c4];
    float4 cw = *(const float4*)&conv_w[c4];
    __syncthreads();

    #pragma unroll
    for (int u = 0; u < TT/4; u++) {
        int tl = tg + u*4;
        int t = t0 + tl;
        if (t < KTOP) {
            float4 acc = make_float4(0.f, 0.f, 0.f, 0.f);
            #pragma unroll
            for (int j = 0; j < JT; j++) {
                const float4 v = *(const float4*)&rows[(tl + JT - 1 - j)*C_ + c4];
                acc.x = fmaf(cfr[j].x, v.x, acc.x);
                acc.y = fmaf(cfr[j].y, v.y, acc.y);
                acc.z = fmaf(cfr[j].z, v.z, acc.z);
                acc.w = fmaf(cfr[j].w, v.w, acc.w);
            }
            acc.x *= cw.x; acc.y *= cw.y; acc.z *= cw.z; acc.w *= cw.w;
            *(float4*)&y[((size_t)b*KTOP + t)*C_ + c4] = acc;
        }
    }
}

// ---------------- GEMM2 + scatter epilogue: BM=128, BN=128, BK=16, dbuf, (256,3) ----------------
__global__ __launch_bounds__(256, 3) void gemm2_kernel(
    const float* __restrict__ y, const float* __restrict__ WoT,
    const float* __restrict__ bo, const float* __restrict__ x,
    const int* __restrict__ idx, float* __restrict__ out0)
{
    __shared__ float As[2][16*132];
    __shared__ float Bs[2][16*128];   // 512B rows; wave covers 1KB = 2 rows
    const int tid = threadIdx.x;
    const int lane = tid & 63;
    const int wv = tid >> 6;
    const int tm2 = tid >> 4;          // rows tm2*8
    const int tn2 = tid & 15;          // cols tn2*4, +64
    const int m0 = blockIdx.x * 128;
    const int n0 = blockIdx.y * 128;
    const int ar = tid >> 2;           // 0..63 (+64)
    const int ak = (tid & 3) * 4;      // 0,4,8,12

    float acc[8][8];
    #pragma unroll
    for (int i = 0; i < 8; i++)
        #pragma unroll
        for (int j = 0; j < 8; j++) acc[i][j] = 0.f;

    // prologue: tile 0
    #pragma unroll
    for (int it = 0; it < 2; it++) {
        int brow = 2*wv + it*8;
        async_copy16(&WoT[(size_t)(brow + (lane>>5))*C_ + n0 + (lane&31)*4],
                     &Bs[0][brow*128]);
    }
    #pragma unroll
    for (int it = 0; it < 2; it++) {
        int r = ar + it*64;
        int m = m0 + r;
        float4 v = (m < M2) ? *(const float4*)&y[(size_t)m*C_ + ak]
                            : make_float4(0.f, 0.f, 0.f, 0.f);
        As[0][(ak+0)*132 + r] = v.x;
        As[0][(ak+1)*132 + r] = v.y;
        As[0][(ak+2)*132 + r] = v.z;
        As[0][(ak+3)*132 + r] = v.w;
    }
    __syncthreads();
    int cur = 0;
    for (int t = 0; t < 16; t++) {
        const int k0 = t * 16;
        float4 ya0, ya1;
        if (t < 15) {
            int nxt = cur ^ 1;
            int mA = m0 + ar, mB = m0 + ar + 64;
            ya0 = (mA < M2) ? *(const float4*)&y[(size_t)mA*C_ + k0 + 16 + ak]
                            : make_float4(0.f, 0.f, 0.f, 0.f);
            ya1 = (mB < M2) ? *(const float4*)&y[(size_t)mB*C_ + k0 + 16 + ak]
                            : make_float4(0.f, 0.f, 0.f, 0.f);
            #pragma unroll
            for (int it = 0; it < 2; it++) {
                int brow = 2*wv + it*8;
                async_copy16(&WoT[(size_t)(k0 + 16 + brow + (lane>>5))*C_ + n0 + (lane&31)*4],
                             &Bs[nxt][brow*128]);
            }
        }
        #pragma unroll 4
        for (int kk = 0; kk < 16; kk++) {
            float a[8], bf[8];
            *(float4*)&a[0]  = *(const float4*)&As[cur][kk*132 + tm2*8];
            *(float4*)&a[4]  = *(const float4*)&As[cur][kk*132 + tm2*8 + 4];
            *(float4*)&bf[0] = *(const float4*)&Bs[cur][kk*128 + tn2*4];
            *(float4*)&bf[4] = *(const float4*)&Bs[cur][kk*128 + tn2*4 + 64];
            #pragma unroll
            for (int i = 0; i < 8; i++)
                #pragma unroll
                for (int j = 0; j < 8; j++)
                    acc[i][j] = fmaf(a[i], bf[j], acc[i][j]);
        }
        if (t < 15) {
            int nxt = cur ^ 1;
            As[nxt][(ak+0)*132 + ar] = ya0.x;
            As[nxt][(ak+1)*132 + ar] = ya0.y;
            As[nxt][(ak+2)*132 + ar] = ya0.z;
            As[nxt][(ak+3)*132 + ar] = ya0.w;
            As[nxt][(ak+0)*132 + ar + 64] = ya1.x;
            As[nxt][(ak+1)*132 + ar + 64] = ya1.y;
            As[nxt][(ak+2)*132 + ar + 64] = ya1.z;
            As[nxt][(ak+3)*132 + ar + 64] = ya1.w;
            cur = nxt;
        }
        __syncthreads();
    }
    float4 bo0 = *(const float4*)&bo[n0 + tn2*4];
    float4 bo1 = *(const float4*)&bo[n0 + 64 + tn2*4];
    #pragma unroll
    for (int i = 0; i < 8; i++) {
        int m = m0 + tm2*8 + i;
        if (m < M2) {
            int b = m / KTOP, t = m - b*KTOP;
            int l = idx[b*KTOP + t];
            size_t base = ((size_t)b*L_ + l)*C_;
            float4 x0 = *(const float4*)&x[base + n0 + tn2*4];
            float4 x1 = *(const float4*)&x[base + n0 + 64 + tn2*4];
            float4 o0 = make_float4(acc[i][0]+bo0.x+x0.x, acc[i][1]+bo0.y+x0.y,
                                    acc[i][2]+bo0.z+x0.z, acc[i][3]+bo0.w+x0.w);
            float4 o1 = make_float4(acc[i][4]+bo1.x+x1.x, acc[i][5]+bo1.y+x1.y,
                                    acc[i][6]+bo1.z+x1.z, acc[i][7]+bo1.w+x1.w);
            *(float4*)&out0[base + n0 + tn2*4]      = o0;
            *(float4*)&out0[base + n0 + 64 + tn2*4] = o1;
        }
    }
}

extern "C" void kernel_launch(void* const* d_in, const int* in_sizes, int n_in,
                              void* d_out, int out_size, void* d_ws, size_t ws_size,
                              hipStream_t stream)
{
    const float* x      = (const float*)d_in[0];
    const float* alpha  = (const float*)d_in[1];
    const float* dyt_w  = (const float*)d_in[2];
    const float* dyt_b  = (const float*)d_in[3];
    const float* Wi     = (const float*)d_in[4];
    const float* bi     = (const float*)d_in[5];
    const float* conv_w = (const float*)d_in[6];
    const float* A      = (const float*)d_in[7];
    const float* Bp     = (const float*)d_in[8];
    const float* Cp     = (const float*)d_in[9];
    const float* Wo     = (const float*)d_in[10];
    const float* bo     = (const float*)d_in[11];

    float* ws  = (float*)d_ws;
    float* xp  = ws + XP_OFF;
    float* yb  = ws + Y_OFF;
    float* cn  = ws + CN_OFF;
    float* cf  = ws + CF_OFF;
    int*   idx = (int*)(ws + IDX_OFF);
    float* WiT = ws + WIT_OFF;
    float* WoT = ws + WOT_OFF;
    // Y-region sub-lease (all dead before y_kernel writes yb):
    unsigned long long* kw1 = (unsigned long long*)(ws + Y_OFF);   // 131072 u64
    unsigned long long* kw2 = kw1 + (size_t)B_*L_;                 // 131072 u64
    float* e = ws + Y_OFF + 524288;                                // M1 floats

    float* out0 = (float*)d_out;
    float* sim  = out0 + (size_t)M1*C_;

    prep_kernel<<<145, 256, 0, stream>>>(Wi, Wo, WiT, WoT, A, Bp, Cp, cf,
                                         x, bi, alpha, dyt_w, dyt_b, cn);
    gemm1_kernel<<<M1/128, 256, 0, stream>>>(x, WiT, bi, alpha, dyt_w, dyt_b, cn, xp, e, out0);
    softmax_kernel<<<B_, 1024, 0, stream>>>(e, sim, kw1);
    sort1k_kernel<<<B_*L_/1024, 256, 0, stream>>>(kw1);
    merge_kernel<<<B_*L_/MT, 256, 0, stream>>>(kw1, kw2, 1024);
    merge_kernel<<<B_*L_/MT, 256, 0, stream>>>(kw2, kw1, 2048);
    merge_top_kernel<<<B_*2, 256, 0, stream>>>(kw1, idx);
    y_kernel<<<dim3((KTOP + TT - 1)/TT, B_), 256, 0, stream>>>(xp, idx, conv_w, cf, yb);
    gemm2_kernel<<<dim3((M2 + 127)/128, 2), 256, 0, stream>>>(yb, WoT, bo, x, idx, out0);
}